// Round 10
// baseline (1878.248 us; speedup 1.0000x reference)
//
#include <hip/hip_runtime.h>
#include <cstdint>

#define B 16
#define TY 1600
#define TX 400
#define MAS 384
#define HID 768
#define NEGV -1e9f

typedef __bf16 bf16x8 __attribute__((ext_vector_type(8)));
typedef float  f32x4  __attribute__((ext_vector_type(4)));
typedef float  f32x16 __attribute__((ext_vector_type(16)));

__device__ __forceinline__ f32x4 mfma16(bf16x8 a, bf16x8 b, f32x4 c) {
  return __builtin_amdgcn_mfma_f32_16x16x32_bf16(a, b, c, 0, 0, 0);
}
__device__ __forceinline__ f32x16 mfma32(bf16x8 a, bf16x8 b, f32x16 c) {
  return __builtin_amdgcn_mfma_f32_32x32x16_bf16(a, b, c, 0, 0, 0);
}

// ---------------- fp32 -> bf16 hi/lo split with channel padding ----------------
__global__ void split_pad_k(const float* __restrict__ in, __bf16* __restrict__ oh,
                            __bf16* __restrict__ ol, int CIN, int CINP, long n) {
  long i = (long)blockIdx.x * 256 + threadIdx.x;
  if (i >= n) return;
  long row = i / CINP; int ci = (int)(i - row * CINP);
  float v = (ci < CIN) ? in[row * CIN + ci] : 0.f;
  __bf16 h = (__bf16)v;
  oh[i] = h; ol[i] = (__bf16)(v - (float)h);
}

// ---------------- weight repack+split: w[N][CIN][K] -> oh/ol[N][k*CINP + ci] ----------------
__global__ void wsplit_k(const float* __restrict__ w, __bf16* __restrict__ oh,
                         __bf16* __restrict__ ol, int CIN, int K_, int CINP, long n) {
  long i = (long)blockIdx.x * 256 + threadIdx.x;
  if (i >= n) return;
  long kdspan = (long)K_ * CINP;
  long nn = i / kdspan; int kd = (int)(i - nn * kdspan);
  int k = kd / CINP, ci = kd - k * CINP;
  float v = (ci < CIN) ? w[(nn * CIN + ci) * K_ + k] : 0.f;
  __bf16 h = (__bf16)v;
  oh[i] = h; ol[i] = (__bf16)(v - (float)h);
}

// ---------------- transpose+split: w2 [m][JTOT] -> oh/ol [j][384] ----------------
__global__ void tsplit_k(const float* __restrict__ in, __bf16* __restrict__ oh,
                         __bf16* __restrict__ ol, int JTOT, long n) {
  long i = (long)blockIdx.x * 256 + threadIdx.x;
  if (i >= n) return;
  int m = (int)(i / JTOT), j = (int)(i - (long)m * JTOT);
  float v = in[i];
  long o = (long)j * 384 + m;
  __bf16 h = (__bf16)v;
  oh[o] = h; ol[o] = (__bf16)(v - (float)h);
}

// ---------------- bias fold: o[n] = sum_m wq[n][m] * b[m] ----------------
__global__ void fold_bias_k(const float* __restrict__ wq, const float* __restrict__ b,
                            float* __restrict__ o) {
  int n = threadIdx.x;
  float s = 0.f;
  for (int m = 0; m < 384; ++m) s = fmaf(wq[n * 384 + m], b[m], s);
  o[n] = s;
}

// ---------------- weight-fold GEMM: WF[n][(j%KK)*768 + j/KK] = sum_m w2t[j][m]*wq[n][m] ----------------
template<int KK>
__global__ __launch_bounds__(256)
void fold_mfma(const __bf16* __restrict__ xh, const __bf16* __restrict__ xl,
               const __bf16* __restrict__ wh, const __bf16* __restrict__ wl,
               __bf16* __restrict__ oh, __bf16* __restrict__ ol)
{
  constexpr int CINP = 384, ROWS = 64, STRIDE = 65;
  __shared__ float4 xs[8 * STRIDE];
  const int t0 = blockIdx.x * 64, n0 = blockIdx.y * 128;
  const int tid = threadIdx.x, wn = tid >> 6, lane = tid & 63;
  const int lr = lane & 15, lg = lane >> 4;
  const f32x4 Z4 = {0.f, 0.f, 0.f, 0.f};
  f32x4 acc[4][2];
  #pragma unroll
  for (int m = 0; m < 4; ++m) { acc[m][0] = Z4; acc[m][1] = Z4; }

  #pragma unroll 1
  for (int ci0 = 0; ci0 < CINP; ci0 += 32) {
    __syncthreads();
    for (int e = tid; e < ROWS * 8; e += 256) {
      int row = e >> 3, sc = e & 7, spl = sc >> 2, cg = sc & 3;
      int t = t0 + row;
      xs[(spl * 4 + cg) * STRIDE + row] =
          *(const float4*)((spl ? xl : xh) + (size_t)t * CINP + ci0 + cg * 8);
    }
    __syncthreads();
    bf16x8 ah[4], al[4];
    #pragma unroll
    for (int mf = 0; mf < 4; ++mf) {
      int row = mf * 16 + lr;
      ah[mf] = *(const bf16x8*)&xs[lg * STRIDE + row];
      al[mf] = *(const bf16x8*)&xs[(4 + lg) * STRIDE + row];
    }
    size_t kd = (size_t)ci0 + lg * 8;
    bf16x8 bh[2], bl[2];
    #pragma unroll
    for (int nf = 0; nf < 2; ++nf) {
      int nc = n0 + wn * 32 + nf * 16 + lr;
      bh[nf] = *(const bf16x8*)(wh + (size_t)nc * 384 + kd);
      bl[nf] = *(const bf16x8*)(wl + (size_t)nc * 384 + kd);
    }
    #pragma unroll
    for (int nf = 0; nf < 2; ++nf)
      #pragma unroll
      for (int mf = 0; mf < 4; ++mf) acc[mf][nf] = mfma16(ah[mf], bh[nf], acc[mf][nf]);
    #pragma unroll
    for (int nf = 0; nf < 2; ++nf)
      #pragma unroll
      for (int mf = 0; mf < 4; ++mf) acc[mf][nf] = mfma16(ah[mf], bl[nf], acc[mf][nf]);
    #pragma unroll
    for (int nf = 0; nf < 2; ++nf)
      #pragma unroll
      for (int mf = 0; mf < 4; ++mf) acc[mf][nf] = mfma16(al[mf], bh[nf], acc[mf][nf]);
  }
  #pragma unroll
  for (int nf = 0; nf < 2; ++nf) {
    int c = n0 + wn * 32 + nf * 16 + lr;
    #pragma unroll
    for (int mf = 0; mf < 4; ++mf) {
      #pragma unroll
      for (int r = 0; r < 4; ++r) {
        int j = t0 + mf * 16 + lg * 4 + r;
        int k = j % KK, ci = j / KK;
        size_t o = (size_t)c * (KK * HID) + (size_t)k * HID + ci;
        float v = acc[mf][nf][r];
        __bf16 vh = (__bf16)v;
        oh[o] = vh; ol[o] = (__bf16)(v - (float)vh);
      }
    }
  }
}

// ---------------- conv1 + ReGLU, split-bf16 MFMA (term-major issue order) ----------------
template<int CINP, int K, int T>
__global__ __launch_bounds__(256)
void conv1_mfma(const __bf16* __restrict__ xh, const __bf16* __restrict__ xl,
                const __bf16* __restrict__ wh, const __bf16* __restrict__ wl,
                const float* __restrict__ bias, const int* __restrict__ lens,
                __bf16* __restrict__ hh, __bf16* __restrict__ hl)
{
  constexpr int BM = 128, PAD = K / 2, ROWS = BM + K - 1, KD = K * CINP;
  __shared__ float4 xs[8 * ROWS];
  const int b = blockIdx.z, t0 = blockIdx.x * BM, n0 = blockIdx.y * 64;
  const int tid = threadIdx.x, wid = tid >> 6, lane = tid & 63;
  const int wm = wid >> 1, wn = wid & 1, lr = lane & 15, lg = lane >> 4;
  const int len = lens[b];
  const f32x4 Z4 = {0.f, 0.f, 0.f, 0.f};
  f32x4 acc_a[4][2], acc_g[4][2];
  #pragma unroll
  for (int m = 0; m < 4; ++m)
    #pragma unroll
    for (int n = 0; n < 2; ++n) { acc_a[m][n] = Z4; acc_g[m][n] = Z4; }

  #pragma unroll 1
  for (int ci0 = 0; ci0 < CINP; ci0 += 32) {
    __syncthreads();
    for (int e = tid; e < ROWS * 8; e += 256) {
      int row = e >> 3, sc = e & 7, spl = sc >> 2, cg = sc & 3;
      int t = t0 + row - PAD;
      float4 v = {0.f, 0.f, 0.f, 0.f};
      if (t >= 0 && t < len)
        v = *(const float4*)((spl ? xl : xh) + ((size_t)b * T + t) * CINP + ci0 + cg * 8);
      xs[(spl * 4 + cg) * ROWS + row] = v;
    }
    __syncthreads();
    #pragma unroll
    for (int k = 0; k < K; ++k) {
      bf16x8 ah[4], al[4];
      #pragma unroll
      for (int mf = 0; mf < 4; ++mf) {
        int row = wm * 64 + mf * 16 + lr + k;
        ah[mf] = *(const bf16x8*)&xs[lg * ROWS + row];
        al[mf] = *(const bf16x8*)&xs[(4 + lg) * ROWS + row];
      }
      size_t kd = (size_t)k * CINP + ci0 + lg * 8;
      bf16x8 bah[2], bal[2], bgh[2], bgl[2];
      #pragma unroll
      for (int nf = 0; nf < 2; ++nf) {
        int na = n0 + wn * 32 + nf * 16 + lr;
        bah[nf] = *(const bf16x8*)(wh + (size_t)na * KD + kd);
        bal[nf] = *(const bf16x8*)(wl + (size_t)na * KD + kd);
        bgh[nf] = *(const bf16x8*)(wh + (size_t)(na + HID) * KD + kd);
        bgl[nf] = *(const bf16x8*)(wl + (size_t)(na + HID) * KD + kd);
      }
      // term-major: same-acc MFMAs are 16 apart
      #pragma unroll
      for (int nf = 0; nf < 2; ++nf)
        #pragma unroll
        for (int mf = 0; mf < 4; ++mf) {
          acc_a[mf][nf] = mfma16(ah[mf], bah[nf], acc_a[mf][nf]);
          acc_g[mf][nf] = mfma16(ah[mf], bgh[nf], acc_g[mf][nf]);
        }
      #pragma unroll
      for (int nf = 0; nf < 2; ++nf)
        #pragma unroll
        for (int mf = 0; mf < 4; ++mf) {
          acc_a[mf][nf] = mfma16(ah[mf], bal[nf], acc_a[mf][nf]);
          acc_g[mf][nf] = mfma16(ah[mf], bgl[nf], acc_g[mf][nf]);
        }
      #pragma unroll
      for (int nf = 0; nf < 2; ++nf)
        #pragma unroll
        for (int mf = 0; mf < 4; ++mf) {
          acc_a[mf][nf] = mfma16(al[mf], bah[nf], acc_a[mf][nf]);
          acc_g[mf][nf] = mfma16(al[mf], bgh[nf], acc_g[mf][nf]);
        }
    }
  }
  #pragma unroll
  for (int nf = 0; nf < 2; ++nf) {
    int c = n0 + wn * 32 + nf * 16 + lr;
    float ba = bias[c], bg = bias[c + HID];
    #pragma unroll
    for (int mf = 0; mf < 4; ++mf) {
      #pragma unroll
      for (int r = 0; r < 4; ++r) {
        int t = t0 + wm * 64 + mf * 16 + lg * 4 + r;
        if (t < T) {
          float a = acc_a[mf][nf][r] + ba;
          float g = acc_g[mf][nf][r] + bg;
          float v = a * fmaxf(g, 0.f);
          __bf16 vh = (__bf16)v;
          size_t o = ((size_t)b * T + t) * HID + c;
          hh[o] = vh;
          hl[o] = (__bf16)(v - (float)vh);
        }
      }
    }
  }
}

// ---------------- conv2 with folded q/k weights, 32x32x16, term-major issue order ----------------
template<int CINP, int K, int T, bool STORET>
__global__ __launch_bounds__(256, 3)
void conv2_mfma(const __bf16* __restrict__ xh, const __bf16* __restrict__ xl,
                const __bf16* __restrict__ wh, const __bf16* __restrict__ wl,
                const float* __restrict__ bias, const float* __restrict__ ab,
                const int* __restrict__ lens, float* __restrict__ out)
{
  constexpr int BM = 128, PAD = K / 2, ROWS = BM + K - 1, STRIDE = ROWS + 1, KD = K * CINP;
  __shared__ float4 xs[8 * STRIDE];
  const int b = blockIdx.z, t0 = blockIdx.x * BM, n0 = blockIdx.y * 192;
  const int tid = threadIdx.x, wid = tid >> 6, lane = tid & 63;
  const int wm = wid >> 1, wn = wid & 1, lc = lane & 31, lk = lane >> 5;
  const int len = lens[b];
  f32x16 acc[2][3];
  #pragma unroll
  for (int m = 0; m < 2; ++m)
    #pragma unroll
    for (int n = 0; n < 3; ++n)
      #pragma unroll
      for (int r = 0; r < 16; ++r) acc[m][n][r] = 0.f;

  #pragma unroll 1
  for (int ci0 = 0; ci0 < CINP; ci0 += 32) {
    __syncthreads();
    for (int e = tid; e < ROWS * 8; e += 256) {
      int row = e >> 3, sc = e & 7, spl = sc >> 2, cg = sc & 3;
      int t = t0 + row - PAD;
      float4 v = {0.f, 0.f, 0.f, 0.f};
      if (t >= 0 && t < len)
        v = *(const float4*)((spl ? xl : xh) + ((size_t)b * T + t) * CINP + ci0 + cg * 8);
      xs[(spl * 4 + cg) * STRIDE + row] = v;
    }
    __syncthreads();
    #pragma unroll
    for (int k = 0; k < K; ++k) {
      #pragma unroll
      for (int kh = 0; kh < 2; ++kh) {
        const int cg = kh * 2 + lk;
        bf16x8 ah[2], al[2], bh[3], bl[3];
        #pragma unroll
        for (int mf = 0; mf < 2; ++mf) {
          int row = wm * 64 + mf * 32 + lc + k;
          ah[mf] = *(const bf16x8*)&xs[cg * STRIDE + row];
          al[mf] = *(const bf16x8*)&xs[(4 + cg) * STRIDE + row];
        }
        size_t kd = (size_t)k * CINP + ci0 + cg * 8;
        #pragma unroll
        for (int nf = 0; nf < 3; ++nf) {
          int nc = n0 + wn * 96 + nf * 32 + lc;
          bh[nf] = *(const bf16x8*)(wh + (size_t)nc * KD + kd);
          bl[nf] = *(const bf16x8*)(wl + (size_t)nc * KD + kd);
        }
        // term-major: same-acc MFMAs are 6 apart
        #pragma unroll
        for (int nf = 0; nf < 3; ++nf)
          #pragma unroll
          for (int mf = 0; mf < 2; ++mf)
            acc[mf][nf] = mfma32(ah[mf], bh[nf], acc[mf][nf]);
        #pragma unroll
        for (int nf = 0; nf < 3; ++nf)
          #pragma unroll
          for (int mf = 0; mf < 2; ++mf)
            acc[mf][nf] = mfma32(ah[mf], bl[nf], acc[mf][nf]);
        #pragma unroll
        for (int nf = 0; nf < 3; ++nf)
          #pragma unroll
          for (int mf = 0; mf < 2; ++mf)
            acc[mf][nf] = mfma32(al[mf], bh[nf], acc[mf][nf]);
      }
    }
  }
  #pragma unroll
  for (int nf = 0; nf < 3; ++nf) {
    int c = n0 + wn * 96 + nf * 32 + lc;
    float bb = bias[c], aB = ab[c];
    #pragma unroll
    for (int mf = 0; mf < 2; ++mf) {
      #pragma unroll
      for (int r = 0; r < 16; ++r) {
        int t = t0 + wm * 64 + mf * 32 + (r & 3) + 8 * (r >> 2) + 4 * lk;
        if (t < T) {
          float v = acc[mf][nf][r] + bb;
          if (t >= len) v = 0.f;
          v += aB;
          if (STORET) out[((size_t)b * MAS + c) * T + t] = v;
          else        out[((size_t)b * T + t) * MAS + c] = v;
        }
      }
    }
  }
}

// ---------------- scores + softmax + safe_log ----------------
__global__ __launch_bounds__(512)
void scores_k(const float* __restrict__ q, const float* __restrict__ kT,
              const int* __restrict__ xl, const int* __restrict__ yl,
              float* __restrict__ oattn, float* __restrict__ ologp)
{
  __shared__ float qs[16 * 384];
  __shared__ float tmp[8];
  const int b = blockIdx.y, y0 = blockIdx.x * 16, tid = threadIdx.x;
  for (int e = tid; e < 16 * 384; e += 512)
    qs[e] = q[((size_t)b * TY + (y0 + e / 384)) * 384 + (e - (e / 384) * 384)];
  __syncthreads();
  float acc[16];
  #pragma unroll
  for (int i = 0; i < 16; ++i) acc[i] = 0.f;
  const int x = tid;
  if (x < TX) {
    const float* kb = kT + (size_t)b * MAS * TX + x;
    for (int d = 0; d < 384; d += 4) {
      float k0 = kb[(size_t)(d + 0) * TX], k1 = kb[(size_t)(d + 1) * TX];
      float k2 = kb[(size_t)(d + 2) * TX], k3 = kb[(size_t)(d + 3) * TX];
      #pragma unroll
      for (int yy = 0; yy < 16; ++yy) {
        float4 qv = *(const float4*)&qs[yy * 384 + d];
        acc[yy] = fmaf(qv.x, k0, fmaf(qv.y, k1, fmaf(qv.z, k2, fmaf(qv.w, k3, acc[yy]))));
      }
    }
  }
  const int xlen = xl[b], ylen = yl[b];
  const float scale = 0.05103103630798288f;
  const bool xpad = (x >= xlen);
  const int wv = tid >> 6, ln = tid & 63;
  #pragma unroll 1
  for (int yy = 0; yy < 16; ++yy) {
    int y = y0 + yy;
    float s = -3.0e38f;
    if (x < TX) {
      s = acc[yy] * scale;
      if (xpad && (y >= ylen)) s = -1e-9f;
    }
    float m = s;
    for (int off = 32; off; off >>= 1) m = fmaxf(m, __shfl_xor(m, off));
    if (ln == 0) tmp[wv] = m;
    __syncthreads();
    float mx = fmaxf(fmaxf(fmaxf(tmp[0], tmp[1]), fmaxf(tmp[2], tmp[3])),
                     fmaxf(fmaxf(tmp[4], tmp[5]), fmaxf(tmp[6], tmp[7])));
    __syncthreads();
    float e = (x < TX) ? expf(s - mx) : 0.f;
    float sm = e;
    for (int off = 32; off; off >>= 1) sm += __shfl_xor(sm, off);
    if (ln == 0) tmp[wv] = sm;
    __syncthreads();
    float tot = tmp[0] + tmp[1] + tmp[2] + tmp[3] + tmp[4] + tmp[5] + tmp[6] + tmp[7];
    __syncthreads();
    if (x < TX) {
      float w = e / tot;
      size_t o = ((size_t)b * TY + y) * TX + x;
      oattn[o] = w;
      ologp[o] = logf(w + 1e-6f);
    }
  }
}

// ---------------- MAS forward: 4-row blocked DP, halo windows ----------------
#define MAS_LD(blkv, buf) do {                                           \
    int base_ = (blkv) * 4;                                              \
    _Pragma("unroll")                                                    \
    for (int d_ = 0; d_ < 4; ++d_) {                                     \
      int yr_ = base_ + d_; if (yr_ > TY - 1) yr_ = TY - 1;              \
      const float* r_ = lpb + (size_t)yr_ * TX;                          \
      buf[d_ * 3 + 0] = *(const float4*)(r_ + lb0);                      \
      buf[d_ * 3 + 1] = *(const float4*)(r_ + lb1);                      \
      buf[d_ * 3 + 2] = *(const float4*)(r_ + lb2);                      \
    } } while (0)

#define MAS_BLK(blkv, buf) do {                                          \
    float h0 = __shfl_up(w[8], 1),  h1 = __shfl_up(w[9], 1);             \
    float h2 = __shfl_up(w[10], 1), h3 = __shfl_up(w[11], 1);            \
    w[0] = lane ? h0 : NEGV; w[1] = lane ? h1 : NEGV;                    \
    w[2] = lane ? h2 : NEGV; w[3] = lane ? h3 : NEGV;                    \
    const int y0_ = (blkv) * 4;                                          \
    const bool ph1_ = (y0_ < TX);                                        \
    _Pragma("unroll")                                                    \
    for (int d_ = 0; d_ < 4; ++d_) {                                     \
      const int y_ = y0_ + d_;                                           \
      float lp[12];                                                      \
      _Pragma("unroll")                                                  \
      for (int k_ = 0; k_ < 3; ++k_) {                                   \
        float4 v_ = buf[d_ * 3 + k_];                                    \
        lp[k_*4+0] = v_.x + wxm[k_*4+0]; lp[k_*4+1] = v_.y + wxm[k_*4+1];\
        lp[k_*4+2] = v_.z + wxm[k_*4+2]; lp[k_*4+3] = v_.w + wxm[k_*4+3];\
      }                                                                  \
      if (ph1_) {                                                        \
        int c_ = y_ - p0;                                                \
        _Pragma("unroll")                                                \
        for (int i_ = 0; i_ < 12; ++i_) lp[i_] = (i_ <= c_) ? lp[i_] : NEGV; \
      }                                                                  \
      unsigned byte_ = 0;                                                \
      _Pragma("unroll")                                                  \
      for (int j_ = 0; j_ < 8; ++j_)                                     \
        byte_ |= (w[j_ + 3] > w[j_ + 4]) ? (1u << j_) : 0u;              \
      float nw[12];                                                      \
      nw[0] = lp[0] + w[0];                                              \
      _Pragma("unroll")                                                  \
      for (int i_ = 1; i_ < 12; ++i_) nw[i_] = lp[i_] + fmaxf(w[i_], w[i_ - 1]); \
      bb[(size_t)y_ * 64 + lane] = (unsigned char)byte_;                 \
      _Pragma("unroll")                                                  \
      for (int i_ = 0; i_ < 12; ++i_) w[i_] = nw[i_];                    \
    } } while (0)

__global__ __launch_bounds__(64)
void mas_fwd(const float* __restrict__ logprob, const int* __restrict__ xl,
             const int* __restrict__ yl, unsigned char* __restrict__ bits)
{
  const int b = blockIdx.x;
  const int lane = threadIdx.x;
  const int xlen = xl[b], ylen = yl[b];
  const float* lpb = logprob + (size_t)b * TY * TX;
  unsigned char* bb = bits + (size_t)b * TY * 64;
  const int p0 = lane * 8 - 4;
  int t;
  t = p0;     if (t < 0) t = 0; if (t > 396) t = 396; const int lb0 = t;
  t = p0 + 4; if (t < 0) t = 0; if (t > 396) t = 396; const int lb1 = t;
  t = p0 + 8; if (t < 0) t = 0; if (t > 396) t = 396; const int lb2 = t;

  float w[12], wxm[12];
  #pragma unroll
  for (int i = 0; i < 12; ++i) {
    int p = p0 + i;
    wxm[i] = (p >= 0 && p < xlen) ? 0.f : NEGV;
    w[i] = (p == 0) ? 0.f : NEGV;
  }

  float4 bufA[12], bufB[12];
  MAS_LD(0, bufA);
  MAS_LD(1, bufB);
  const int nblk = (ylen + 3) >> 2;
  int blk = 0;
  #pragma unroll 1
  for (; blk + 1 < nblk; blk += 2) {
    MAS_BLK(blk, bufA);
    MAS_LD(blk + 2, bufA);
    MAS_BLK(blk + 1, bufB);
    MAS_LD(blk + 3, bufB);
  }
  if (blk < nblk) MAS_BLK(blk, bufA);
}

// ---------------- MAS backtrack: uniform scalar walk via readlane ----------------
__global__ __launch_bounds__(64)
void mas_bt(const unsigned char* __restrict__ bits, const int* __restrict__ xl,
            const int* __restrict__ yl, float* __restrict__ hard, float* __restrict__ dur)
{
  const int b = blockIdx.x;
  const int lane = threadIdx.x;
  const int xlen = xl[b], ylen = yl[b];
  const unsigned char* bb = bits + (size_t)b * TY * 64;
  float* hb = hard + (size_t)b * TX * TY;
  float* db = dur + (size_t)b * TX;

  int x = xlen - 1;
  int cnt = 0;
  #pragma unroll 1
  for (int ycur = ylen - 1; ycur >= 0; ycur -= 64) {
    int lo = x - 63; if (lo < 0) lo = 0;
    const int wb = (lo >> 3) & ~3;
    int ry = ycur - lane;
    unsigned w0 = 0, w1 = 0, w2 = 0;
    if (ry >= 0) {
      const unsigned* rp = (const unsigned*)(bb + (size_t)ry * 64 + wb);
      w0 = rp[0]; w1 = rp[1]; w2 = rp[2];
    }
    const int rows = (ycur + 1 < 64) ? (ycur + 1) : 64;
    #pragma unroll 1
    for (int s = 0; s < rows; s += 8) {
      const int cnt8 = (rows - s < 8) ? (rows - s) : 8;
      unsigned r0[8], r1[8], r2[8];
      #pragma unroll
      for (int u = 0; u < 8; ++u) {
        r0[u] = (unsigned)__builtin_amdgcn_readlane((int)w0, s + u);
        r1[u] = (unsigned)__builtin_amdgcn_readlane((int)w1, s + u);
        r2[u] = (unsigned)__builtin_amdgcn_readlane((int)w2, s + u);
      }
      #pragma unroll
      for (int u = 0; u < 8; ++u) {
        if (u < cnt8) {
          const int yy = ycur - s - u;
          ++cnt;
          if (yy > 0 && x > 0) {
            const int boff = (x >> 3) - wb;
            const unsigned word = (boff < 4) ? r0[u] : ((boff < 8) ? r1[u] : r2[u]);
            const unsigned byte = word >> ((boff & 3) * 8);
            if ((x == yy) || ((byte >> (x & 7)) & 1)) {
              for (int q = lane; q < cnt; q += 64) hb[(size_t)x * TY + yy + q] = 1.0f;
              if (lane == 0) db[x] = (float)cnt;
              cnt = 0;
              --x;
            }
          }
        }
      }
    }
  }
  for (int q = lane; q < cnt; q += 64) hb[(size_t)x * TY + q] = 1.0f;
  if (lane == 0) db[x] = (float)cnt;
}

extern "C" void kernel_launch(void* const* d_in, const int* in_sizes, int n_in,
                              void* d_out, int out_size, void* d_ws, size_t ws_size,
                              hipStream_t stream) {
  const float* mel_x  = (const float*)d_in[0];
  const float* txt_x  = (const float*)d_in[1];
  const float* mel_w1 = (const float*)d_in[2];
  const float* mel_b1 = (const float*)d_in[3];
  const float* mel_w2 = (const float*)d_in[4];
  const float* mel_b2 = (const float*)d_in[5];
  const float* txt_w1 = (const float*)d_in[6];
  const float* txt_b1 = (const float*)d_in[7];
  const float* txt_w2 = (const float*)d_in[8];
  const float* txt_b2 = (const float*)d_in[9];
  const float* wq     = (const float*)d_in[10];
  const float* bq     = (const float*)d_in[11];
  const float* wk     = (const float*)d_in[12];
  const float* bk     = (const float*)d_in[13];
  const int*   xl     = (const int*)d_in[14];
  const int*   yl     = (const int*)d_in[15];

  char* wsb = (char*)d_ws;
  constexpr size_t MXH   = 0;
  constexpr size_t MXL   = MXH   + 4915200;
  constexpr size_t TXH   = MXL   + 4915200;
  constexpr size_t TXL   = TXH   + 6553600;
  constexpr size_t KTF   = TXH;
  constexpr size_t WFMH  = TXL   + 6553600;
  constexpr size_t WFML  = WFMH  + 2949120;
  constexpr size_t WFTH  = WFML  + 2949120;
  constexpr size_t WFTL  = WFTH  + 1769472;
  constexpr size_t B2M   = WFTL  + 1769472;
  constexpr size_t B2T   = B2M   + 2048;
  constexpr size_t HH    = B2T   + 2048;
  constexpr size_t HL    = HH    + 39321600;
  constexpr size_t BITS  = MXH;
  constexpr size_t SCR   = HL    + 39321600;
  constexpr size_t W1MH  = SCR;
  constexpr size_t W1ML  = W1MH  + 1474560;
  constexpr size_t W1TH  = W1ML  + 1474560;
  constexpr size_t W1TL  = W1TH  + 4718592;
  constexpr size_t WQH   = W1TL  + 4718592;
  constexpr size_t WQL   = WQH   + 294912;
  constexpr size_t WKH   = WQL   + 294912;
  constexpr size_t WKL   = WKH   + 294912;
  constexpr size_t W2TMH = WKL   + 294912;
  constexpr size_t W2TML = W2TMH + 2949120;
  constexpr size_t W2TTH = W2TML + 2949120;
  constexpr size_t W2TTL = W2TTH + 1769472;
  constexpr size_t QF    = SCR;

  float* out = (float*)d_out;
  float* o_attn = out;
  float* o_logp = out + (size_t)10240000;
  float* o_hard = out + (size_t)20480000;
  float* o_dur  = out + (size_t)30720000;

  hipMemsetAsync(o_hard, 0, (size_t)(10240000 + 6400) * sizeof(float), stream);

  split_pad_k<<<9600, 256, 0, stream>>>(mel_x, (__bf16*)(wsb + MXH), (__bf16*)(wsb + MXL), 80, 96, 2457600L);
  split_pad_k<<<12800, 256, 0, stream>>>(txt_x, (__bf16*)(wsb + TXH), (__bf16*)(wsb + TXL), 512, 512, 3276800L);
  wsplit_k<<<2880, 256, 0, stream>>>(mel_w1, (__bf16*)(wsb + W1MH), (__bf16*)(wsb + W1ML), 80, 5, 96, 737280L);
  wsplit_k<<<9216, 256, 0, stream>>>(txt_w1, (__bf16*)(wsb + W1TH), (__bf16*)(wsb + W1TL), 512, 3, 512, 2359296L);
  wsplit_k<<<576, 256, 0, stream>>>(wq, (__bf16*)(wsb + WQH), (__bf16*)(wsb + WQL), 384, 1, 384, 147456L);
  wsplit_k<<<576, 256, 0, stream>>>(wk, (__bf16*)(wsb + WKH), (__bf16*)(wsb + WKL), 384, 1, 384, 147456L);
  tsplit_k<<<5760, 256, 0, stream>>>(mel_w2, (__bf16*)(wsb + W2TMH), (__bf16*)(wsb + W2TML), 3840, 1474560L);
  tsplit_k<<<3456, 256, 0, stream>>>(txt_w2, (__bf16*)(wsb + W2TTH), (__bf16*)(wsb + W2TTL), 2304, 884736L);
  fold_mfma<5><<<dim3(60, 3), 256, 0, stream>>>(
      (const __bf16*)(wsb + W2TMH), (const __bf16*)(wsb + W2TML),
      (const __bf16*)(wsb + WQH), (const __bf16*)(wsb + WQL),
      (__bf16*)(wsb + WFMH), (__bf16*)(wsb + WFML));
  fold_mfma<3><<<dim3(36, 3), 256, 0, stream>>>(
      (const __bf16*)(wsb + W2TTH), (const __bf16*)(wsb + W2TTL),
      (const __bf16*)(wsb + WKH), (const __bf16*)(wsb + WKL),
      (__bf16*)(wsb + WFTH), (__bf16*)(wsb + WFTL));
  fold_bias_k<<<1, 384, 0, stream>>>(wq, mel_b2, (float*)(wsb + B2M));
  fold_bias_k<<<1, 384, 0, stream>>>(wk, txt_b2, (float*)(wsb + B2T));

  // text pipeline: conv1 -> conv2(folded) writes kT directly
  conv1_mfma<512, 3, 400><<<dim3(4, 12, B), 256, 0, stream>>>(
      (const __bf16*)(wsb + TXH), (const __bf16*)(wsb + TXL),
      (const __bf16*)(wsb + W1TH), (const __bf16*)(wsb + W1TL),
      txt_b1, xl, (__bf16*)(wsb + HH), (__bf16*)(wsb + HL));
  conv2_mfma<768, 3, 400, true><<<dim3(4, 2, B), 256, 0, stream>>>(
      (const __bf16*)(wsb + HH), (const __bf16*)(wsb + HL),
      (const __bf16*)(wsb + WFTH), (const __bf16*)(wsb + WFTL),
      (const float*)(wsb + B2T), bk, xl, (float*)(wsb + KTF));

  // mel pipeline: conv1 -> conv2(folded) writes q directly
  conv1_mfma<96, 5, 1600><<<dim3(13, 12, B), 256, 0, stream>>>(
      (const __bf16*)(wsb + MXH), (const __bf16*)(wsb + MXL),
      (const __bf16*)(wsb + W1MH), (const __bf16*)(wsb + W1ML),
      mel_b1, yl, (__bf16*)(wsb + HH), (__bf16*)(wsb + HL));
  conv2_mfma<768, 5, 1600, false><<<dim3(13, 2, B), 256, 0, stream>>>(
      (const __bf16*)(wsb + HH), (const __bf16*)(wsb + HL),
      (const __bf16*)(wsb + WFMH), (const __bf16*)(wsb + WFML),
      (const float*)(wsb + B2M), bq, yl, (float*)(wsb + QF));

  // attention + MAS
  scores_k<<<dim3(100, B), 512, 0, stream>>>(
      (const float*)(wsb + QF), (const float*)(wsb + KTF), xl, yl, o_attn, o_logp);
  mas_fwd<<<B, 64, 0, stream>>>(o_logp, xl, yl, (unsigned char*)(wsb + BITS));
  mas_bt<<<B, 64, 0, stream>>>((const unsigned char*)(wsb + BITS), xl, yl, o_hard, o_dur);
}

// Round 11
// 1574.021 us; speedup vs baseline: 1.1933x; 1.1933x over previous
//
#include <hip/hip_runtime.h>
#include <cstdint>

#define B 16
#define TY 1600
#define TX 400
#define MAS 384
#define HID 768
#define NEGV -1e9f

typedef __bf16 bf16x8 __attribute__((ext_vector_type(8)));
typedef float  f32x4  __attribute__((ext_vector_type(4)));
typedef float  f32x16 __attribute__((ext_vector_type(16)));

__device__ __forceinline__ f32x4 mfma16(bf16x8 a, bf16x8 b, f32x4 c) {
  return __builtin_amdgcn_mfma_f32_16x16x32_bf16(a, b, c, 0, 0, 0);
}
__device__ __forceinline__ f32x16 mfma32(bf16x8 a, bf16x8 b, f32x16 c) {
  return __builtin_amdgcn_mfma_f32_32x32x16_bf16(a, b, c, 0, 0, 0);
}

// ---------------- fp32 -> bf16 hi/lo split with channel padding ----------------
__global__ void split_pad_k(const float* __restrict__ in, __bf16* __restrict__ oh,
                            __bf16* __restrict__ ol, int CIN, int CINP, long n) {
  long i = (long)blockIdx.x * 256 + threadIdx.x;
  if (i >= n) return;
  long row = i / CINP; int ci = (int)(i - row * CINP);
  float v = (ci < CIN) ? in[row * CIN + ci] : 0.f;
  __bf16 h = (__bf16)v;
  oh[i] = h; ol[i] = (__bf16)(v - (float)h);
}

// ---------------- weight repack+split: w[N][CIN][K] -> oh/ol[N][k*CINP + ci] ----------------
__global__ void wsplit_k(const float* __restrict__ w, __bf16* __restrict__ oh,
                         __bf16* __restrict__ ol, int CIN, int K_, int CINP, long n) {
  long i = (long)blockIdx.x * 256 + threadIdx.x;
  if (i >= n) return;
  long kdspan = (long)K_ * CINP;
  long nn = i / kdspan; int kd = (int)(i - nn * kdspan);
  int k = kd / CINP, ci = kd - k * CINP;
  float v = (ci < CIN) ? w[(nn * CIN + ci) * K_ + k] : 0.f;
  __bf16 h = (__bf16)v;
  oh[i] = h; ol[i] = (__bf16)(v - (float)h);
}

// ---------------- transpose+split: w2 [m][JTOT] -> oh/ol [j][384] ----------------
__global__ void tsplit_k(const float* __restrict__ in, __bf16* __restrict__ oh,
                         __bf16* __restrict__ ol, int JTOT, long n) {
  long i = (long)blockIdx.x * 256 + threadIdx.x;
  if (i >= n) return;
  int m = (int)(i / JTOT), j = (int)(i - (long)m * JTOT);
  float v = in[i];
  long o = (long)j * 384 + m;
  __bf16 h = (__bf16)v;
  oh[o] = h; ol[o] = (__bf16)(v - (float)h);
}

// ---------------- bias fold: o[n] = sum_m wq[n][m] * b[m] ----------------
__global__ void fold_bias_k(const float* __restrict__ wq, const float* __restrict__ b,
                            float* __restrict__ o) {
  int n = threadIdx.x;
  float s = 0.f;
  for (int m = 0; m < 384; ++m) s = fmaf(wq[n * 384 + m], b[m], s);
  o[n] = s;
}

// ---------------- weight-fold GEMM ----------------
// Output layout is conv2-staging-native:
//   WF[((ci>>4)*KK + k)*2 + ((ci>>3)&1)][384 cols][8 ci-elems]  (bf16, hi/lo buffers)
template<int KK>
__global__ __launch_bounds__(256)
void fold_mfma(const __bf16* __restrict__ xh, const __bf16* __restrict__ xl,
               const __bf16* __restrict__ wh, const __bf16* __restrict__ wl,
               __bf16* __restrict__ oh, __bf16* __restrict__ ol)
{
  constexpr int CINP = 384, ROWS = 64, STRIDE = 65;
  __shared__ float4 xs[8 * STRIDE];
  const int t0 = blockIdx.x * 64, n0 = blockIdx.y * 128;
  const int tid = threadIdx.x, wn = tid >> 6, lane = tid & 63;
  const int lr = lane & 15, lg = lane >> 4;
  const f32x4 Z4 = {0.f, 0.f, 0.f, 0.f};
  f32x4 acc[4][2];
  #pragma unroll
  for (int m = 0; m < 4; ++m) { acc[m][0] = Z4; acc[m][1] = Z4; }

  #pragma unroll 1
  for (int ci0 = 0; ci0 < CINP; ci0 += 32) {
    __syncthreads();
    for (int e = tid; e < ROWS * 8; e += 256) {
      int row = e >> 3, sc = e & 7, spl = sc >> 2, cg = sc & 3;
      int t = t0 + row;
      xs[(spl * 4 + cg) * STRIDE + row] =
          *(const float4*)((spl ? xl : xh) + (size_t)t * CINP + ci0 + cg * 8);
    }
    __syncthreads();
    bf16x8 ah[4], al[4];
    #pragma unroll
    for (int mf = 0; mf < 4; ++mf) {
      int row = mf * 16 + lr;
      ah[mf] = *(const bf16x8*)&xs[lg * STRIDE + row];
      al[mf] = *(const bf16x8*)&xs[(4 + lg) * STRIDE + row];
    }
    size_t kd = (size_t)ci0 + lg * 8;
    bf16x8 bh[2], bl[2];
    #pragma unroll
    for (int nf = 0; nf < 2; ++nf) {
      int nc = n0 + wn * 32 + nf * 16 + lr;
      bh[nf] = *(const bf16x8*)(wh + (size_t)nc * 384 + kd);
      bl[nf] = *(const bf16x8*)(wl + (size_t)nc * 384 + kd);
    }
    #pragma unroll
    for (int nf = 0; nf < 2; ++nf)
      #pragma unroll
      for (int mf = 0; mf < 4; ++mf) acc[mf][nf] = mfma16(ah[mf], bh[nf], acc[mf][nf]);
    #pragma unroll
    for (int nf = 0; nf < 2; ++nf)
      #pragma unroll
      for (int mf = 0; mf < 4; ++mf) acc[mf][nf] = mfma16(ah[mf], bl[nf], acc[mf][nf]);
    #pragma unroll
    for (int nf = 0; nf < 2; ++nf)
      #pragma unroll
      for (int mf = 0; mf < 4; ++mf) acc[mf][nf] = mfma16(al[mf], bh[nf], acc[mf][nf]);
  }
  #pragma unroll
  for (int nf = 0; nf < 2; ++nf) {
    int c = n0 + wn * 32 + nf * 16 + lr;
    #pragma unroll
    for (int mf = 0; mf < 4; ++mf) {
      #pragma unroll
      for (int r = 0; r < 4; ++r) {
        int j = t0 + mf * 16 + lg * 4 + r;   // j = ci*KK + k
        int k = j % KK, ci = j / KK;
        size_t o = (size_t)((((ci >> 4) * KK + k) * 2 + ((ci >> 3) & 1)) * 3072)
                 + (size_t)c * 8 + (ci & 7);
        float v = acc[mf][nf][r];
        __bf16 vh = (__bf16)v;
        oh[o] = vh; ol[o] = (__bf16)(v - (float)vh);
      }
    }
  }
}

// ---------------- conv1 + ReGLU, split-bf16 MFMA (R9 ordering) ----------------
template<int CINP, int K, int T>
__global__ __launch_bounds__(256)
void conv1_mfma(const __bf16* __restrict__ xh, const __bf16* __restrict__ xl,
                const __bf16* __restrict__ wh, const __bf16* __restrict__ wl,
                const float* __restrict__ bias, const int* __restrict__ lens,
                __bf16* __restrict__ hh, __bf16* __restrict__ hl)
{
  constexpr int BM = 128, PAD = K / 2, ROWS = BM + K - 1, KD = K * CINP;
  __shared__ float4 xs[8 * ROWS];
  const int b = blockIdx.z, t0 = blockIdx.x * BM, n0 = blockIdx.y * 64;
  const int tid = threadIdx.x, wid = tid >> 6, lane = tid & 63;
  const int wm = wid >> 1, wn = wid & 1, lr = lane & 15, lg = lane >> 4;
  const int len = lens[b];
  const f32x4 Z4 = {0.f, 0.f, 0.f, 0.f};
  f32x4 acc_a[4][2], acc_g[4][2];
  #pragma unroll
  for (int m = 0; m < 4; ++m)
    #pragma unroll
    for (int n = 0; n < 2; ++n) { acc_a[m][n] = Z4; acc_g[m][n] = Z4; }

  #pragma unroll 1
  for (int ci0 = 0; ci0 < CINP; ci0 += 32) {
    __syncthreads();
    for (int e = tid; e < ROWS * 8; e += 256) {
      int row = e >> 3, sc = e & 7, spl = sc >> 2, cg = sc & 3;
      int t = t0 + row - PAD;
      float4 v = {0.f, 0.f, 0.f, 0.f};
      if (t >= 0 && t < len)
        v = *(const float4*)((spl ? xl : xh) + ((size_t)b * T + t) * CINP + ci0 + cg * 8);
      xs[(spl * 4 + cg) * ROWS + row] = v;
    }
    __syncthreads();
    #pragma unroll
    for (int k = 0; k < K; ++k) {
      bf16x8 ah[4], al[4];
      #pragma unroll
      for (int mf = 0; mf < 4; ++mf) {
        int row = wm * 64 + mf * 16 + lr + k;
        ah[mf] = *(const bf16x8*)&xs[lg * ROWS + row];
        al[mf] = *(const bf16x8*)&xs[(4 + lg) * ROWS + row];
      }
      size_t kd = (size_t)k * CINP + ci0 + lg * 8;
      #pragma unroll
      for (int nf = 0; nf < 2; ++nf) {
        int na = n0 + wn * 32 + nf * 16 + lr;
        bf16x8 bah = *(const bf16x8*)(wh + (size_t)na * KD + kd);
        bf16x8 bal = *(const bf16x8*)(wl + (size_t)na * KD + kd);
        bf16x8 bgh = *(const bf16x8*)(wh + (size_t)(na + HID) * KD + kd);
        bf16x8 bgl = *(const bf16x8*)(wl + (size_t)(na + HID) * KD + kd);
        #pragma unroll
        for (int mf = 0; mf < 4; ++mf) {
          acc_a[mf][nf] = mfma16(ah[mf], bah, acc_a[mf][nf]);
          acc_a[mf][nf] = mfma16(ah[mf], bal, acc_a[mf][nf]);
          acc_a[mf][nf] = mfma16(al[mf], bah, acc_a[mf][nf]);
          acc_g[mf][nf] = mfma16(ah[mf], bgh, acc_g[mf][nf]);
          acc_g[mf][nf] = mfma16(ah[mf], bgl, acc_g[mf][nf]);
          acc_g[mf][nf] = mfma16(al[mf], bgh, acc_g[mf][nf]);
        }
      }
    }
  }
  #pragma unroll
  for (int nf = 0; nf < 2; ++nf) {
    int c = n0 + wn * 32 + nf * 16 + lr;
    float ba = bias[c], bg = bias[c + HID];
    #pragma unroll
    for (int mf = 0; mf < 4; ++mf) {
      #pragma unroll
      for (int r = 0; r < 4; ++r) {
        int t = t0 + wm * 64 + mf * 16 + lg * 4 + r;
        if (t < T) {
          float a = acc_a[mf][nf][r] + ba;
          float g = acc_g[mf][nf][r] + bg;
          float v = a * fmaxf(g, 0.f);
          __bf16 vh = (__bf16)v;
          size_t o = ((size_t)b * T + t) * HID + c;
          hh[o] = vh;
          hl[o] = (__bf16)(v - (float)vh);
        }
      }
    }
  }
}

// ---------------- conv2 (folded weights), 32x32x16, B staged in LDS via global_load_lds ----------------
// 256 thr (4 waves 2m x 2n), BM=128, BN=192; 48 steps of 16 ci.
// A: xa[spl2][cg2][row] float4.  B: bs[spl][k][cg][192 cols] float4 (3KB contiguous rows).
template<int K, int T, bool STORET>
__global__ __launch_bounds__(256)
void conv2_mfma(const __bf16* __restrict__ xh, const __bf16* __restrict__ xl,
                const __bf16* __restrict__ wh, const __bf16* __restrict__ wl,
                const float* __restrict__ bias, const float* __restrict__ ab,
                const int* __restrict__ lens, float* __restrict__ out)
{
  constexpr int CINP = 768, BM = 128, PAD = K / 2, ROWS = BM + K - 1, STRIDE = ROWS + 1;
  constexpr int BROWS = K * 2;                 // per-split rows: K taps x 2 cg
  __shared__ float4 xa[4 * STRIDE];
  __shared__ float4 bs[2 * BROWS * 192];
  const int b = blockIdx.z, t0 = blockIdx.x * BM, n0 = blockIdx.y * 192;
  const int tid = threadIdx.x, wid = tid >> 6, lane = tid & 63;
  const int wm = wid >> 1, wn = wid & 1, lc = lane & 31, lk = lane >> 5;
  const int len = lens[b];
  f32x16 acc[2][3];
  #pragma unroll
  for (int m = 0; m < 2; ++m)
    #pragma unroll
    for (int n = 0; n < 3; ++n)
      #pragma unroll
      for (int r = 0; r < 16; ++r) acc[m][n][r] = 0.f;

  #pragma unroll 1
  for (int s = 0; s < 48; ++s) {
    __syncthreads();
    // stage A (16 ci): registers path, boundary-masked
    for (int e = tid; e < ROWS * 4; e += 256) {
      int row = e >> 2, sc = e & 3, spl = sc >> 1, cg = sc & 1;
      int t = t0 + row - PAD;
      float4 v = {0.f, 0.f, 0.f, 0.f};
      if (t >= 0 && t < len)
        v = *(const float4*)((spl ? xl : xh) + ((size_t)b * T + t) * CINP + s * 16 + cg * 8);
      xa[(spl * 2 + cg) * STRIDE + row] = v;
    }
    // stage B: contiguous 3KB rows via async global_load_lds (wave-uniform dst + lane*16)
    for (int r = wid; r < 2 * BROWS; r += 4) {
      int spl = r / BROWS, rr = r - spl * BROWS;
      const char* src = (const char*)((spl ? wl : wh) + (size_t)(s * BROWS + rr) * 3072
                                      + (size_t)n0 * 8) + (size_t)lane * 16;
      char* dst = (char*)&bs[r * 192];
      #pragma unroll
      for (int i = 0; i < 3; ++i)
        __builtin_amdgcn_global_load_lds(
            (const __attribute__((address_space(1))) void*)(src + i * 1024),
            (__attribute__((address_space(3))) void*)(dst + i * 1024), 16, 0, 0);
    }
    __syncthreads();
    #pragma unroll
    for (int k = 0; k < K; ++k) {
      bf16x8 ah[2], al[2], bh[3], bl[3];
      #pragma unroll
      for (int mf = 0; mf < 2; ++mf) {
        int row = wm * 64 + mf * 32 + lc + k;
        ah[mf] = *(const bf16x8*)&xa[lk * STRIDE + row];
        al[mf] = *(const bf16x8*)&xa[(2 + lk) * STRIDE + row];
      }
      #pragma unroll
      for (int nf = 0; nf < 3; ++nf) {
        int col = wn * 96 + nf * 32 + lc;
        bh[nf] = *(const bf16x8*)&bs[(k * 2 + lk) * 192 + col];
        bl[nf] = *(const bf16x8*)&bs[(BROWS + k * 2 + lk) * 192 + col];
      }
      #pragma unroll
      for (int nf = 0; nf < 3; ++nf)
        #pragma unroll
        for (int mf = 0; mf < 2; ++mf)
          acc[mf][nf] = mfma32(ah[mf], bh[nf], acc[mf][nf]);
      #pragma unroll
      for (int nf = 0; nf < 3; ++nf)
        #pragma unroll
        for (int mf = 0; mf < 2; ++mf)
          acc[mf][nf] = mfma32(ah[mf], bl[nf], acc[mf][nf]);
      #pragma unroll
      for (int nf = 0; nf < 3; ++nf)
        #pragma unroll
        for (int mf = 0; mf < 2; ++mf)
          acc[mf][nf] = mfma32(al[mf], bh[nf], acc[mf][nf]);
    }
  }
  #pragma unroll
  for (int nf = 0; nf < 3; ++nf) {
    int c = n0 + wn * 96 + nf * 32 + lc;
    float bb = bias[c], aB = ab[c];
    #pragma unroll
    for (int mf = 0; mf < 2; ++mf) {
      #pragma unroll
      for (int r = 0; r < 16; ++r) {
        int t = t0 + wm * 64 + mf * 32 + (r & 3) + 8 * (r >> 2) + 4 * lk;
        if (t < T) {
          float v = acc[mf][nf][r] + bb;
          if (t >= len) v = 0.f;
          v += aB;
          if (STORET) out[((size_t)b * MAS + c) * T + t] = v;
          else        out[((size_t)b * T + t) * MAS + c] = v;
        }
      }
    }
  }
}

// ---------------- scores + softmax + safe_log ----------------
__global__ __launch_bounds__(512)
void scores_k(const float* __restrict__ q, const float* __restrict__ kT,
              const int* __restrict__ xl, const int* __restrict__ yl,
              float* __restrict__ oattn, float* __restrict__ ologp)
{
  __shared__ float qs[16 * 384];
  __shared__ float tmp[8];
  const int b = blockIdx.y, y0 = blockIdx.x * 16, tid = threadIdx.x;
  for (int e = tid; e < 16 * 384; e += 512)
    qs[e] = q[((size_t)b * TY + (y0 + e / 384)) * 384 + (e - (e / 384) * 384)];
  __syncthreads();
  float acc[16];
  #pragma unroll
  for (int i = 0; i < 16; ++i) acc[i] = 0.f;
  const int x = tid;
  if (x < TX) {
    const float* kb = kT + (size_t)b * MAS * TX + x;
    for (int d = 0; d < 384; d += 4) {
      float k0 = kb[(size_t)(d + 0) * TX], k1 = kb[(size_t)(d + 1) * TX];
      float k2 = kb[(size_t)(d + 2) * TX], k3 = kb[(size_t)(d + 3) * TX];
      #pragma unroll
      for (int yy = 0; yy < 16; ++yy) {
        float4 qv = *(const float4*)&qs[yy * 384 + d];
        acc[yy] = fmaf(qv.x, k0, fmaf(qv.y, k1, fmaf(qv.z, k2, fmaf(qv.w, k3, acc[yy]))));
      }
    }
  }
  const int xlen = xl[b], ylen = yl[b];
  const float scale = 0.05103103630798288f;
  const bool xpad = (x >= xlen);
  const int wv = tid >> 6, ln = tid & 63;
  #pragma unroll 1
  for (int yy = 0; yy < 16; ++yy) {
    int y = y0 + yy;
    float s = -3.0e38f;
    if (x < TX) {
      s = acc[yy] * scale;
      if (xpad && (y >= ylen)) s = -1e-9f;
    }
    float m = s;
    for (int off = 32; off; off >>= 1) m = fmaxf(m, __shfl_xor(m, off));
    if (ln == 0) tmp[wv] = m;
    __syncthreads();
    float mx = fmaxf(fmaxf(fmaxf(tmp[0], tmp[1]), fmaxf(tmp[2], tmp[3])),
                     fmaxf(fmaxf(tmp[4], tmp[5]), fmaxf(tmp[6], tmp[7])));
    __syncthreads();
    float e = (x < TX) ? expf(s - mx) : 0.f;
    float sm = e;
    for (int off = 32; off; off >>= 1) sm += __shfl_xor(sm, off);
    if (ln == 0) tmp[wv] = sm;
    __syncthreads();
    float tot = tmp[0] + tmp[1] + tmp[2] + tmp[3] + tmp[4] + tmp[5] + tmp[6] + tmp[7];
    __syncthreads();
    if (x < TX) {
      float w = e / tot;
      size_t o = ((size_t)b * TY + y) * TX + x;
      oattn[o] = w;
      ologp[o] = logf(w + 1e-6f);
    }
  }
}

// ---------------- MAS forward: 4-row blocked DP, halo windows ----------------
#define MAS_LD(blkv, buf) do {                                           \
    int base_ = (blkv) * 4;                                              \
    _Pragma("unroll")                                                    \
    for (int d_ = 0; d_ < 4; ++d_) {                                     \
      int yr_ = base_ + d_; if (yr_ > TY - 1) yr_ = TY - 1;              \
      const float* r_ = lpb + (size_t)yr_ * TX;                          \
      buf[d_ * 3 + 0] = *(const float4*)(r_ + lb0);                      \
      buf[d_ * 3 + 1] = *(const float4*)(r_ + lb1);                      \
      buf[d_ * 3 + 2] = *(const float4*)(r_ + lb2);                      \
    } } while (0)

#define MAS_BLK(blkv, buf) do {                                          \
    float h0 = __shfl_up(w[8], 1),  h1 = __shfl_up(w[9], 1);             \
    float h2 = __shfl_up(w[10], 1), h3 = __shfl_up(w[11], 1);            \
    w[0] = lane ? h0 : NEGV; w[1] = lane ? h1 : NEGV;                    \
    w[2] = lane ? h2 : NEGV; w[3] = lane ? h3 : NEGV;                    \
    const int y0_ = (blkv) * 4;                                          \
    const bool ph1_ = (y0_ < TX);                                        \
    _Pragma("unroll")                                                    \
    for (int d_ = 0; d_ < 4; ++d_) {                                     \
      const int y_ = y0_ + d_;                                           \
      float lp[12];                                                      \
      _Pragma("unroll")                                                  \
      for (int k_ = 0; k_ < 3; ++k_) {                                   \
        float4 v_ = buf[d_ * 3 + k_];                                    \
        lp[k_*4+0] = v_.x + wxm[k_*4+0]; lp[k_*4+1] = v_.y + wxm[k_*4+1];\
        lp[k_*4+2] = v_.z + wxm[k_*4+2]; lp[k_*4+3] = v_.w + wxm[k_*4+3];\
      }                                                                  \
      if (ph1_) {                                                        \
        int c_ = y_ - p0;                                                \
        _Pragma("unroll")                                                \
        for (int i_ = 0; i_ < 12; ++i_) lp[i_] = (i_ <= c_) ? lp[i_] : NEGV; \
      }                                                                  \
      unsigned byte_ = 0;                                                \
      _Pragma("unroll")                                                  \
      for (int j_ = 0; j_ < 8; ++j_)                                     \
        byte_ |= (w[j_ + 3] > w[j_ + 4]) ? (1u << j_) : 0u;              \
      float nw[12];                                                      \
      nw[0] = lp[0] + w[0];                                              \
      _Pragma("unroll")                                                  \
      for (int i_ = 1; i_ < 12; ++i_) nw[i_] = lp[i_] + fmaxf(w[i_], w[i_ - 1]); \
      bb[(size_t)y_ * 64 + lane] = (unsigned char)byte_;                 \
      _Pragma("unroll")                                                  \
      for (int i_ = 0; i_ < 12; ++i_) w[i_] = nw[i_];                    \
    } } while (0)

__global__ __launch_bounds__(64)
void mas_fwd(const float* __restrict__ logprob, const int* __restrict__ xl,
             const int* __restrict__ yl, unsigned char* __restrict__ bits)
{
  const int b = blockIdx.x;
  const int lane = threadIdx.x;
  const int xlen = xl[b], ylen = yl[b];
  const float* lpb = logprob + (size_t)b * TY * TX;
  unsigned char* bb = bits + (size_t)b * TY * 64;
  const int p0 = lane * 8 - 4;
  int t;
  t = p0;     if (t < 0) t = 0; if (t > 396) t = 396; const int lb0 = t;
  t = p0 + 4; if (t < 0) t = 0; if (t > 396) t = 396; const int lb1 = t;
  t = p0 + 8; if (t < 0) t = 0; if (t > 396) t = 396; const int lb2 = t;

  float w[12], wxm[12];
  #pragma unroll
  for (int i = 0; i < 12; ++i) {
    int p = p0 + i;
    wxm[i] = (p >= 0 && p < xlen) ? 0.f : NEGV;
    w[i] = (p == 0) ? 0.f : NEGV;
  }

  float4 bufA[12], bufB[12];
  MAS_LD(0, bufA);
  MAS_LD(1, bufB);
  const int nblk = (ylen + 3) >> 2;
  int blk = 0;
  #pragma unroll 1
  for (; blk + 1 < nblk; blk += 2) {
    MAS_BLK(blk, bufA);
    MAS_LD(blk + 2, bufA);
    MAS_BLK(blk + 1, bufB);
    MAS_LD(blk + 3, bufB);
  }
  if (blk < nblk) MAS_BLK(blk, bufA);
}

// ---------------- MAS backtrack: uniform scalar walk via readlane ----------------
__global__ __launch_bounds__(64)
void mas_bt(const unsigned char* __restrict__ bits, const int* __restrict__ xl,
            const int* __restrict__ yl, float* __restrict__ hard, float* __restrict__ dur)
{
  const int b = blockIdx.x;
  const int lane = threadIdx.x;
  const int xlen = xl[b], ylen = yl[b];
  const unsigned char* bb = bits + (size_t)b * TY * 64;
  float* hb = hard + (size_t)b * TX * TY;
  float* db = dur + (size_t)b * TX;

  int x = xlen - 1;
  int cnt = 0;
  #pragma unroll 1
  for (int ycur = ylen - 1; ycur >= 0; ycur -= 64) {
    int lo = x - 63; if (lo < 0) lo = 0;
    const int wb = (lo >> 3) & ~3;
    int ry = ycur - lane;
    unsigned w0 = 0, w1 = 0, w2 = 0;
    if (ry >= 0) {
      const unsigned* rp = (const unsigned*)(bb + (size_t)ry * 64 + wb);
      w0 = rp[0]; w1 = rp[1]; w2 = rp[2];
    }
    const int rows = (ycur + 1 < 64) ? (ycur + 1) : 64;
    #pragma unroll 1
    for (int s = 0; s < rows; s += 8) {
      const int cnt8 = (rows - s < 8) ? (rows - s) : 8;
      unsigned r0[8], r1[8], r2[8];
      #pragma unroll
      for (int u = 0; u < 8; ++u) {
        r0[u] = (unsigned)__builtin_amdgcn_readlane((int)w0, s + u);
        r1[u] = (unsigned)__builtin_amdgcn_readlane((int)w1, s + u);
        r2[u] = (unsigned)__builtin_amdgcn_readlane((int)w2, s + u);
      }
      #pragma unroll
      for (int u = 0; u < 8; ++u) {
        if (u < cnt8) {
          const int yy = ycur - s - u;
          ++cnt;
          if (yy > 0 && x > 0) {
            const int boff = (x >> 3) - wb;
            const unsigned word = (boff < 4) ? r0[u] : ((boff < 8) ? r1[u] : r2[u]);
            const unsigned byte = word >> ((boff & 3) * 8);
            if ((x == yy) || ((byte >> (x & 7)) & 1)) {
              for (int q = lane; q < cnt; q += 64) hb[(size_t)x * TY + yy + q] = 1.0f;
              if (lane == 0) db[x] = (float)cnt;
              cnt = 0;
              --x;
            }
          }
        }
      }
    }
  }
  for (int q = lane; q < cnt; q += 64) hb[(size_t)x * TY + q] = 1.0f;
  if (lane == 0) db[x] = (float)cnt;
}

extern "C" void kernel_launch(void* const* d_in, const int* in_sizes, int n_in,
                              void* d_out, int out_size, void* d_ws, size_t ws_size,
                              hipStream_t stream) {
  const float* mel_x  = (const float*)d_in[0];
  const float* txt_x  = (const float*)d_in[1];
  const float* mel_w1 = (const float*)d_in[2];
  const float* mel_b1 = (const float*)d_in[3];
  const float* mel_w2 = (const float*)d_in[4];
  const float* mel_b2 = (const float*)d_in[5];
  const float* txt_w1 = (const float*)d_in[6];
  const float* txt_b1 = (const float*)d_in[7];
  const float* txt_w2 = (const float*)d_in[8];
  const float* txt_b2 = (const float*)d_in[9];
  const float* wq     = (const float*)d_in[10];
  const float* bq     = (const float*)d_in[11];
  const float* wk     = (const float*)d_in[12];
  const float* bk     = (const float*)d_in[13];
  const int*   xl     = (const int*)d_in[14];
  const int*   yl     = (const int*)d_in[15];

  char* wsb = (char*)d_ws;
  constexpr size_t MXH   = 0;
  constexpr size_t MXL   = MXH   + 4915200;
  constexpr size_t TXH   = MXL   + 4915200;
  constexpr size_t TXL   = TXH   + 6553600;
  constexpr size_t KTF   = TXH;
  constexpr size_t WFMH  = TXL   + 6553600;
  constexpr size_t WFML  = WFMH  + 2949120;
  constexpr size_t WFTH  = WFML  + 2949120;
  constexpr size_t WFTL  = WFTH  + 1769472;
  constexpr size_t B2M   = WFTL  + 1769472;
  constexpr size_t B2T   = B2M   + 2048;
  constexpr size_t HH    = B2T   + 2048;
  constexpr size_t HL    = HH    + 39321600;
  constexpr size_t BITS  = MXH;
  constexpr size_t SCR   = HL    + 39321600;
  constexpr size_t W1MH  = SCR;
  constexpr size_t W1ML  = W1MH  + 1474560;
  constexpr size_t W1TH  = W1ML  + 1474560;
  constexpr size_t W1TL  = W1TH  + 4718592;
  constexpr size_t WQH   = W1TL  + 4718592;
  constexpr size_t WQL   = WQH   + 294912;
  constexpr size_t WKH   = WQL   + 294912;
  constexpr size_t WKL   = WKH   + 294912;
  constexpr size_t W2TMH = WKL   + 294912;
  constexpr size_t W2TML = W2TMH + 2949120;
  constexpr size_t W2TTH = W2TML + 2949120;
  constexpr size_t W2TTL = W2TTH + 1769472;
  constexpr size_t QF    = SCR;

  float* out = (float*)d_out;
  float* o_attn = out;
  float* o_logp = out + (size_t)10240000;
  float* o_hard = out + (size_t)20480000;
  float* o_dur  = out + (size_t)30720000;

  hipMemsetAsync(o_hard, 0, (size_t)(10240000 + 6400) * sizeof(float), stream);

  split_pad_k<<<9600, 256, 0, stream>>>(mel_x, (__bf16*)(wsb + MXH), (__bf16*)(wsb + MXL), 80, 96, 2457600L);
  split_pad_k<<<12800, 256, 0, stream>>>(txt_x, (__bf16*)(wsb + TXH), (__bf16*)(wsb + TXL), 512, 512, 3276800L);
  wsplit_k<<<2880, 256, 0, stream>>>(mel_w1, (__bf16*)(wsb + W1MH), (__bf16*)(wsb + W1ML), 80, 5, 96, 737280L);
  wsplit_k<<<9216, 256, 0, stream>>>(txt_w1, (__bf16*)(wsb + W1TH), (__bf16*)(wsb + W1TL), 512, 3, 512, 2359296L);
  wsplit_k<<<576, 256, 0, stream>>>(wq, (__bf16*)(wsb + WQH), (__bf16*)(wsb + WQL), 384, 1, 384, 147456L);
  wsplit_k<<<576, 256, 0, stream>>>(wk, (__bf16*)(wsb + WKH), (__bf16*)(wsb + WKL), 384, 1, 384, 147456L);
  tsplit_k<<<5760, 256, 0, stream>>>(mel_w2, (__bf16*)(wsb + W2TMH), (__bf16*)(wsb + W2TML), 3840, 1474560L);
  tsplit_k<<<3456, 256, 0, stream>>>(txt_w2, (__bf16*)(wsb + W2TTH), (__bf16*)(wsb + W2TTL), 2304, 884736L);
  fold_mfma<5><<<dim3(60, 3), 256, 0, stream>>>(
      (const __bf16*)(wsb + W2TMH), (const __bf16*)(wsb + W2TML),
      (const __bf16*)(wsb + WQH), (const __bf16*)(wsb + WQL),
      (__bf16*)(wsb + WFMH), (__bf16*)(wsb + WFML));
  fold_mfma<3><<<dim3(36, 3), 256, 0, stream>>>(
      (const __bf16*)(wsb + W2TTH), (const __bf16*)(wsb + W2TTL),
      (const __bf16*)(wsb + WKH), (const __bf16*)(wsb + WKL),
      (__bf16*)(wsb + WFTH), (__bf16*)(wsb + WFTL));
  fold_bias_k<<<1, 384, 0, stream>>>(wq, mel_b2, (float*)(wsb + B2M));
  fold_bias_k<<<1, 384, 0, stream>>>(wk, txt_b2, (float*)(wsb + B2T));

  // text pipeline: conv1 -> conv2(folded) writes kT directly
  conv1_mfma<512, 3, 400><<<dim3(4, 12, B), 256, 0, stream>>>(
      (const __bf16*)(wsb + TXH), (const __bf16*)(wsb + TXL),
      (const __bf16*)(wsb + W1TH), (const __bf16*)(wsb + W1TL),
      txt_b1, xl, (__bf16*)(wsb + HH), (__bf16*)(wsb + HL));
  conv2_mfma<3, 400, true><<<dim3(4, 2, B), 256, 0, stream>>>(
      (const __bf16*)(wsb + HH), (const __bf16*)(wsb + HL),
      (const __bf16*)(wsb + WFTH), (const __bf16*)(wsb + WFTL),
      (const float*)(wsb + B2T), bk, xl, (float*)(wsb + KTF));

  // mel pipeline: conv1 -> conv2(folded) writes q directly
  conv1_mfma<96, 5, 1600><<<dim3(13, 12, B), 256, 0, stream>>>(
      (const __bf16*)(wsb + MXH), (const __bf16*)(wsb + MXL),
      (const __bf16*)(wsb + W1MH), (const __bf16*)(wsb + W1ML),
      mel_b1, yl, (__bf16*)(wsb + HH), (__bf16*)(wsb + HL));
  conv2_mfma<5, 1600, false><<<dim3(13, 2, B), 256, 0, stream>>>(
      (const __bf16*)(wsb + HH), (const __bf16*)(wsb + HL),
      (const __bf16*)(wsb + WFMH), (const __bf16*)(wsb + WFML),
      (const float*)(wsb + B2M), bq, yl, (float*)(wsb + QF));

  // attention + MAS
  scores_k<<<dim3(100, B), 512, 0, stream>>>(
      (const float*)(wsb + QF), (const float*)(wsb + KTF), xl, yl, o_attn, o_logp);
  mas_fwd<<<B, 64, 0, stream>>>(o_logp, xl, yl, (unsigned char*)(wsb + BITS));
  mas_bt<<<B, 64, 0, stream>>>((const unsigned char*)(wsb + BITS), xl, yl, o_hard, o_dur);
}

// Round 12
// 1555.180 us; speedup vs baseline: 1.2077x; 1.0121x over previous
//
#include <hip/hip_runtime.h>
#include <cstdint>

#define B 16
#define TY 1600
#define TX 400
#define MAS 384
#define HID 768
#define NEGV -1e9f

typedef __bf16 bf16x8 __attribute__((ext_vector_type(8)));
typedef float  f32x4  __attribute__((ext_vector_type(4)));
typedef float  f32x16 __attribute__((ext_vector_type(16)));

__device__ __forceinline__ f32x4 mfma16(bf16x8 a, bf16x8 b, f32x4 c) {
  return __builtin_amdgcn_mfma_f32_16x16x32_bf16(a, b, c, 0, 0, 0);
}
__device__ __forceinline__ f32x16 mfma32(bf16x8 a, bf16x8 b, f32x16 c) {
  return __builtin_amdgcn_mfma_f32_32x32x16_bf16(a, b, c, 0, 0, 0);
}

// ---------------- fp32 -> bf16 hi/lo split with channel padding ----------------
__global__ void split_pad_k(const float* __restrict__ in, __bf16* __restrict__ oh,
                            __bf16* __restrict__ ol, int CIN, int CINP, long n) {
  long i = (long)blockIdx.x * 256 + threadIdx.x;
  if (i >= n) return;
  long row = i / CINP; int ci = (int)(i - row * CINP);
  float v = (ci < CIN) ? in[row * CIN + ci] : 0.f;
  __bf16 h = (__bf16)v;
  oh[i] = h; ol[i] = (__bf16)(v - (float)h);
}

// ---------------- weight repack+split: w[N][CIN][K] -> oh/ol[N][k*CINP + ci] ----------------
__global__ void wsplit_k(const float* __restrict__ w, __bf16* __restrict__ oh,
                         __bf16* __restrict__ ol, int CIN, int K_, int CINP, long n) {
  long i = (long)blockIdx.x * 256 + threadIdx.x;
  if (i >= n) return;
  long kdspan = (long)K_ * CINP;
  long nn = i / kdspan; int kd = (int)(i - nn * kdspan);
  int k = kd / CINP, ci = kd - k * CINP;
  float v = (ci < CIN) ? w[(nn * CIN + ci) * K_ + k] : 0.f;
  __bf16 h = (__bf16)v;
  oh[i] = h; ol[i] = (__bf16)(v - (float)h);
}

// ---------------- transpose+split: w2 [m][JTOT] -> oh/ol [j][384] ----------------
__global__ void tsplit_k(const float* __restrict__ in, __bf16* __restrict__ oh,
                         __bf16* __restrict__ ol, int JTOT, long n) {
  long i = (long)blockIdx.x * 256 + threadIdx.x;
  if (i >= n) return;
  int m = (int)(i / JTOT), j = (int)(i - (long)m * JTOT);
  float v = in[i];
  long o = (long)j * 384 + m;
  __bf16 h = (__bf16)v;
  oh[o] = h; ol[o] = (__bf16)(v - (float)h);
}

// ---------------- bias fold: o[n] = sum_m wq[n][m] * b[m] ----------------
__global__ void fold_bias_k(const float* __restrict__ wq, const float* __restrict__ b,
                            float* __restrict__ o) {
  int n = threadIdx.x;
  float s = 0.f;
  for (int m = 0; m < 384; ++m) s = fmaf(wq[n * 384 + m], b[m], s);
  o[n] = s;
}

// ---------------- weight-fold GEMM (conv2-staging-native output layout) ----------------
template<int KK>
__global__ __launch_bounds__(256)
void fold_mfma(const __bf16* __restrict__ xh, const __bf16* __restrict__ xl,
               const __bf16* __restrict__ wh, const __bf16* __restrict__ wl,
               __bf16* __restrict__ oh, __bf16* __restrict__ ol)
{
  constexpr int CINP = 384, ROWS = 64, STRIDE = 65;
  __shared__ float4 xs[8 * STRIDE];
  const int t0 = blockIdx.x * 64, n0 = blockIdx.y * 128;
  const int tid = threadIdx.x, wn = tid >> 6, lane = tid & 63;
  const int lr = lane & 15, lg = lane >> 4;
  const f32x4 Z4 = {0.f, 0.f, 0.f, 0.f};
  f32x4 acc[4][2];
  #pragma unroll
  for (int m = 0; m < 4; ++m) { acc[m][0] = Z4; acc[m][1] = Z4; }

  #pragma unroll 1
  for (int ci0 = 0; ci0 < CINP; ci0 += 32) {
    __syncthreads();
    for (int e = tid; e < ROWS * 8; e += 256) {
      int row = e >> 3, sc = e & 7, spl = sc >> 2, cg = sc & 3;
      int t = t0 + row;
      xs[(spl * 4 + cg) * STRIDE + row] =
          *(const float4*)((spl ? xl : xh) + (size_t)t * CINP + ci0 + cg * 8);
    }
    __syncthreads();
    bf16x8 ah[4], al[4];
    #pragma unroll
    for (int mf = 0; mf < 4; ++mf) {
      int row = mf * 16 + lr;
      ah[mf] = *(const bf16x8*)&xs[lg * STRIDE + row];
      al[mf] = *(const bf16x8*)&xs[(4 + lg) * STRIDE + row];
    }
    size_t kd = (size_t)ci0 + lg * 8;
    bf16x8 bh[2], bl[2];
    #pragma unroll
    for (int nf = 0; nf < 2; ++nf) {
      int nc = n0 + wn * 32 + nf * 16 + lr;
      bh[nf] = *(const bf16x8*)(wh + (size_t)nc * 384 + kd);
      bl[nf] = *(const bf16x8*)(wl + (size_t)nc * 384 + kd);
    }
    #pragma unroll
    for (int nf = 0; nf < 2; ++nf)
      #pragma unroll
      for (int mf = 0; mf < 4; ++mf) acc[mf][nf] = mfma16(ah[mf], bh[nf], acc[mf][nf]);
    #pragma unroll
    for (int nf = 0; nf < 2; ++nf)
      #pragma unroll
      for (int mf = 0; mf < 4; ++mf) acc[mf][nf] = mfma16(ah[mf], bl[nf], acc[mf][nf]);
    #pragma unroll
    for (int nf = 0; nf < 2; ++nf)
      #pragma unroll
      for (int mf = 0; mf < 4; ++mf) acc[mf][nf] = mfma16(al[mf], bh[nf], acc[mf][nf]);
  }
  #pragma unroll
  for (int nf = 0; nf < 2; ++nf) {
    int c = n0 + wn * 32 + nf * 16 + lr;
    #pragma unroll
    for (int mf = 0; mf < 4; ++mf) {
      #pragma unroll
      for (int r = 0; r < 4; ++r) {
        int j = t0 + mf * 16 + lg * 4 + r;   // j = ci*KK + k
        int k = j % KK, ci = j / KK;
        size_t o = (size_t)((((ci >> 4) * KK + k) * 2 + ((ci >> 3) & 1)) * 3072)
                 + (size_t)c * 8 + (ci & 7);
        float v = acc[mf][nf][r];
        __bf16 vh = (__bf16)v;
        oh[o] = vh; ol[o] = (__bf16)(v - (float)vh);
      }
    }
  }
}

// ---------------- conv1 + ReGLU, split-bf16 MFMA ----------------
template<int CINP, int K, int T>
__global__ __launch_bounds__(256)
void conv1_mfma(const __bf16* __restrict__ xh, const __bf16* __restrict__ xl,
                const __bf16* __restrict__ wh, const __bf16* __restrict__ wl,
                const float* __restrict__ bias, const int* __restrict__ lens,
                __bf16* __restrict__ hh, __bf16* __restrict__ hl)
{
  constexpr int BM = 128, PAD = K / 2, ROWS = BM + K - 1, KD = K * CINP;
  __shared__ float4 xs[8 * ROWS];
  const int b = blockIdx.z, t0 = blockIdx.x * BM, n0 = blockIdx.y * 64;
  const int tid = threadIdx.x, wid = tid >> 6, lane = tid & 63;
  const int wm = wid >> 1, wn = wid & 1, lr = lane & 15, lg = lane >> 4;
  const int len = lens[b];
  const f32x4 Z4 = {0.f, 0.f, 0.f, 0.f};
  f32x4 acc_a[4][2], acc_g[4][2];
  #pragma unroll
  for (int m = 0; m < 4; ++m)
    #pragma unroll
    for (int n = 0; n < 2; ++n) { acc_a[m][n] = Z4; acc_g[m][n] = Z4; }

  #pragma unroll 1
  for (int ci0 = 0; ci0 < CINP; ci0 += 32) {
    __syncthreads();
    for (int e = tid; e < ROWS * 8; e += 256) {
      int row = e >> 3, sc = e & 7, spl = sc >> 2, cg = sc & 3;
      int t = t0 + row - PAD;
      float4 v = {0.f, 0.f, 0.f, 0.f};
      if (t >= 0 && t < len)
        v = *(const float4*)((spl ? xl : xh) + ((size_t)b * T + t) * CINP + ci0 + cg * 8);
      xs[(spl * 4 + cg) * ROWS + row] = v;
    }
    __syncthreads();
    #pragma unroll
    for (int k = 0; k < K; ++k) {
      bf16x8 ah[4], al[4];
      #pragma unroll
      for (int mf = 0; mf < 4; ++mf) {
        int row = wm * 64 + mf * 16 + lr + k;
        ah[mf] = *(const bf16x8*)&xs[lg * ROWS + row];
        al[mf] = *(const bf16x8*)&xs[(4 + lg) * ROWS + row];
      }
      size_t kd = (size_t)k * CINP + ci0 + lg * 8;
      #pragma unroll
      for (int nf = 0; nf < 2; ++nf) {
        int na = n0 + wn * 32 + nf * 16 + lr;
        bf16x8 bah = *(const bf16x8*)(wh + (size_t)na * KD + kd);
        bf16x8 bal = *(const bf16x8*)(wl + (size_t)na * KD + kd);
        bf16x8 bgh = *(const bf16x8*)(wh + (size_t)(na + HID) * KD + kd);
        bf16x8 bgl = *(const bf16x8*)(wl + (size_t)(na + HID) * KD + kd);
        #pragma unroll
        for (int mf = 0; mf < 4; ++mf) {
          acc_a[mf][nf] = mfma16(ah[mf], bah, acc_a[mf][nf]);
          acc_a[mf][nf] = mfma16(ah[mf], bal, acc_a[mf][nf]);
          acc_a[mf][nf] = mfma16(al[mf], bah, acc_a[mf][nf]);
          acc_g[mf][nf] = mfma16(ah[mf], bgh, acc_g[mf][nf]);
          acc_g[mf][nf] = mfma16(ah[mf], bgl, acc_g[mf][nf]);
          acc_g[mf][nf] = mfma16(al[mf], bgh, acc_g[mf][nf]);
        }
      }
    }
  }
  #pragma unroll
  for (int nf = 0; nf < 2; ++nf) {
    int c = n0 + wn * 32 + nf * 16 + lr;
    float ba = bias[c], bg = bias[c + HID];
    #pragma unroll
    for (int mf = 0; mf < 4; ++mf) {
      #pragma unroll
      for (int r = 0; r < 4; ++r) {
        int t = t0 + wm * 64 + mf * 16 + lg * 4 + r;
        if (t < T) {
          float a = acc_a[mf][nf][r] + ba;
          float g = acc_g[mf][nf][r] + bg;
          float v = a * fmaxf(g, 0.f);
          __bf16 vh = (__bf16)v;
          size_t o = ((size_t)b * T + t) * HID + c;
          hh[o] = vh;
          hl[o] = (__bf16)(v - (float)vh);
        }
      }
    }
  }
}

// ---------------- conv2 (folded weights), 32x32x16, B staged in LDS via global_load_lds ----------------
template<int K, int T, bool STORET>
__global__ __launch_bounds__(256)
void conv2_mfma(const __bf16* __restrict__ xh, const __bf16* __restrict__ xl,
                const __bf16* __restrict__ wh, const __bf16* __restrict__ wl,
                const float* __restrict__ bias, const float* __restrict__ ab,
                const int* __restrict__ lens, float* __restrict__ out)
{
  constexpr int CINP = 768, BM = 128, PAD = K / 2, ROWS = BM + K - 1, STRIDE = ROWS + 1;
  constexpr int BROWS = K * 2;
  __shared__ float4 xa[4 * STRIDE];
  __shared__ float4 bs[2 * BROWS * 192];
  const int b = blockIdx.z, t0 = blockIdx.x * BM, n0 = blockIdx.y * 192;
  const int tid = threadIdx.x, wid = tid >> 6, lane = tid & 63;
  const int wm = wid >> 1, wn = wid & 1, lc = lane & 31, lk = lane >> 5;
  const int len = lens[b];
  f32x16 acc[2][3];
  #pragma unroll
  for (int m = 0; m < 2; ++m)
    #pragma unroll
    for (int n = 0; n < 3; ++n)
      #pragma unroll
      for (int r = 0; r < 16; ++r) acc[m][n][r] = 0.f;

  #pragma unroll 1
  for (int s = 0; s < 48; ++s) {
    __syncthreads();
    for (int e = tid; e < ROWS * 4; e += 256) {
      int row = e >> 2, sc = e & 3, spl = sc >> 1, cg = sc & 1;
      int t = t0 + row - PAD;
      float4 v = {0.f, 0.f, 0.f, 0.f};
      if (t >= 0 && t < len)
        v = *(const float4*)((spl ? xl : xh) + ((size_t)b * T + t) * CINP + s * 16 + cg * 8);
      xa[(spl * 2 + cg) * STRIDE + row] = v;
    }
    for (int r = wid; r < 2 * BROWS; r += 4) {
      int spl = r / BROWS, rr = r - spl * BROWS;
      const char* src = (const char*)((spl ? wl : wh) + (size_t)(s * BROWS + rr) * 3072
                                      + (size_t)n0 * 8) + (size_t)lane * 16;
      char* dst = (char*)&bs[r * 192];
      #pragma unroll
      for (int i = 0; i < 3; ++i)
        __builtin_amdgcn_global_load_lds(
            (const __attribute__((address_space(1))) void*)(src + i * 1024),
            (__attribute__((address_space(3))) void*)(dst + i * 1024), 16, 0, 0);
    }
    __syncthreads();
    #pragma unroll
    for (int k = 0; k < K; ++k) {
      bf16x8 ah[2], al[2], bh[3], bl[3];
      #pragma unroll
      for (int mf = 0; mf < 2; ++mf) {
        int row = wm * 64 + mf * 32 + lc + k;
        ah[mf] = *(const bf16x8*)&xa[lk * STRIDE + row];
        al[mf] = *(const bf16x8*)&xa[(2 + lk) * STRIDE + row];
      }
      #pragma unroll
      for (int nf = 0; nf < 3; ++nf) {
        int col = wn * 96 + nf * 32 + lc;
        bh[nf] = *(const bf16x8*)&bs[(k * 2 + lk) * 192 + col];
        bl[nf] = *(const bf16x8*)&bs[(BROWS + k * 2 + lk) * 192 + col];
      }
      #pragma unroll
      for (int nf = 0; nf < 3; ++nf)
        #pragma unroll
        for (int mf = 0; mf < 2; ++mf)
          acc[mf][nf] = mfma32(ah[mf], bh[nf], acc[mf][nf]);
      #pragma unroll
      for (int nf = 0; nf < 3; ++nf)
        #pragma unroll
        for (int mf = 0; mf < 2; ++mf)
          acc[mf][nf] = mfma32(ah[mf], bl[nf], acc[mf][nf]);
      #pragma unroll
      for (int nf = 0; nf < 3; ++nf)
        #pragma unroll
        for (int mf = 0; mf < 2; ++mf)
          acc[mf][nf] = mfma32(al[mf], bh[nf], acc[mf][nf]);
    }
  }
  #pragma unroll
  for (int nf = 0; nf < 3; ++nf) {
    int c = n0 + wn * 96 + nf * 32 + lc;
    float bb = bias[c], aB = ab[c];
    #pragma unroll
    for (int mf = 0; mf < 2; ++mf) {
      #pragma unroll
      for (int r = 0; r < 16; ++r) {
        int t = t0 + wm * 64 + mf * 32 + (r & 3) + 8 * (r >> 2) + 4 * lk;
        if (t < T) {
          float v = acc[mf][nf][r] + bb;
          if (t >= len) v = 0.f;
          v += aB;
          if (STORET) out[((size_t)b * MAS + c) * T + t] = v;
          else        out[((size_t)b * T + t) * MAS + c] = v;
        }
      }
    }
  }
}

// ---------------- scores + softmax + safe_log ----------------
__global__ __launch_bounds__(512)
void scores_k(const float* __restrict__ q, const float* __restrict__ kT,
              const int* __restrict__ xl, const int* __restrict__ yl,
              float* __restrict__ oattn, float* __restrict__ ologp)
{
  __shared__ float qs[16 * 384];
  __shared__ float tmp[8];
  const int b = blockIdx.y, y0 = blockIdx.x * 16, tid = threadIdx.x;
  for (int e = tid; e < 16 * 384; e += 512)
    qs[e] = q[((size_t)b * TY + (y0 + e / 384)) * 384 + (e - (e / 384) * 384)];
  __syncthreads();
  float acc[16];
  #pragma unroll
  for (int i = 0; i < 16; ++i) acc[i] = 0.f;
  const int x = tid;
  if (x < TX) {
    const float* kb = kT + (size_t)b * MAS * TX + x;
    for (int d = 0; d < 384; d += 4) {
      float k0 = kb[(size_t)(d + 0) * TX], k1 = kb[(size_t)(d + 1) * TX];
      float k2 = kb[(size_t)(d + 2) * TX], k3 = kb[(size_t)(d + 3) * TX];
      #pragma unroll
      for (int yy = 0; yy < 16; ++yy) {
        float4 qv = *(const float4*)&qs[yy * 384 + d];
        acc[yy] = fmaf(qv.x, k0, fmaf(qv.y, k1, fmaf(qv.z, k2, fmaf(qv.w, k3, acc[yy]))));
      }
    }
  }
  const int xlen = xl[b], ylen = yl[b];
  const float scale = 0.05103103630798288f;
  const bool xpad = (x >= xlen);
  const int wv = tid >> 6, ln = tid & 63;
  #pragma unroll 1
  for (int yy = 0; yy < 16; ++yy) {
    int y = y0 + yy;
    float s = -3.0e38f;
    if (x < TX) {
      s = acc[yy] * scale;
      if (xpad && (y >= ylen)) s = -1e-9f;
    }
    float m = s;
    for (int off = 32; off; off >>= 1) m = fmaxf(m, __shfl_xor(m, off));
    if (ln == 0) tmp[wv] = m;
    __syncthreads();
    float mx = fmaxf(fmaxf(fmaxf(tmp[0], tmp[1]), fmaxf(tmp[2], tmp[3])),
                     fmaxf(fmaxf(tmp[4], tmp[5]), fmaxf(tmp[6], tmp[7])));
    __syncthreads();
    float e = (x < TX) ? expf(s - mx) : 0.f;
    float sm = e;
    for (int off = 32; off; off >>= 1) sm += __shfl_xor(sm, off);
    if (ln == 0) tmp[wv] = sm;
    __syncthreads();
    float tot = tmp[0] + tmp[1] + tmp[2] + tmp[3] + tmp[4] + tmp[5] + tmp[6] + tmp[7];
    __syncthreads();
    if (x < TX) {
      float w = e / tot;
      size_t o = ((size_t)b * TY + y) * TX + x;
      oattn[o] = w;
      ologp[o] = logf(w + 1e-6f);
    }
  }
}

// ---------------- MAS fused: 4-row blocked DP (4-deep reg ring, store-free load stream)
//                  + in-kernel backtrack. bits8[yblk][lane][8B] global, 1 store / 8 rows.
#define MAS_LD(blkv, buf) do {                                           \
    int base_ = (blkv) * 4;                                              \
    _Pragma("unroll")                                                    \
    for (int d_ = 0; d_ < 4; ++d_) {                                     \
      int yr_ = base_ + d_; if (yr_ > TY - 1) yr_ = TY - 1;              \
      const float* r_ = lpb + (size_t)yr_ * TX;                          \
      buf[d_ * 3 + 0] = *(const float4*)(r_ + lb0);                      \
      buf[d_ * 3 + 1] = *(const float4*)(r_ + lb1);                      \
      buf[d_ * 3 + 2] = *(const float4*)(r_ + lb2);                      \
    } } while (0)

#define MAS_BLK(blkv, buf, PAR) do {                                     \
    float h0 = __shfl_up(w[8], 1),  h1 = __shfl_up(w[9], 1);             \
    float h2 = __shfl_up(w[10], 1), h3 = __shfl_up(w[11], 1);            \
    w[0] = lane ? h0 : NEGV; w[1] = lane ? h1 : NEGV;                    \
    w[2] = lane ? h2 : NEGV; w[3] = lane ? h3 : NEGV;                    \
    const int y0_ = (blkv) * 4;                                          \
    const bool ph1_ = (y0_ < TX);                                        \
    _Pragma("unroll")                                                    \
    for (int d_ = 0; d_ < 4; ++d_) {                                     \
      const int y_ = y0_ + d_;                                           \
      float lp[12];                                                      \
      _Pragma("unroll")                                                  \
      for (int k_ = 0; k_ < 3; ++k_) {                                   \
        float4 v_ = buf[d_ * 3 + k_];                                    \
        lp[k_*4+0] = v_.x + wxm[k_*4+0]; lp[k_*4+1] = v_.y + wxm[k_*4+1];\
        lp[k_*4+2] = v_.z + wxm[k_*4+2]; lp[k_*4+3] = v_.w + wxm[k_*4+3];\
      }                                                                  \
      if (ph1_) {                                                        \
        int c_ = y_ - p0;                                                \
        _Pragma("unroll")                                                \
        for (int i_ = 0; i_ < 12; ++i_) lp[i_] = (i_ <= c_) ? lp[i_] : NEGV; \
      }                                                                  \
      unsigned byte_ = 0;                                                \
      _Pragma("unroll")                                                  \
      for (int j_ = 0; j_ < 8; ++j_)                                     \
        byte_ |= (w[j_ + 3] > w[j_ + 4]) ? (1u << j_) : 0u;              \
      bitsacc |= (unsigned long long)byte_ << (((PAR) * 4 + d_) * 8);    \
      float nw[12];                                                      \
      nw[0] = lp[0] + w[0];                                              \
      _Pragma("unroll")                                                  \
      for (int i_ = 1; i_ < 12; ++i_) nw[i_] = lp[i_] + fmaxf(w[i_], w[i_ - 1]); \
      _Pragma("unroll")                                                  \
      for (int i_ = 0; i_ < 12; ++i_) w[i_] = nw[i_];                    \
    } } while (0)

#define MAS_ST(oddblk) do {                                              \
    *(unsigned long long*)(bb8 + ((size_t)((oddblk) >> 1)) * 512 + (size_t)lane * 8) = bitsacc; \
    bitsacc = 0ULL; } while (0)

__global__ __launch_bounds__(64, 1)
void mas_k(const float* __restrict__ logprob, const int* __restrict__ xl,
           const int* __restrict__ yl, unsigned char* __restrict__ bits,
           float* __restrict__ hard, float* __restrict__ dur)
{
  const int b = blockIdx.x;
  const int lane = threadIdx.x;
  const int xlen = xl[b], ylen = yl[b];
  const float* lpb = logprob + (size_t)b * TY * TX;
  unsigned char* bb8 = bits + (size_t)b * 102400;   // [yblk(200)][lane(64)][8B]
  const int p0 = lane * 8 - 4;
  int t;
  t = p0;     if (t < 0) t = 0; if (t > 396) t = 396; const int lb0 = t;
  t = p0 + 4; if (t < 0) t = 0; if (t > 396) t = 396; const int lb1 = t;
  t = p0 + 8; if (t < 0) t = 0; if (t > 396) t = 396; const int lb2 = t;

  float w[12], wxm[12];
  #pragma unroll
  for (int i = 0; i < 12; ++i) {
    int p = p0 + i;
    wxm[i] = (p >= 0 && p < xlen) ? 0.f : NEGV;
    w[i] = (p == 0) ? 0.f : NEGV;
  }

  float4 buf0[12], buf1[12], buf2[12], buf3[12];
  MAS_LD(0, buf0); MAS_LD(1, buf1); MAS_LD(2, buf2); MAS_LD(3, buf3);
  unsigned long long bitsacc = 0ULL;
  const int nblk = (ylen + 3) >> 2;
  int blk = 0;
  #pragma unroll 1
  for (; blk + 3 < nblk; blk += 4) {
    __builtin_amdgcn_sched_barrier(0);
    MAS_BLK(blk, buf0, 0);     MAS_LD(blk + 4, buf0);
    __builtin_amdgcn_sched_barrier(0);
    MAS_BLK(blk + 1, buf1, 1); MAS_LD(blk + 5, buf1); MAS_ST(blk + 1);
    __builtin_amdgcn_sched_barrier(0);
    MAS_BLK(blk + 2, buf2, 0); MAS_LD(blk + 6, buf2);
    __builtin_amdgcn_sched_barrier(0);
    MAS_BLK(blk + 3, buf3, 1); MAS_LD(blk + 7, buf3); MAS_ST(blk + 3);
  }
  {
    const int r = nblk - blk;
    if (r > 0) MAS_BLK(blk, buf0, 0);
    if (r > 1) { MAS_BLK(blk + 1, buf1, 1); MAS_ST(blk + 1); }
    if (r > 2) MAS_BLK(blk + 2, buf2, 0);
    if (r == 1 || r == 3) {
      *(unsigned long long*)(bb8 + ((size_t)((blk + r - 1) >> 1)) * 512 + (size_t)lane * 8) = bitsacc;
    }
  }

  __threadfence();   // drain own stores + invalidate L1 before re-reading bits
  __syncthreads();

  // backtrack: uniform scalar walk via readlane; window reassembled from bits8
  int x = xlen - 1;
  int cnt = 0;
  float* hb = hard + (size_t)b * TX * TY;
  float* db = dur + (size_t)b * TX;

  #pragma unroll 1
  for (int ycur = ylen - 1; ycur >= 0; ycur -= 64) {
    int lo = x - 63; if (lo < 0) lo = 0;
    const int wb = (lo >> 3) & ~3;                  // window bytes [wb, wb+12)
    int ry = ycur - lane;
    unsigned w0 = 0, w1 = 0, w2 = 0;
    if (ry >= 0) {
      const unsigned char* p = bb8 + (size_t)(ry >> 3) * 512 + (ry & 7);
      unsigned bt_[12];
      #pragma unroll
      for (int j = 0; j < 12; ++j) bt_[j] = p[(size_t)(wb + j) * 8];
      w0 = bt_[0] | (bt_[1] << 8) | (bt_[2] << 16) | (bt_[3] << 24);
      w1 = bt_[4] | (bt_[5] << 8) | (bt_[6] << 16) | (bt_[7] << 24);
      w2 = bt_[8] | (bt_[9] << 8) | (bt_[10] << 16) | (bt_[11] << 24);
    }
    const int rows = (ycur + 1 < 64) ? (ycur + 1) : 64;
    #pragma unroll 1
    for (int s = 0; s < rows; s += 8) {
      const int cnt8 = (rows - s < 8) ? (rows - s) : 8;
      unsigned r0[8], r1[8], r2[8];
      #pragma unroll
      for (int u = 0; u < 8; ++u) {
        r0[u] = (unsigned)__builtin_amdgcn_readlane((int)w0, s + u);
        r1[u] = (unsigned)__builtin_amdgcn_readlane((int)w1, s + u);
        r2[u] = (unsigned)__builtin_amdgcn_readlane((int)w2, s + u);
      }
      #pragma unroll
      for (int u = 0; u < 8; ++u) {
        if (u < cnt8) {
          const int yy = ycur - s - u;
          ++cnt;
          if (yy > 0 && x > 0) {
            const int boff = (x >> 3) - wb;
            const unsigned word = (boff < 4) ? r0[u] : ((boff < 8) ? r1[u] : r2[u]);
            const unsigned byte = word >> ((boff & 3) * 8);
            if ((x == yy) || ((byte >> (x & 7)) & 1)) {
              for (int q = lane; q < cnt; q += 64) hb[(size_t)x * TY + yy + q] = 1.0f;
              if (lane == 0) db[x] = (float)cnt;
              cnt = 0;
              --x;
            }
          }
        }
      }
    }
  }
  for (int q = lane; q < cnt; q += 64) hb[(size_t)x * TY + q] = 1.0f;
  if (lane == 0) db[x] = (float)cnt;
}

extern "C" void kernel_launch(void* const* d_in, const int* in_sizes, int n_in,
                              void* d_out, int out_size, void* d_ws, size_t ws_size,
                              hipStream_t stream) {
  const float* mel_x  = (const float*)d_in[0];
  const float* txt_x  = (const float*)d_in[1];
  const float* mel_w1 = (const float*)d_in[2];
  const float* mel_b1 = (const float*)d_in[3];
  const float* mel_w2 = (const float*)d_in[4];
  const float* mel_b2 = (const float*)d_in[5];
  const float* txt_w1 = (const float*)d_in[6];
  const float* txt_b1 = (const float*)d_in[7];
  const float* txt_w2 = (const float*)d_in[8];
  const float* txt_b2 = (const float*)d_in[9];
  const float* wq     = (const float*)d_in[10];
  const float* bq     = (const float*)d_in[11];
  const float* wk     = (const float*)d_in[12];
  const float* bk     = (const float*)d_in[13];
  const int*   xl     = (const int*)d_in[14];
  const int*   yl     = (const int*)d_in[15];

  char* wsb = (char*)d_ws;
  constexpr size_t MXH   = 0;
  constexpr size_t MXL   = MXH   + 4915200;
  constexpr size_t TXH   = MXL   + 4915200;
  constexpr size_t TXL   = TXH   + 6553600;
  constexpr size_t KTF   = TXH;
  constexpr size_t WFMH  = TXL   + 6553600;
  constexpr size_t WFML  = WFMH  + 2949120;
  constexpr size_t WFTH  = WFML  + 2949120;
  constexpr size_t WFTL  = WFTH  + 1769472;
  constexpr size_t B2M   = WFTL  + 1769472;
  constexpr size_t B2T   = B2M   + 2048;
  constexpr size_t HH    = B2T   + 2048;
  constexpr size_t HL    = HH    + 39321600;
  constexpr size_t BITS  = MXH;
  constexpr size_t SCR   = HL    + 39321600;
  constexpr size_t W1MH  = SCR;
  constexpr size_t W1ML  = W1MH  + 1474560;
  constexpr size_t W1TH  = W1ML  + 1474560;
  constexpr size_t W1TL  = W1TH  + 4718592;
  constexpr size_t WQH   = W1TL  + 4718592;
  constexpr size_t WQL   = WQH   + 294912;
  constexpr size_t WKH   = WQL   + 294912;
  constexpr size_t WKL   = WKH   + 294912;
  constexpr size_t W2TMH = WKL   + 294912;
  constexpr size_t W2TML = W2TMH + 2949120;
  constexpr size_t W2TTH = W2TML + 2949120;
  constexpr size_t W2TTL = W2TTH + 1769472;
  constexpr size_t QF    = SCR;

  float* out = (float*)d_out;
  float* o_attn = out;
  float* o_logp = out + (size_t)10240000;
  float* o_hard = out + (size_t)20480000;
  float* o_dur  = out + (size_t)30720000;

  hipMemsetAsync(o_hard, 0, (size_t)(10240000 + 6400) * sizeof(float), stream);

  split_pad_k<<<9600, 256, 0, stream>>>(mel_x, (__bf16*)(wsb + MXH), (__bf16*)(wsb + MXL), 80, 96, 2457600L);
  split_pad_k<<<12800, 256, 0, stream>>>(txt_x, (__bf16*)(wsb + TXH), (__bf16*)(wsb + TXL), 512, 512, 3276800L);
  wsplit_k<<<2880, 256, 0, stream>>>(mel_w1, (__bf16*)(wsb + W1MH), (__bf16*)(wsb + W1ML), 80, 5, 96, 737280L);
  wsplit_k<<<9216, 256, 0, stream>>>(txt_w1, (__bf16*)(wsb + W1TH), (__bf16*)(wsb + W1TL), 512, 3, 512, 2359296L);
  wsplit_k<<<576, 256, 0, stream>>>(wq, (__bf16*)(wsb + WQH), (__bf16*)(wsb + WQL), 384, 1, 384, 147456L);
  wsplit_k<<<576, 256, 0, stream>>>(wk, (__bf16*)(wsb + WKH), (__bf16*)(wsb + WKL), 384, 1, 384, 147456L);
  tsplit_k<<<5760, 256, 0, stream>>>(mel_w2, (__bf16*)(wsb + W2TMH), (__bf16*)(wsb + W2TML), 3840, 1474560L);
  tsplit_k<<<3456, 256, 0, stream>>>(txt_w2, (__bf16*)(wsb + W2TTH), (__bf16*)(wsb + W2TTL), 2304, 884736L);
  fold_mfma<5><<<dim3(60, 3), 256, 0, stream>>>(
      (const __bf16*)(wsb + W2TMH), (const __bf16*)(wsb + W2TML),
      (const __bf16*)(wsb + WQH), (const __bf16*)(wsb + WQL),
      (__bf16*)(wsb + WFMH), (__bf16*)(wsb + WFML));
  fold_mfma<3><<<dim3(36, 3), 256, 0, stream>>>(
      (const __bf16*)(wsb + W2TTH), (const __bf16*)(wsb + W2TTL),
      (const __bf16*)(wsb + WKH), (const __bf16*)(wsb + WKL),
      (__bf16*)(wsb + WFTH), (__bf16*)(wsb + WFTL));
  fold_bias_k<<<1, 384, 0, stream>>>(wq, mel_b2, (float*)(wsb + B2M));
  fold_bias_k<<<1, 384, 0, stream>>>(wk, txt_b2, (float*)(wsb + B2T));

  // text pipeline: conv1 -> conv2(folded) writes kT directly
  conv1_mfma<512, 3, 400><<<dim3(4, 12, B), 256, 0, stream>>>(
      (const __bf16*)(wsb + TXH), (const __bf16*)(wsb + TXL),
      (const __bf16*)(wsb + W1TH), (const __bf16*)(wsb + W1TL),
      txt_b1, xl, (__bf16*)(wsb + HH), (__bf16*)(wsb + HL));
  conv2_mfma<3, 400, true><<<dim3(4, 2, B), 256, 0, stream>>>(
      (const __bf16*)(wsb + HH), (const __bf16*)(wsb + HL),
      (const __bf16*)(wsb + WFTH), (const __bf16*)(wsb + WFTL),
      (const float*)(wsb + B2T), bk, xl, (float*)(wsb + KTF));

  // mel pipeline: conv1 -> conv2(folded) writes q directly
  conv1_mfma<96, 5, 1600><<<dim3(13, 12, B), 256, 0, stream>>>(
      (const __bf16*)(wsb + MXH), (const __bf16*)(wsb + MXL),
      (const __bf16*)(wsb + W1MH), (const __bf16*)(wsb + W1ML),
      mel_b1, yl, (__bf16*)(wsb + HH), (__bf16*)(wsb + HL));
  conv2_mfma<5, 1600, false><<<dim3(13, 2, B), 256, 0, stream>>>(
      (const __bf16*)(wsb + HH), (const __bf16*)(wsb + HL),
      (const __bf16*)(wsb + WFMH), (const __bf16*)(wsb + WFML),
      (const float*)(wsb + B2M), bq, yl, (float*)(wsb + QF));

  // attention + MAS (fused fwd+bt)
  scores_k<<<dim3(100, B), 512, 0, stream>>>(
      (const float*)(wsb + QF), (const float*)(wsb + KTF), xl, yl, o_attn, o_logp);
  mas_k<<<B, 64, 0, stream>>>(o_logp, xl, yl, (unsigned char*)(wsb + BITS), o_hard, o_dur);
}

// Round 13
// 1528.433 us; speedup vs baseline: 1.2289x; 1.0175x over previous
//
#include <hip/hip_runtime.h>
#include <cstdint>

#define B 16
#define TY 1600
#define TX 400
#define MAS 384
#define HID 768
#define NEGV -1e9f

typedef __bf16 bf16x8 __attribute__((ext_vector_type(8)));
typedef float  f32x4  __attribute__((ext_vector_type(4)));
typedef float  f32x16 __attribute__((ext_vector_type(16)));

__device__ __forceinline__ f32x4 mfma16(bf16x8 a, bf16x8 b, f32x4 c) {
  return __builtin_amdgcn_mfma_f32_16x16x32_bf16(a, b, c, 0, 0, 0);
}
__device__ __forceinline__ f32x16 mfma32(bf16x8 a, bf16x8 b, f32x16 c) {
  return __builtin_amdgcn_mfma_f32_32x32x16_bf16(a, b, c, 0, 0, 0);
}

// ---------------- fp32 -> bf16 hi/lo split with channel padding ----------------
__global__ void split_pad_k(const float* __restrict__ in, __bf16* __restrict__ oh,
                            __bf16* __restrict__ ol, int CIN, int CINP, long n) {
  long i = (long)blockIdx.x * 256 + threadIdx.x;
  if (i >= n) return;
  long row = i / CINP; int ci = (int)(i - row * CINP);
  float v = (ci < CIN) ? in[row * CIN + ci] : 0.f;
  __bf16 h = (__bf16)v;
  oh[i] = h; ol[i] = (__bf16)(v - (float)h);
}

// ---------------- weight repack+split: w[N][CIN][K] -> oh/ol[N][k*CINP + ci] ----------------
__global__ void wsplit_k(const float* __restrict__ w, __bf16* __restrict__ oh,
                         __bf16* __restrict__ ol, int CIN, int K_, int CINP, long n) {
  long i = (long)blockIdx.x * 256 + threadIdx.x;
  if (i >= n) return;
  long kdspan = (long)K_ * CINP;
  long nn = i / kdspan; int kd = (int)(i - nn * kdspan);
  int k = kd / CINP, ci = kd - k * CINP;
  float v = (ci < CIN) ? w[(nn * CIN + ci) * K_ + k] : 0.f;
  __bf16 h = (__bf16)v;
  oh[i] = h; ol[i] = (__bf16)(v - (float)h);
}

// ---------------- transpose+split: w2 [m][JTOT] -> oh/ol [j][384] ----------------
__global__ void tsplit_k(const float* __restrict__ in, __bf16* __restrict__ oh,
                         __bf16* __restrict__ ol, int JTOT, long n) {
  long i = (long)blockIdx.x * 256 + threadIdx.x;
  if (i >= n) return;
  int m = (int)(i / JTOT), j = (int)(i - (long)m * JTOT);
  float v = in[i];
  long o = (long)j * 384 + m;
  __bf16 h = (__bf16)v;
  oh[o] = h; ol[o] = (__bf16)(v - (float)h);
}

// ---------------- bias fold: o[n] = sum_m wq[n][m] * b[m] ----------------
__global__ void fold_bias_k(const float* __restrict__ wq, const float* __restrict__ b,
                            float* __restrict__ o) {
  int n = threadIdx.x;
  float s = 0.f;
  for (int m = 0; m < 384; ++m) s = fmaf(wq[n * 384 + m], b[m], s);
  o[n] = s;
}

// ---------------- weight-fold GEMM (conv2-staging-native output layout) ----------------
template<int KK>
__global__ __launch_bounds__(256)
void fold_mfma(const __bf16* __restrict__ xh, const __bf16* __restrict__ xl,
               const __bf16* __restrict__ wh, const __bf16* __restrict__ wl,
               __bf16* __restrict__ oh, __bf16* __restrict__ ol)
{
  constexpr int CINP = 384, ROWS = 64, STRIDE = 65;
  __shared__ float4 xs[8 * STRIDE];
  const int t0 = blockIdx.x * 64, n0 = blockIdx.y * 128;
  const int tid = threadIdx.x, wn = tid >> 6, lane = tid & 63;
  const int lr = lane & 15, lg = lane >> 4;
  const f32x4 Z4 = {0.f, 0.f, 0.f, 0.f};
  f32x4 acc[4][2];
  #pragma unroll
  for (int m = 0; m < 4; ++m) { acc[m][0] = Z4; acc[m][1] = Z4; }

  #pragma unroll 1
  for (int ci0 = 0; ci0 < CINP; ci0 += 32) {
    __syncthreads();
    for (int e = tid; e < ROWS * 8; e += 256) {
      int row = e >> 3, sc = e & 7, spl = sc >> 2, cg = sc & 3;
      int t = t0 + row;
      xs[(spl * 4 + cg) * STRIDE + row] =
          *(const float4*)((spl ? xl : xh) + (size_t)t * CINP + ci0 + cg * 8);
    }
    __syncthreads();
    bf16x8 ah[4], al[4];
    #pragma unroll
    for (int mf = 0; mf < 4; ++mf) {
      int row = mf * 16 + lr;
      ah[mf] = *(const bf16x8*)&xs[lg * STRIDE + row];
      al[mf] = *(const bf16x8*)&xs[(4 + lg) * STRIDE + row];
    }
    size_t kd = (size_t)ci0 + lg * 8;
    bf16x8 bh[2], bl[2];
    #pragma unroll
    for (int nf = 0; nf < 2; ++nf) {
      int nc = n0 + wn * 32 + nf * 16 + lr;
      bh[nf] = *(const bf16x8*)(wh + (size_t)nc * 384 + kd);
      bl[nf] = *(const bf16x8*)(wl + (size_t)nc * 384 + kd);
    }
    #pragma unroll
    for (int nf = 0; nf < 2; ++nf)
      #pragma unroll
      for (int mf = 0; mf < 4; ++mf) acc[mf][nf] = mfma16(ah[mf], bh[nf], acc[mf][nf]);
    #pragma unroll
    for (int nf = 0; nf < 2; ++nf)
      #pragma unroll
      for (int mf = 0; mf < 4; ++mf) acc[mf][nf] = mfma16(ah[mf], bl[nf], acc[mf][nf]);
    #pragma unroll
    for (int nf = 0; nf < 2; ++nf)
      #pragma unroll
      for (int mf = 0; mf < 4; ++mf) acc[mf][nf] = mfma16(al[mf], bh[nf], acc[mf][nf]);
  }
  #pragma unroll
  for (int nf = 0; nf < 2; ++nf) {
    int c = n0 + wn * 32 + nf * 16 + lr;
    #pragma unroll
    for (int mf = 0; mf < 4; ++mf) {
      #pragma unroll
      for (int r = 0; r < 4; ++r) {
        int j = t0 + mf * 16 + lg * 4 + r;   // j = ci*KK + k
        int k = j % KK, ci = j / KK;
        size_t o = (size_t)((((ci >> 4) * KK + k) * 2 + ((ci >> 3) & 1)) * 3072)
                 + (size_t)c * 8 + (ci & 7);
        float v = acc[mf][nf][r];
        __bf16 vh = (__bf16)v;
        oh[o] = vh; ol[o] = (__bf16)(v - (float)vh);
      }
    }
  }
}

// ---------------- conv1 + ReGLU, split-bf16 MFMA ----------------
template<int CINP, int K, int T>
__global__ __launch_bounds__(256)
void conv1_mfma(const __bf16* __restrict__ xh, const __bf16* __restrict__ xl,
                const __bf16* __restrict__ wh, const __bf16* __restrict__ wl,
                const float* __restrict__ bias, const int* __restrict__ lens,
                __bf16* __restrict__ hh, __bf16* __restrict__ hl)
{
  constexpr int BM = 128, PAD = K / 2, ROWS = BM + K - 1, KD = K * CINP;
  __shared__ float4 xs[8 * ROWS];
  const int b = blockIdx.z, t0 = blockIdx.x * BM, n0 = blockIdx.y * 64;
  const int tid = threadIdx.x, wid = tid >> 6, lane = tid & 63;
  const int wm = wid >> 1, wn = wid & 1, lr = lane & 15, lg = lane >> 4;
  const int len = lens[b];
  const f32x4 Z4 = {0.f, 0.f, 0.f, 0.f};
  f32x4 acc_a[4][2], acc_g[4][2];
  #pragma unroll
  for (int m = 0; m < 4; ++m)
    #pragma unroll
    for (int n = 0; n < 2; ++n) { acc_a[m][n] = Z4; acc_g[m][n] = Z4; }

  #pragma unroll 1
  for (int ci0 = 0; ci0 < CINP; ci0 += 32) {
    __syncthreads();
    for (int e = tid; e < ROWS * 8; e += 256) {
      int row = e >> 3, sc = e & 7, spl = sc >> 2, cg = sc & 3;
      int t = t0 + row - PAD;
      float4 v = {0.f, 0.f, 0.f, 0.f};
      if (t >= 0 && t < len)
        v = *(const float4*)((spl ? xl : xh) + ((size_t)b * T + t) * CINP + ci0 + cg * 8);
      xs[(spl * 4 + cg) * ROWS + row] = v;
    }
    __syncthreads();
    #pragma unroll
    for (int k = 0; k < K; ++k) {
      bf16x8 ah[4], al[4];
      #pragma unroll
      for (int mf = 0; mf < 4; ++mf) {
        int row = wm * 64 + mf * 16 + lr + k;
        ah[mf] = *(const bf16x8*)&xs[lg * ROWS + row];
        al[mf] = *(const bf16x8*)&xs[(4 + lg) * ROWS + row];
      }
      size_t kd = (size_t)k * CINP + ci0 + lg * 8;
      #pragma unroll
      for (int nf = 0; nf < 2; ++nf) {
        int na = n0 + wn * 32 + nf * 16 + lr;
        bf16x8 bah = *(const bf16x8*)(wh + (size_t)na * KD + kd);
        bf16x8 bal = *(const bf16x8*)(wl + (size_t)na * KD + kd);
        bf16x8 bgh = *(const bf16x8*)(wh + (size_t)(na + HID) * KD + kd);
        bf16x8 bgl = *(const bf16x8*)(wl + (size_t)(na + HID) * KD + kd);
        #pragma unroll
        for (int mf = 0; mf < 4; ++mf) {
          acc_a[mf][nf] = mfma16(ah[mf], bah, acc_a[mf][nf]);
          acc_a[mf][nf] = mfma16(ah[mf], bal, acc_a[mf][nf]);
          acc_a[mf][nf] = mfma16(al[mf], bah, acc_a[mf][nf]);
          acc_g[mf][nf] = mfma16(ah[mf], bgh, acc_g[mf][nf]);
          acc_g[mf][nf] = mfma16(ah[mf], bgl, acc_g[mf][nf]);
          acc_g[mf][nf] = mfma16(al[mf], bgh, acc_g[mf][nf]);
        }
      }
    }
  }
  #pragma unroll
  for (int nf = 0; nf < 2; ++nf) {
    int c = n0 + wn * 32 + nf * 16 + lr;
    float ba = bias[c], bg = bias[c + HID];
    #pragma unroll
    for (int mf = 0; mf < 4; ++mf) {
      #pragma unroll
      for (int r = 0; r < 4; ++r) {
        int t = t0 + wm * 64 + mf * 16 + lg * 4 + r;
        if (t < T) {
          float a = acc_a[mf][nf][r] + ba;
          float g = acc_g[mf][nf][r] + bg;
          float v = a * fmaxf(g, 0.f);
          __bf16 vh = (__bf16)v;
          size_t o = ((size_t)b * T + t) * HID + c;
          hh[o] = vh;
          hl[o] = (__bf16)(v - (float)vh);
        }
      }
    }
  }
}

// ---------------- conv2 (folded weights), 32x32x16, B staged in LDS via global_load_lds ----------------
template<int K, int T, bool STORET>
__global__ __launch_bounds__(256)
void conv2_mfma(const __bf16* __restrict__ xh, const __bf16* __restrict__ xl,
                const __bf16* __restrict__ wh, const __bf16* __restrict__ wl,
                const float* __restrict__ bias, const float* __restrict__ ab,
                const int* __restrict__ lens, float* __restrict__ out)
{
  constexpr int CINP = 768, BM = 128, PAD = K / 2, ROWS = BM + K - 1, STRIDE = ROWS + 1;
  constexpr int BROWS = K * 2;
  __shared__ float4 xa[4 * STRIDE];
  __shared__ float4 bs[2 * BROWS * 192];
  const int b = blockIdx.z, t0 = blockIdx.x * BM, n0 = blockIdx.y * 192;
  const int tid = threadIdx.x, wid = tid >> 6, lane = tid & 63;
  const int wm = wid >> 1, wn = wid & 1, lc = lane & 31, lk = lane >> 5;
  const int len = lens[b];
  f32x16 acc[2][3];
  #pragma unroll
  for (int m = 0; m < 2; ++m)
    #pragma unroll
    for (int n = 0; n < 3; ++n)
      #pragma unroll
      for (int r = 0; r < 16; ++r) acc[m][n][r] = 0.f;

  #pragma unroll 1
  for (int s = 0; s < 48; ++s) {
    __syncthreads();
    for (int e = tid; e < ROWS * 4; e += 256) {
      int row = e >> 2, sc = e & 3, spl = sc >> 1, cg = sc & 1;
      int t = t0 + row - PAD;
      float4 v = {0.f, 0.f, 0.f, 0.f};
      if (t >= 0 && t < len)
        v = *(const float4*)((spl ? xl : xh) + ((size_t)b * T + t) * CINP + s * 16 + cg * 8);
      xa[(spl * 2 + cg) * STRIDE + row] = v;
    }
    for (int r = wid; r < 2 * BROWS; r += 4) {
      int spl = r / BROWS, rr = r - spl * BROWS;
      const char* src = (const char*)((spl ? wl : wh) + (size_t)(s * BROWS + rr) * 3072
                                      + (size_t)n0 * 8) + (size_t)lane * 16;
      char* dst = (char*)&bs[r * 192];
      #pragma unroll
      for (int i = 0; i < 3; ++i)
        __builtin_amdgcn_global_load_lds(
            (const __attribute__((address_space(1))) void*)(src + i * 1024),
            (__attribute__((address_space(3))) void*)(dst + i * 1024), 16, 0, 0);
    }
    __syncthreads();
    #pragma unroll
    for (int k = 0; k < K; ++k) {
      bf16x8 ah[2], al[2], bh[3], bl[3];
      #pragma unroll
      for (int mf = 0; mf < 2; ++mf) {
        int row = wm * 64 + mf * 32 + lc + k;
        ah[mf] = *(const bf16x8*)&xa[lk * STRIDE + row];
        al[mf] = *(const bf16x8*)&xa[(2 + lk) * STRIDE + row];
      }
      #pragma unroll
      for (int nf = 0; nf < 3; ++nf) {
        int col = wn * 96 + nf * 32 + lc;
        bh[nf] = *(const bf16x8*)&bs[(k * 2 + lk) * 192 + col];
        bl[nf] = *(const bf16x8*)&bs[(BROWS + k * 2 + lk) * 192 + col];
      }
      #pragma unroll
      for (int nf = 0; nf < 3; ++nf)
        #pragma unroll
        for (int mf = 0; mf < 2; ++mf)
          acc[mf][nf] = mfma32(ah[mf], bh[nf], acc[mf][nf]);
      #pragma unroll
      for (int nf = 0; nf < 3; ++nf)
        #pragma unroll
        for (int mf = 0; mf < 2; ++mf)
          acc[mf][nf] = mfma32(ah[mf], bl[nf], acc[mf][nf]);
      #pragma unroll
      for (int nf = 0; nf < 3; ++nf)
        #pragma unroll
        for (int mf = 0; mf < 2; ++mf)
          acc[mf][nf] = mfma32(al[mf], bh[nf], acc[mf][nf]);
    }
  }
  #pragma unroll
  for (int nf = 0; nf < 3; ++nf) {
    int c = n0 + wn * 96 + nf * 32 + lc;
    float bb = bias[c], aB = ab[c];
    #pragma unroll
    for (int mf = 0; mf < 2; ++mf) {
      #pragma unroll
      for (int r = 0; r < 16; ++r) {
        int t = t0 + wm * 64 + mf * 32 + (r & 3) + 8 * (r >> 2) + 4 * lk;
        if (t < T) {
          float v = acc[mf][nf][r] + bb;
          if (t >= len) v = 0.f;
          v += aB;
          if (STORET) out[((size_t)b * MAS + c) * T + t] = v;
          else        out[((size_t)b * T + t) * MAS + c] = v;
        }
      }
    }
  }
}

// ---------------- scores + softmax + safe_log ----------------
__global__ __launch_bounds__(512)
void scores_k(const float* __restrict__ q, const float* __restrict__ kT,
              const int* __restrict__ xl, const int* __restrict__ yl,
              float* __restrict__ oattn, float* __restrict__ ologp)
{
  __shared__ float qs[16 * 384];
  __shared__ float tmp[8];
  const int b = blockIdx.y, y0 = blockIdx.x * 16, tid = threadIdx.x;
  for (int e = tid; e < 16 * 384; e += 512)
    qs[e] = q[((size_t)b * TY + (y0 + e / 384)) * 384 + (e - (e / 384) * 384)];
  __syncthreads();
  float acc[16];
  #pragma unroll
  for (int i = 0; i < 16; ++i) acc[i] = 0.f;
  const int x = tid;
  if (x < TX) {
    const float* kb = kT + (size_t)b * MAS * TX + x;
    for (int d = 0; d < 384; d += 4) {
      float k0 = kb[(size_t)(d + 0) * TX], k1 = kb[(size_t)(d + 1) * TX];
      float k2 = kb[(size_t)(d + 2) * TX], k3 = kb[(size_t)(d + 3) * TX];
      #pragma unroll
      for (int yy = 0; yy < 16; ++yy) {
        float4 qv = *(const float4*)&qs[yy * 384 + d];
        acc[yy] = fmaf(qv.x, k0, fmaf(qv.y, k1, fmaf(qv.z, k2, fmaf(qv.w, k3, acc[yy]))));
      }
    }
  }
  const int xlen = xl[b], ylen = yl[b];
  const float scale = 0.05103103630798288f;
  const bool xpad = (x >= xlen);
  const int wv = tid >> 6, ln = tid & 63;
  #pragma unroll 1
  for (int yy = 0; yy < 16; ++yy) {
    int y = y0 + yy;
    float s = -3.0e38f;
    if (x < TX) {
      s = acc[yy] * scale;
      if (xpad && (y >= ylen)) s = -1e-9f;
    }
    float m = s;
    for (int off = 32; off; off >>= 1) m = fmaxf(m, __shfl_xor(m, off));
    if (ln == 0) tmp[wv] = m;
    __syncthreads();
    float mx = fmaxf(fmaxf(fmaxf(tmp[0], tmp[1]), fmaxf(tmp[2], tmp[3])),
                     fmaxf(fmaxf(tmp[4], tmp[5]), fmaxf(tmp[6], tmp[7])));
    __syncthreads();
    float e = (x < TX) ? expf(s - mx) : 0.f;
    float sm = e;
    for (int off = 32; off; off >>= 1) sm += __shfl_xor(sm, off);
    if (ln == 0) tmp[wv] = sm;
    __syncthreads();
    float tot = tmp[0] + tmp[1] + tmp[2] + tmp[3] + tmp[4] + tmp[5] + tmp[6] + tmp[7];
    __syncthreads();
    if (x < TX) {
      float w = e / tot;
      size_t o = ((size_t)b * TY + y) * TX + x;
      oattn[o] = w;
      ologp[o] = logf(w + 1e-6f);
    }
  }
}

// ---------------- MAS fused: gload_lds-streamed forward DP (loads-only vmcnt stream,
//                  bits in LDS) + in-LDS backtrack. One block/batch, 1 wave. ----------------
__global__ __launch_bounds__(64, 1)
void mas_k(const float* __restrict__ logprob, const int* __restrict__ xl,
           const int* __restrict__ yl, float* __restrict__ hard, float* __restrict__ dur)
{
  __shared__ float ring[12800];              // 2 slots x 16 rows x 400 floats = 51,200 B
  __shared__ unsigned char lbits[102400];    // [yblk 200][lane 64][8 rows] = 100 KB
  const int b = blockIdx.x;
  const int lane = threadIdx.x;
  const int xlen = xl[b], ylen = yl[b];
  const float* lpb = logprob + (size_t)b * TY * TX;
  const int p0 = lane * 8 - 4;
  int t;
  t = p0;     if (t < 0) t = 0; if (t > 396) t = 396; const int lb0 = t;
  t = p0 + 4; if (t < 0) t = 0; if (t > 396) t = 396; const int lb1 = t;
  t = p0 + 8; if (t < 0) t = 0; if (t > 396) t = 396; const int lb2 = t;

  float w[12], wxm[12];
  #pragma unroll
  for (int i = 0; i < 12; ++i) {
    int p = p0 + i;
    wxm[i] = (p >= 0 && p < xlen) ? 0.f : NEGV;
    w[i] = (p == 0) ? 0.f : NEGV;
  }

  const char* lpc = (const char*)lpb;
  constexpr size_t maxgs = (size_t)TY * 1600 - 25600;  // last in-bounds group start
  char* ringc = (char*)ring;
  auto issue_group = [&](int g) {
    size_t gs = (size_t)g * 25600; if (gs > maxgs) gs = maxgs;
    const char* src = lpc + gs + (size_t)lane * 16;
    char* dst = ringc + (g & 1) * 25600;
    #pragma unroll
    for (int i = 0; i < 25; ++i)
      __builtin_amdgcn_global_load_lds(
          (const __attribute__((address_space(1))) void*)(src + i * 1024),
          (__attribute__((address_space(3))) void*)(dst + i * 1024), 16, 0, 0);
  };

  issue_group(0);
  issue_group(1);

  const int ngroups = (ylen + 15) >> 4;
  #pragma unroll 1
  for (int g = 0; g < ngroups; ++g) {
    asm volatile("s_waitcnt vmcnt(25)" ::: "memory");   // group g landed; g+1 in flight
    __builtin_amdgcn_sched_barrier(0);
    const float* half = ring + (g & 1) * 6400;
    const int ybase = g * 16;
    const bool phase1 = (ybase < TX);                   // rows < 400 need x<=y mask
    unsigned long long bitsacc = 0ULL;
    #pragma unroll
    for (int d = 0; d < 4; ++d) {                       // 4 sub-blocks of 4 rows (halo=4)
      float h0 = __shfl_up(w[8], 1),  h1 = __shfl_up(w[9], 1);
      float h2 = __shfl_up(w[10], 1), h3 = __shfl_up(w[11], 1);
      w[0] = lane ? h0 : NEGV; w[1] = lane ? h1 : NEGV;
      w[2] = lane ? h2 : NEGV; w[3] = lane ? h3 : NEGV;
      #pragma unroll
      for (int r = 0; r < 4; ++r) {
        const int row = d * 4 + r;
        const int y = ybase + row;
        const float4 v0 = *(const float4*)&half[row * 400 + lb0];
        const float4 v1 = *(const float4*)&half[row * 400 + lb1];
        const float4 v2 = *(const float4*)&half[row * 400 + lb2];
        float lp[12] = {v0.x + wxm[0], v0.y + wxm[1], v0.z + wxm[2],  v0.w + wxm[3],
                        v1.x + wxm[4], v1.y + wxm[5], v1.z + wxm[6],  v1.w + wxm[7],
                        v2.x + wxm[8], v2.y + wxm[9], v2.z + wxm[10], v2.w + wxm[11]};
        if (phase1) {
          int c = y - p0;
          #pragma unroll
          for (int i = 0; i < 12; ++i) lp[i] = (i <= c) ? lp[i] : NEGV;
        }
        unsigned byte = 0;
        #pragma unroll
        for (int j = 0; j < 8; ++j)
          byte |= (w[j + 3] > w[j + 4]) ? (1u << j) : 0u;
        bitsacc |= (unsigned long long)byte << (((d & 1) * 4 + r) * 8);
        float nw[12];
        nw[0] = lp[0] + w[0];
        #pragma unroll
        for (int i = 1; i < 12; ++i) nw[i] = lp[i] + fmaxf(w[i], w[i - 1]);
        #pragma unroll
        for (int i = 0; i < 12; ++i) w[i] = nw[i];
      }
      if (d & 1) {
        *(unsigned long long*)&lbits[(size_t)((ybase >> 3) + (d >> 1)) * 512 + (size_t)lane * 8] = bitsacc;
        bitsacc = 0ULL;
      }
    }
    __builtin_amdgcn_sched_barrier(0);                  // keep refill after this slot's ds_reads
    issue_group(g + 2);                                 // overwrites the slot just consumed
  }

  __syncthreads();

  // backtrack: uniform scalar walk via readlane; window from LDS bits
  int x = xlen - 1;
  int cnt = 0;
  float* hb = hard + (size_t)b * TX * TY;
  float* db = dur + (size_t)b * TX;

  #pragma unroll 1
  for (int ycur = ylen - 1; ycur >= 0; ycur -= 64) {
    int lo = x - 63; if (lo < 0) lo = 0;
    const int wb = (lo >> 3) & ~3;                  // window bytes [wb, wb+12)
    int ry = ycur - lane;
    unsigned w0 = 0, w1 = 0, w2 = 0;
    if (ry >= 0) {
      const unsigned char* p = lbits + (size_t)(ry >> 3) * 512 + (ry & 7);
      unsigned bt_[12];
      #pragma unroll
      for (int j = 0; j < 12; ++j) bt_[j] = p[(size_t)(wb + j) * 8];
      w0 = bt_[0] | (bt_[1] << 8) | (bt_[2] << 16) | (bt_[3] << 24);
      w1 = bt_[4] | (bt_[5] << 8) | (bt_[6] << 16) | (bt_[7] << 24);
      w2 = bt_[8] | (bt_[9] << 8) | (bt_[10] << 16) | (bt_[11] << 24);
    }
    const int rows = (ycur + 1 < 64) ? (ycur + 1) : 64;
    #pragma unroll 1
    for (int s = 0; s < rows; s += 8) {
      const int cnt8 = (rows - s < 8) ? (rows - s) : 8;
      unsigned r0[8], r1[8], r2[8];
      #pragma unroll
      for (int u = 0; u < 8; ++u) {
        r0[u] = (unsigned)__builtin_amdgcn_readlane((int)w0, s + u);
        r1[u] = (unsigned)__builtin_amdgcn_readlane((int)w1, s + u);
        r2[u] = (unsigned)__builtin_amdgcn_readlane((int)w2, s + u);
      }
      #pragma unroll
      for (int u = 0; u < 8; ++u) {
        if (u < cnt8) {
          const int yy = ycur - s - u;
          ++cnt;
          if (yy > 0 && x > 0) {
            const int boff = (x >> 3) - wb;
            const unsigned word = (boff < 4) ? r0[u] : ((boff < 8) ? r1[u] : r2[u]);
            const unsigned byte = word >> ((boff & 3) * 8);
            if ((x == yy) || ((byte >> (x & 7)) & 1)) {
              for (int q = lane; q < cnt; q += 64) hb[(size_t)x * TY + yy + q] = 1.0f;
              if (lane == 0) db[x] = (float)cnt;
              cnt = 0;
              --x;
            }
          }
        }
      }
    }
  }
  for (int q = lane; q < cnt; q += 64) hb[(size_t)x * TY + q] = 1.0f;
  if (lane == 0) db[x] = (float)cnt;
}

extern "C" void kernel_launch(void* const* d_in, const int* in_sizes, int n_in,
                              void* d_out, int out_size, void* d_ws, size_t ws_size,
                              hipStream_t stream) {
  const float* mel_x  = (const float*)d_in[0];
  const float* txt_x  = (const float*)d_in[1];
  const float* mel_w1 = (const float*)d_in[2];
  const float* mel_b1 = (const float*)d_in[3];
  const float* mel_w2 = (const float*)d_in[4];
  const float* mel_b2 = (const float*)d_in[5];
  const float* txt_w1 = (const float*)d_in[6];
  const float* txt_b1 = (const float*)d_in[7];
  const float* txt_w2 = (const float*)d_in[8];
  const float* txt_b2 = (const float*)d_in[9];
  const float* wq     = (const float*)d_in[10];
  const float* bq     = (const float*)d_in[11];
  const float* wk     = (const float*)d_in[12];
  const float* bk     = (const float*)d_in[13];
  const int*   xl     = (const int*)d_in[14];
  const int*   yl     = (const int*)d_in[15];

  char* wsb = (char*)d_ws;
  constexpr size_t MXH   = 0;
  constexpr size_t MXL   = MXH   + 4915200;
  constexpr size_t TXH   = MXL   + 4915200;
  constexpr size_t TXL   = TXH   + 6553600;
  constexpr size_t KTF   = TXH;
  constexpr size_t WFMH  = TXL   + 6553600;
  constexpr size_t WFML  = WFMH  + 2949120;
  constexpr size_t WFTH  = WFML  + 2949120;
  constexpr size_t WFTL  = WFTH  + 1769472;
  constexpr size_t B2M   = WFTL  + 1769472;
  constexpr size_t B2T   = B2M   + 2048;
  constexpr size_t HH    = B2T   + 2048;
  constexpr size_t HL    = HH    + 39321600;
  constexpr size_t SCR   = HL    + 39321600;
  constexpr size_t W1MH  = SCR;
  constexpr size_t W1ML  = W1MH  + 1474560;
  constexpr size_t W1TH  = W1ML  + 1474560;
  constexpr size_t W1TL  = W1TH  + 4718592;
  constexpr size_t WQH   = W1TL  + 4718592;
  constexpr size_t WQL   = WQH   + 294912;
  constexpr size_t WKH   = WQL   + 294912;
  constexpr size_t WKL   = WKH   + 294912;
  constexpr size_t W2TMH = WKL   + 294912;
  constexpr size_t W2TML = W2TMH + 2949120;
  constexpr size_t W2TTH = W2TML + 2949120;
  constexpr size_t W2TTL = W2TTH + 1769472;
  constexpr size_t QF    = SCR;

  float* out = (float*)d_out;
  float* o_attn = out;
  float* o_logp = out + (size_t)10240000;
  float* o_hard = out + (size_t)20480000;
  float* o_dur  = out + (size_t)30720000;

  hipMemsetAsync(o_hard, 0, (size_t)(10240000 + 6400) * sizeof(float), stream);

  split_pad_k<<<9600, 256, 0, stream>>>(mel_x, (__bf16*)(wsb + MXH), (__bf16*)(wsb + MXL), 80, 96, 2457600L);
  split_pad_k<<<12800, 256, 0, stream>>>(txt_x, (__bf16*)(wsb + TXH), (__bf16*)(wsb + TXL), 512, 512, 3276800L);
  wsplit_k<<<2880, 256, 0, stream>>>(mel_w1, (__bf16*)(wsb + W1MH), (__bf16*)(wsb + W1ML), 80, 5, 96, 737280L);
  wsplit_k<<<9216, 256, 0, stream>>>(txt_w1, (__bf16*)(wsb + W1TH), (__bf16*)(wsb + W1TL), 512, 3, 512, 2359296L);
  wsplit_k<<<576, 256, 0, stream>>>(wq, (__bf16*)(wsb + WQH), (__bf16*)(wsb + WQL), 384, 1, 384, 147456L);
  wsplit_k<<<576, 256, 0, stream>>>(wk, (__bf16*)(wsb + WKH), (__bf16*)(wsb + WKL), 384, 1, 384, 147456L);
  tsplit_k<<<5760, 256, 0, stream>>>(mel_w2, (__bf16*)(wsb + W2TMH), (__bf16*)(wsb + W2TML), 3840, 1474560L);
  tsplit_k<<<3456, 256, 0, stream>>>(txt_w2, (__bf16*)(wsb + W2TTH), (__bf16*)(wsb + W2TTL), 2304, 884736L);
  fold_mfma<5><<<dim3(60, 3), 256, 0, stream>>>(
      (const __bf16*)(wsb + W2TMH), (const __bf16*)(wsb + W2TML),
      (const __bf16*)(wsb + WQH), (const __bf16*)(wsb + WQL),
      (__bf16*)(wsb + WFMH), (__bf16*)(wsb + WFML));
  fold_mfma<3><<<dim3(36, 3), 256, 0, stream>>>(
      (const __bf16*)(wsb + W2TTH), (const __bf16*)(wsb + W2TTL),
      (const __bf16*)(wsb + WKH), (const __bf16*)(wsb + WKL),
      (__bf16*)(wsb + WFTH), (__bf16*)(wsb + WFTL));
  fold_bias_k<<<1, 384, 0, stream>>>(wq, mel_b2, (float*)(wsb + B2M));
  fold_bias_k<<<1, 384, 0, stream>>>(wk, txt_b2, (float*)(wsb + B2T));

  // text pipeline: conv1 -> conv2(folded) writes kT directly
  conv1_mfma<512, 3, 400><<<dim3(4, 12, B), 256, 0, stream>>>(
      (const __bf16*)(wsb + TXH), (const __bf16*)(wsb + TXL),
      (const __bf16*)(wsb + W1TH), (const __bf16*)(wsb + W1TL),
      txt_b1, xl, (__bf16*)(wsb + HH), (__bf16*)(wsb + HL));
  conv2_mfma<3, 400, true><<<dim3(4, 2, B), 256, 0, stream>>>(
      (const __bf16*)(wsb + HH), (const __bf16*)(wsb + HL),
      (const __bf16*)(wsb + WFTH), (const __bf16*)(wsb + WFTL),
      (const float*)(wsb + B2T), bk, xl, (float*)(wsb + KTF));

  // mel pipeline: conv1 -> conv2(folded) writes q directly
  conv1_mfma<96, 5, 1600><<<dim3(13, 12, B), 256, 0, stream>>>(
      (const __bf16*)(wsb + MXH), (const __bf16*)(wsb + MXL),
      (const __bf16*)(wsb + W1MH), (const __bf16*)(wsb + W1ML),
      mel_b1, yl, (__bf16*)(wsb + HH), (__bf16*)(wsb + HL));
  conv2_mfma<5, 1600, false><<<dim3(13, 2, B), 256, 0, stream>>>(
      (const __bf16*)(wsb + HH), (const __bf16*)(wsb + HL),
      (const __bf16*)(wsb + WFMH), (const __bf16*)(wsb + WFML),
      (const float*)(wsb + B2M), bq, yl, (float*)(wsb + QF));

  // attention + MAS (fused fwd+bt, bits in LDS)
  scores_k<<<dim3(100, B), 512, 0, stream>>>(
      (const float*)(wsb + QF), (const float*)(wsb + KTF), xl, yl, o_attn, o_logp);
  mas_k<<<B, 64, 0, stream>>>(o_logp, xl, yl, o_hard, o_dur);
}

// Round 14
// 1500.533 us; speedup vs baseline: 1.2517x; 1.0186x over previous
//
#include <hip/hip_runtime.h>
#include <cstdint>

#define B 16
#define TY 1600
#define TX 400
#define MAS 384
#define HID 768
#define NEGV -1e9f

typedef __bf16 bf16x8 __attribute__((ext_vector_type(8)));
typedef float  f32x4  __attribute__((ext_vector_type(4)));
typedef float  f32x16 __attribute__((ext_vector_type(16)));

__device__ __forceinline__ f32x4 mfma16(bf16x8 a, bf16x8 b, f32x4 c) {
  return __builtin_amdgcn_mfma_f32_16x16x32_bf16(a, b, c, 0, 0, 0);
}
__device__ __forceinline__ f32x16 mfma32(bf16x8 a, bf16x8 b, f32x16 c) {
  return __builtin_amdgcn_mfma_f32_32x32x16_bf16(a, b, c, 0, 0, 0);
}

// ---------------- fp32 -> bf16 hi/lo split with channel padding ----------------
__global__ void split_pad_k(const float* __restrict__ in, __bf16* __restrict__ oh,
                            __bf16* __restrict__ ol, int CIN, int CINP, long n) {
  long i = (long)blockIdx.x * 256 + threadIdx.x;
  if (i >= n) return;
  long row = i / CINP; int ci = (int)(i - row * CINP);
  float v = (ci < CIN) ? in[row * CIN + ci] : 0.f;
  __bf16 h = (__bf16)v;
  oh[i] = h; ol[i] = (__bf16)(v - (float)h);
}

// ---------------- weight repack+split: w[N][CIN][K] -> oh/ol[N][k*CINP + ci] ----------------
__global__ void wsplit_k(const float* __restrict__ w, __bf16* __restrict__ oh,
                         __bf16* __restrict__ ol, int CIN, int K_, int CINP, long n) {
  long i = (long)blockIdx.x * 256 + threadIdx.x;
  if (i >= n) return;
  long kdspan = (long)K_ * CINP;
  long nn = i / kdspan; int kd = (int)(i - nn * kdspan);
  int k = kd / CINP, ci = kd - k * CINP;
  float v = (ci < CIN) ? w[(nn * CIN + ci) * K_ + k] : 0.f;
  __bf16 h = (__bf16)v;
  oh[i] = h; ol[i] = (__bf16)(v - (float)h);
}

// ---------------- transpose+split: w2 [m][JTOT] -> oh/ol [j][384] ----------------
__global__ void tsplit_k(const float* __restrict__ in, __bf16* __restrict__ oh,
                         __bf16* __restrict__ ol, int JTOT, long n) {
  long i = (long)blockIdx.x * 256 + threadIdx.x;
  if (i >= n) return;
  int m = (int)(i / JTOT), j = (int)(i - (long)m * JTOT);
  float v = in[i];
  long o = (long)j * 384 + m;
  __bf16 h = (__bf16)v;
  oh[o] = h; ol[o] = (__bf16)(v - (float)h);
}

// ---------------- bias fold: o[n] = sum_m wq[n][m] * b[m] ----------------
__global__ void fold_bias_k(const float* __restrict__ wq, const float* __restrict__ b,
                            float* __restrict__ o) {
  int n = threadIdx.x;
  float s = 0.f;
  for (int m = 0; m < 384; ++m) s = fmaf(wq[n * 384 + m], b[m], s);
  o[n] = s;
}

// ---------------- weight-fold GEMM (conv2-staging-native output layout) ----------------
template<int KK>
__global__ __launch_bounds__(256)
void fold_mfma(const __bf16* __restrict__ xh, const __bf16* __restrict__ xl,
               const __bf16* __restrict__ wh, const __bf16* __restrict__ wl,
               __bf16* __restrict__ oh, __bf16* __restrict__ ol)
{
  constexpr int CINP = 384, ROWS = 64, STRIDE = 65;
  __shared__ float4 xs[8 * STRIDE];
  const int t0 = blockIdx.x * 64, n0 = blockIdx.y * 128;
  const int tid = threadIdx.x, wn = tid >> 6, lane = tid & 63;
  const int lr = lane & 15, lg = lane >> 4;
  const f32x4 Z4 = {0.f, 0.f, 0.f, 0.f};
  f32x4 acc[4][2];
  #pragma unroll
  for (int m = 0; m < 4; ++m) { acc[m][0] = Z4; acc[m][1] = Z4; }

  #pragma unroll 1
  for (int ci0 = 0; ci0 < CINP; ci0 += 32) {
    __syncthreads();
    for (int e = tid; e < ROWS * 8; e += 256) {
      int row = e >> 3, sc = e & 7, spl = sc >> 2, cg = sc & 3;
      int t = t0 + row;
      xs[(spl * 4 + cg) * STRIDE + row] =
          *(const float4*)((spl ? xl : xh) + (size_t)t * CINP + ci0 + cg * 8);
    }
    __syncthreads();
    bf16x8 ah[4], al[4];
    #pragma unroll
    for (int mf = 0; mf < 4; ++mf) {
      int row = mf * 16 + lr;
      ah[mf] = *(const bf16x8*)&xs[lg * STRIDE + row];
      al[mf] = *(const bf16x8*)&xs[(4 + lg) * STRIDE + row];
    }
    size_t kd = (size_t)ci0 + lg * 8;
    bf16x8 bh[2], bl[2];
    #pragma unroll
    for (int nf = 0; nf < 2; ++nf) {
      int nc = n0 + wn * 32 + nf * 16 + lr;
      bh[nf] = *(const bf16x8*)(wh + (size_t)nc * 384 + kd);
      bl[nf] = *(const bf16x8*)(wl + (size_t)nc * 384 + kd);
    }
    #pragma unroll
    for (int nf = 0; nf < 2; ++nf)
      #pragma unroll
      for (int mf = 0; mf < 4; ++mf) acc[mf][nf] = mfma16(ah[mf], bh[nf], acc[mf][nf]);
    #pragma unroll
    for (int nf = 0; nf < 2; ++nf)
      #pragma unroll
      for (int mf = 0; mf < 4; ++mf) acc[mf][nf] = mfma16(ah[mf], bl[nf], acc[mf][nf]);
    #pragma unroll
    for (int nf = 0; nf < 2; ++nf)
      #pragma unroll
      for (int mf = 0; mf < 4; ++mf) acc[mf][nf] = mfma16(al[mf], bh[nf], acc[mf][nf]);
  }
  #pragma unroll
  for (int nf = 0; nf < 2; ++nf) {
    int c = n0 + wn * 32 + nf * 16 + lr;
    #pragma unroll
    for (int mf = 0; mf < 4; ++mf) {
      #pragma unroll
      for (int r = 0; r < 4; ++r) {
        int j = t0 + mf * 16 + lg * 4 + r;   // j = ci*KK + k
        int k = j % KK, ci = j / KK;
        size_t o = (size_t)((((ci >> 4) * KK + k) * 2 + ((ci >> 3) & 1)) * 3072)
                 + (size_t)c * 8 + (ci & 7);
        float v = acc[mf][nf][r];
        __bf16 vh = (__bf16)v;
        oh[o] = vh; ol[o] = (__bf16)(v - (float)vh);
      }
    }
  }
}

// ---------------- conv1 + ReGLU, split-bf16 MFMA ----------------
template<int CINP, int K, int T>
__global__ __launch_bounds__(256)
void conv1_mfma(const __bf16* __restrict__ xh, const __bf16* __restrict__ xl,
                const __bf16* __restrict__ wh, const __bf16* __restrict__ wl,
                const float* __restrict__ bias, const int* __restrict__ lens,
                __bf16* __restrict__ hh, __bf16* __restrict__ hl)
{
  constexpr int BM = 128, PAD = K / 2, ROWS = BM + K - 1, KD = K * CINP;
  __shared__ float4 xs[8 * ROWS];
  const int b = blockIdx.z, t0 = blockIdx.x * BM, n0 = blockIdx.y * 64;
  const int tid = threadIdx.x, wid = tid >> 6, lane = tid & 63;
  const int wm = wid >> 1, wn = wid & 1, lr = lane & 15, lg = lane >> 4;
  const int len = lens[b];
  const f32x4 Z4 = {0.f, 0.f, 0.f, 0.f};
  f32x4 acc_a[4][2], acc_g[4][2];
  #pragma unroll
  for (int m = 0; m < 4; ++m)
    #pragma unroll
    for (int n = 0; n < 2; ++n) { acc_a[m][n] = Z4; acc_g[m][n] = Z4; }

  #pragma unroll 1
  for (int ci0 = 0; ci0 < CINP; ci0 += 32) {
    __syncthreads();
    for (int e = tid; e < ROWS * 8; e += 256) {
      int row = e >> 3, sc = e & 7, spl = sc >> 2, cg = sc & 3;
      int t = t0 + row - PAD;
      float4 v = {0.f, 0.f, 0.f, 0.f};
      if (t >= 0 && t < len)
        v = *(const float4*)((spl ? xl : xh) + ((size_t)b * T + t) * CINP + ci0 + cg * 8);
      xs[(spl * 4 + cg) * ROWS + row] = v;
    }
    __syncthreads();
    #pragma unroll
    for (int k = 0; k < K; ++k) {
      bf16x8 ah[4], al[4];
      #pragma unroll
      for (int mf = 0; mf < 4; ++mf) {
        int row = wm * 64 + mf * 16 + lr + k;
        ah[mf] = *(const bf16x8*)&xs[lg * ROWS + row];
        al[mf] = *(const bf16x8*)&xs[(4 + lg) * ROWS + row];
      }
      size_t kd = (size_t)k * CINP + ci0 + lg * 8;
      #pragma unroll
      for (int nf = 0; nf < 2; ++nf) {
        int na = n0 + wn * 32 + nf * 16 + lr;
        bf16x8 bah = *(const bf16x8*)(wh + (size_t)na * KD + kd);
        bf16x8 bal = *(const bf16x8*)(wl + (size_t)na * KD + kd);
        bf16x8 bgh = *(const bf16x8*)(wh + (size_t)(na + HID) * KD + kd);
        bf16x8 bgl = *(const bf16x8*)(wl + (size_t)(na + HID) * KD + kd);
        #pragma unroll
        for (int mf = 0; mf < 4; ++mf) {
          acc_a[mf][nf] = mfma16(ah[mf], bah, acc_a[mf][nf]);
          acc_a[mf][nf] = mfma16(ah[mf], bal, acc_a[mf][nf]);
          acc_a[mf][nf] = mfma16(al[mf], bah, acc_a[mf][nf]);
          acc_g[mf][nf] = mfma16(ah[mf], bgh, acc_g[mf][nf]);
          acc_g[mf][nf] = mfma16(ah[mf], bgl, acc_g[mf][nf]);
          acc_g[mf][nf] = mfma16(al[mf], bgh, acc_g[mf][nf]);
        }
      }
    }
  }
  #pragma unroll
  for (int nf = 0; nf < 2; ++nf) {
    int c = n0 + wn * 32 + nf * 16 + lr;
    float ba = bias[c], bg = bias[c + HID];
    #pragma unroll
    for (int mf = 0; mf < 4; ++mf) {
      #pragma unroll
      for (int r = 0; r < 4; ++r) {
        int t = t0 + wm * 64 + mf * 16 + lg * 4 + r;
        if (t < T) {
          float a = acc_a[mf][nf][r] + ba;
          float g = acc_g[mf][nf][r] + bg;
          float v = a * fmaxf(g, 0.f);
          __bf16 vh = (__bf16)v;
          size_t o = ((size_t)b * T + t) * HID + c;
          hh[o] = vh;
          hl[o] = (__bf16)(v - (float)vh);
        }
      }
    }
  }
}

// ---------------- conv2 (folded weights), 32x32x16, B staged in LDS via global_load_lds ----------------
template<int K, int T, bool STORET>
__global__ __launch_bounds__(256)
void conv2_mfma(const __bf16* __restrict__ xh, const __bf16* __restrict__ xl,
                const __bf16* __restrict__ wh, const __bf16* __restrict__ wl,
                const float* __restrict__ bias, const float* __restrict__ ab,
                const int* __restrict__ lens, float* __restrict__ out)
{
  constexpr int CINP = 768, BM = 128, PAD = K / 2, ROWS = BM + K - 1, STRIDE = ROWS + 1;
  constexpr int BROWS = K * 2;
  __shared__ float4 xa[4 * STRIDE];
  __shared__ float4 bs[2 * BROWS * 192];
  const int b = blockIdx.z, t0 = blockIdx.x * BM, n0 = blockIdx.y * 192;
  const int tid = threadIdx.x, wid = tid >> 6, lane = tid & 63;
  const int wm = wid >> 1, wn = wid & 1, lc = lane & 31, lk = lane >> 5;
  const int len = lens[b];
  f32x16 acc[2][3];
  #pragma unroll
  for (int m = 0; m < 2; ++m)
    #pragma unroll
    for (int n = 0; n < 3; ++n)
      #pragma unroll
      for (int r = 0; r < 16; ++r) acc[m][n][r] = 0.f;

  #pragma unroll 1
  for (int s = 0; s < 48; ++s) {
    __syncthreads();
    for (int e = tid; e < ROWS * 4; e += 256) {
      int row = e >> 2, sc = e & 3, spl = sc >> 1, cg = sc & 1;
      int t = t0 + row - PAD;
      float4 v = {0.f, 0.f, 0.f, 0.f};
      if (t >= 0 && t < len)
        v = *(const float4*)((spl ? xl : xh) + ((size_t)b * T + t) * CINP + s * 16 + cg * 8);
      xa[(spl * 2 + cg) * STRIDE + row] = v;
    }
    for (int r = wid; r < 2 * BROWS; r += 4) {
      int spl = r / BROWS, rr = r - spl * BROWS;
      const char* src = (const char*)((spl ? wl : wh) + (size_t)(s * BROWS + rr) * 3072
                                      + (size_t)n0 * 8) + (size_t)lane * 16;
      char* dst = (char*)&bs[r * 192];
      #pragma unroll
      for (int i = 0; i < 3; ++i)
        __builtin_amdgcn_global_load_lds(
            (const __attribute__((address_space(1))) void*)(src + i * 1024),
            (__attribute__((address_space(3))) void*)(dst + i * 1024), 16, 0, 0);
    }
    __syncthreads();
    #pragma unroll
    for (int k = 0; k < K; ++k) {
      bf16x8 ah[2], al[2], bh[3], bl[3];
      #pragma unroll
      for (int mf = 0; mf < 2; ++mf) {
        int row = wm * 64 + mf * 32 + lc + k;
        ah[mf] = *(const bf16x8*)&xa[lk * STRIDE + row];
        al[mf] = *(const bf16x8*)&xa[(2 + lk) * STRIDE + row];
      }
      #pragma unroll
      for (int nf = 0; nf < 3; ++nf) {
        int col = wn * 96 + nf * 32 + lc;
        bh[nf] = *(const bf16x8*)&bs[(k * 2 + lk) * 192 + col];
        bl[nf] = *(const bf16x8*)&bs[(BROWS + k * 2 + lk) * 192 + col];
      }
      #pragma unroll
      for (int nf = 0; nf < 3; ++nf)
        #pragma unroll
        for (int mf = 0; mf < 2; ++mf)
          acc[mf][nf] = mfma32(ah[mf], bh[nf], acc[mf][nf]);
      #pragma unroll
      for (int nf = 0; nf < 3; ++nf)
        #pragma unroll
        for (int mf = 0; mf < 2; ++mf)
          acc[mf][nf] = mfma32(ah[mf], bl[nf], acc[mf][nf]);
      #pragma unroll
      for (int nf = 0; nf < 3; ++nf)
        #pragma unroll
        for (int mf = 0; mf < 2; ++mf)
          acc[mf][nf] = mfma32(al[mf], bh[nf], acc[mf][nf]);
    }
  }
  #pragma unroll
  for (int nf = 0; nf < 3; ++nf) {
    int c = n0 + wn * 96 + nf * 32 + lc;
    float bb = bias[c], aB = ab[c];
    #pragma unroll
    for (int mf = 0; mf < 2; ++mf) {
      #pragma unroll
      for (int r = 0; r < 16; ++r) {
        int t = t0 + wm * 64 + mf * 32 + (r & 3) + 8 * (r >> 2) + 4 * lk;
        if (t < T) {
          float v = acc[mf][nf][r] + bb;
          if (t >= len) v = 0.f;
          v += aB;
          if (STORET) out[((size_t)b * MAS + c) * T + t] = v;
          else        out[((size_t)b * T + t) * MAS + c] = v;
        }
      }
    }
  }
}

// ---------------- scores + softmax + safe_log ----------------
__global__ __launch_bounds__(512)
void scores_k(const float* __restrict__ q, const float* __restrict__ kT,
              const int* __restrict__ xl, const int* __restrict__ yl,
              float* __restrict__ oattn, float* __restrict__ ologp)
{
  __shared__ float qs[16 * 384];
  __shared__ float tmp[8];
  const int b = blockIdx.y, y0 = blockIdx.x * 16, tid = threadIdx.x;
  for (int e = tid; e < 16 * 384; e += 512)
    qs[e] = q[((size_t)b * TY + (y0 + e / 384)) * 384 + (e - (e / 384) * 384)];
  __syncthreads();
  float acc[16];
  #pragma unroll
  for (int i = 0; i < 16; ++i) acc[i] = 0.f;
  const int x = tid;
  if (x < TX) {
    const float* kb = kT + (size_t)b * MAS * TX + x;
    for (int d = 0; d < 384; d += 4) {
      float k0 = kb[(size_t)(d + 0) * TX], k1 = kb[(size_t)(d + 1) * TX];
      float k2 = kb[(size_t)(d + 2) * TX], k3 = kb[(size_t)(d + 3) * TX];
      #pragma unroll
      for (int yy = 0; yy < 16; ++yy) {
        float4 qv = *(const float4*)&qs[yy * 384 + d];
        acc[yy] = fmaf(qv.x, k0, fmaf(qv.y, k1, fmaf(qv.z, k2, fmaf(qv.w, k3, acc[yy]))));
      }
    }
  }
  const int xlen = xl[b], ylen = yl[b];
  const float scale = 0.05103103630798288f;
  const bool xpad = (x >= xlen);
  const int wv = tid >> 6, ln = tid & 63;
  #pragma unroll 1
  for (int yy = 0; yy < 16; ++yy) {
    int y = y0 + yy;
    float s = -3.0e38f;
    if (x < TX) {
      s = acc[yy] * scale;
      if (xpad && (y >= ylen)) s = -1e-9f;
    }
    float m = s;
    for (int off = 32; off; off >>= 1) m = fmaxf(m, __shfl_xor(m, off));
    if (ln == 0) tmp[wv] = m;
    __syncthreads();
    float mx = fmaxf(fmaxf(fmaxf(tmp[0], tmp[1]), fmaxf(tmp[2], tmp[3])),
                     fmaxf(fmaxf(tmp[4], tmp[5]), fmaxf(tmp[6], tmp[7])));
    __syncthreads();
    float e = (x < TX) ? expf(s - mx) : 0.f;
    float sm = e;
    for (int off = 32; off; off >>= 1) sm += __shfl_xor(sm, off);
    if (ln == 0) tmp[wv] = sm;
    __syncthreads();
    float tot = tmp[0] + tmp[1] + tmp[2] + tmp[3] + tmp[4] + tmp[5] + tmp[6] + tmp[7];
    __syncthreads();
    if (x < TX) {
      float w = e / tot;
      size_t o = ((size_t)b * TY + y) * TX + x;
      oattn[o] = w;
      ologp[o] = logf(w + 1e-6f);
    }
  }
}

// ---------------- MAS fused: LDS-ring forward DP with 3-row register lookahead
//                  (4 rotating float4-sets, sched_barrier-pinned) + in-LDS backtrack ----------------
#define MLOAD(row_, S0, S1, S2) do {                        \
    const float* rp_ = half + (row_) * 400;                 \
    S0 = *(const float4*)(rp_ + lb0);                       \
    S1 = *(const float4*)(rp_ + lb1);                       \
    S2 = *(const float4*)(rp_ + lb2);                       \
  } while (0)

#define MSHFL() do {                                        \
    float h0 = __shfl_up(w[8], 1),  h1 = __shfl_up(w[9], 1);   \
    float h2 = __shfl_up(w[10], 1), h3 = __shfl_up(w[11], 1);  \
    w[0] = lane ? h0 : NEGV; w[1] = lane ? h1 : NEGV;          \
    w[2] = lane ? h2 : NEGV; w[3] = lane ? h3 : NEGV;          \
  } while (0)

#define MROW(r_, S0, S1, S2) do {                           \
    const int y_ = ybase + (r_);                            \
    float lp[12] = {S0.x + wxm[0], S0.y + wxm[1], S0.z + wxm[2],  S0.w + wxm[3],   \
                    S1.x + wxm[4], S1.y + wxm[5], S1.z + wxm[6],  S1.w + wxm[7],   \
                    S2.x + wxm[8], S2.y + wxm[9], S2.z + wxm[10], S2.w + wxm[11]}; \
    if (phase1) {                                           \
      int c_ = y_ - p0;                                     \
      _Pragma("unroll")                                     \
      for (int i_ = 0; i_ < 12; ++i_) lp[i_] = (i_ <= c_) ? lp[i_] : NEGV; \
    }                                                       \
    unsigned byte_ = 0;                                     \
    _Pragma("unroll")                                       \
    for (int j_ = 0; j_ < 8; ++j_)                          \
      byte_ |= (w[j_ + 3] > w[j_ + 4]) ? (1u << j_) : 0u;   \
    bitsacc |= (unsigned long long)byte_ << (((r_) & 7) * 8); \
    float nw[12];                                           \
    nw[0] = lp[0] + w[0];                                   \
    _Pragma("unroll")                                       \
    for (int i_ = 1; i_ < 12; ++i_) nw[i_] = lp[i_] + fmaxf(w[i_], w[i_ - 1]); \
    _Pragma("unroll")                                       \
    for (int i_ = 0; i_ < 12; ++i_) w[i_] = nw[i_];         \
  } while (0)

#define MBITS(r_) do {                                      \
    *(unsigned long long*)&lbits[(size_t)((ybase >> 3) + ((r_) >> 3)) * 512 + (size_t)lane * 8] = bitsacc; \
    bitsacc = 0ULL;                                         \
  } while (0)

#define SBAR() __builtin_amdgcn_sched_barrier(0)

__global__ __launch_bounds__(64, 1)
void mas_k(const float* __restrict__ logprob, const int* __restrict__ xl,
           const int* __restrict__ yl, float* __restrict__ hard, float* __restrict__ dur)
{
  __shared__ float ring[12800];              // 2 slots x 16 rows x 400 floats
  __shared__ unsigned char lbits[102400];    // [yblk 200][lane 64][8 rows]
  const int b = blockIdx.x;
  const int lane = threadIdx.x;
  const int xlen = xl[b], ylen = yl[b];
  const float* lpb = logprob + (size_t)b * TY * TX;
  const int p0 = lane * 8 - 4;
  int t;
  t = p0;     if (t < 0) t = 0; if (t > 396) t = 396; const int lb0 = t;
  t = p0 + 4; if (t < 0) t = 0; if (t > 396) t = 396; const int lb1 = t;
  t = p0 + 8; if (t < 0) t = 0; if (t > 396) t = 396; const int lb2 = t;

  float w[12], wxm[12];
  #pragma unroll
  for (int i = 0; i < 12; ++i) {
    int p = p0 + i;
    wxm[i] = (p >= 0 && p < xlen) ? 0.f : NEGV;
    w[i] = (p == 0) ? 0.f : NEGV;
  }

  const char* lpc = (const char*)lpb;
  constexpr size_t maxgs = (size_t)TY * 1600 - 25600;
  char* ringc = (char*)ring;
  auto issue_group = [&](int g) {
    size_t gs = (size_t)g * 25600; if (gs > maxgs) gs = maxgs;
    const char* src = lpc + gs + (size_t)lane * 16;
    char* dst = ringc + (g & 1) * 25600;
    #pragma unroll
    for (int i = 0; i < 25; ++i)
      __builtin_amdgcn_global_load_lds(
          (const __attribute__((address_space(1))) void*)(src + i * 1024),
          (__attribute__((address_space(3))) void*)(dst + i * 1024), 16, 0, 0);
  };

  issue_group(0);
  issue_group(1);

  const int ngroups = (ylen + 15) >> 4;
  #pragma unroll 1
  for (int g = 0; g < ngroups; ++g) {
    asm volatile("s_waitcnt vmcnt(25)" ::: "memory");   // group g landed; g+1 in flight
    SBAR();
    const float* half = ring + (g & 1) * 6400;
    const int ybase = g * 16;
    const bool phase1 = (ybase < TX);
    unsigned long long bitsacc = 0ULL;
    float4 a0, a1, a2, b0, b1, b2, c0, c1, c2, d0, d1, d2;
    MLOAD(0, a0, a1, a2); MLOAD(1, b0, b1, b2); MLOAD(2, c0, c1, c2); SBAR();
    MSHFL();
    MLOAD(3, d0, d1, d2);  SBAR(); MROW(0,  a0, a1, a2);
    MLOAD(4, a0, a1, a2);  SBAR(); MROW(1,  b0, b1, b2);
    MLOAD(5, b0, b1, b2);  SBAR(); MROW(2,  c0, c1, c2);
    MLOAD(6, c0, c1, c2);  SBAR(); MROW(3,  d0, d1, d2);
    MSHFL();
    MLOAD(7, d0, d1, d2);  SBAR(); MROW(4,  a0, a1, a2);
    MLOAD(8, a0, a1, a2);  SBAR(); MROW(5,  b0, b1, b2);
    MLOAD(9, b0, b1, b2);  SBAR(); MROW(6,  c0, c1, c2);
    MLOAD(10, c0, c1, c2); SBAR(); MROW(7,  d0, d1, d2); MBITS(7);
    MSHFL();
    MLOAD(11, d0, d1, d2); SBAR(); MROW(8,  a0, a1, a2);
    MLOAD(12, a0, a1, a2); SBAR(); MROW(9,  b0, b1, b2);
    MLOAD(13, b0, b1, b2); SBAR(); MROW(10, c0, c1, c2);
    MLOAD(14, c0, c1, c2); SBAR(); MROW(11, d0, d1, d2);
    MSHFL();
    MLOAD(15, d0, d1, d2); SBAR(); MROW(12, a0, a1, a2);
    MROW(13, b0, b1, b2);
    MROW(14, c0, c1, c2);
    MROW(15, d0, d1, d2); MBITS(15);
    SBAR();
    issue_group(g + 2);
  }

  __syncthreads();

  // backtrack: uniform scalar walk via readlane; window from LDS bits
  int x = xlen - 1;
  int cnt = 0;
  float* hb = hard + (size_t)b * TX * TY;
  float* db = dur + (size_t)b * TX;

  #pragma unroll 1
  for (int ycur = ylen - 1; ycur >= 0; ycur -= 64) {
    int lo = x - 63; if (lo < 0) lo = 0;
    const int wb = (lo >> 3) & ~3;
    int ry = ycur - lane;
    unsigned w0 = 0, w1 = 0, w2 = 0;
    if (ry >= 0) {
      const unsigned char* p = lbits + (size_t)(ry >> 3) * 512 + (ry & 7);
      unsigned bt_[12];
      #pragma unroll
      for (int j = 0; j < 12; ++j) bt_[j] = p[(size_t)(wb + j) * 8];
      w0 = bt_[0] | (bt_[1] << 8) | (bt_[2] << 16) | (bt_[3] << 24);
      w1 = bt_[4] | (bt_[5] << 8) | (bt_[6] << 16) | (bt_[7] << 24);
      w2 = bt_[8] | (bt_[9] << 8) | (bt_[10] << 16) | (bt_[11] << 24);
    }
    const int rows = (ycur + 1 < 64) ? (ycur + 1) : 64;
    #pragma unroll 1
    for (int s = 0; s < rows; s += 8) {
      const int cnt8 = (rows - s < 8) ? (rows - s) : 8;
      unsigned r0[8], r1[8], r2[8];
      #pragma unroll
      for (int u = 0; u < 8; ++u) {
        r0[u] = (unsigned)__builtin_amdgcn_readlane((int)w0, s + u);
        r1[u] = (unsigned)__builtin_amdgcn_readlane((int)w1, s + u);
        r2[u] = (unsigned)__builtin_amdgcn_readlane((int)w2, s + u);
      }
      #pragma unroll
      for (int u = 0; u < 8; ++u) {
        if (u < cnt8) {
          const int yy = ycur - s - u;
          ++cnt;
          if (yy > 0 && x > 0) {
            const int boff = (x >> 3) - wb;
            const unsigned word = (boff < 4) ? r0[u] : ((boff < 8) ? r1[u] : r2[u]);
            const unsigned byte = word >> ((boff & 3) * 8);
            if ((x == yy) || ((byte >> (x & 7)) & 1)) {
              for (int q = lane; q < cnt; q += 64) hb[(size_t)x * TY + yy + q] = 1.0f;
              if (lane == 0) db[x] = (float)cnt;
              cnt = 0;
              --x;
            }
          }
        }
      }
    }
  }
  for (int q = lane; q < cnt; q += 64) hb[(size_t)x * TY + q] = 1.0f;
  if (lane == 0) db[x] = (float)cnt;
}

extern "C" void kernel_launch(void* const* d_in, const int* in_sizes, int n_in,
                              void* d_out, int out_size, void* d_ws, size_t ws_size,
                              hipStream_t stream) {
  const float* mel_x  = (const float*)d_in[0];
  const float* txt_x  = (const float*)d_in[1];
  const float* mel_w1 = (const float*)d_in[2];
  const float* mel_b1 = (const float*)d_in[3];
  const float* mel_w2 = (const float*)d_in[4];
  const float* mel_b2 = (const float*)d_in[5];
  const float* txt_w1 = (const float*)d_in[6];
  const float* txt_b1 = (const float*)d_in[7];
  const float* txt_w2 = (const float*)d_in[8];
  const float* txt_b2 = (const float*)d_in[9];
  const float* wq     = (const float*)d_in[10];
  const float* bq     = (const float*)d_in[11];
  const float* wk     = (const float*)d_in[12];
  const float* bk     = (const float*)d_in[13];
  const int*   xl     = (const int*)d_in[14];
  const int*   yl     = (const int*)d_in[15];

  char* wsb = (char*)d_ws;
  constexpr size_t MXH   = 0;
  constexpr size_t MXL   = MXH   + 4915200;
  constexpr size_t TXH   = MXL   + 4915200;
  constexpr size_t TXL   = TXH   + 6553600;
  constexpr size_t KTF   = TXH;
  constexpr size_t WFMH  = TXL   + 6553600;
  constexpr size_t WFML  = WFMH  + 2949120;
  constexpr size_t WFTH  = WFML  + 2949120;
  constexpr size_t WFTL  = WFTH  + 1769472;
  constexpr size_t B2M   = WFTL  + 1769472;
  constexpr size_t B2T   = B2M   + 2048;
  constexpr size_t HH    = B2T   + 2048;
  constexpr size_t HL    = HH    + 39321600;
  constexpr size_t SCR   = HL    + 39321600;
  constexpr size_t W1MH  = SCR;
  constexpr size_t W1ML  = W1MH  + 1474560;
  constexpr size_t W1TH  = W1ML  + 1474560;
  constexpr size_t W1TL  = W1TH  + 4718592;
  constexpr size_t WQH   = W1TL  + 4718592;
  constexpr size_t WQL   = WQH   + 294912;
  constexpr size_t WKH   = WQL   + 294912;
  constexpr size_t WKL   = WKH   + 294912;
  constexpr size_t W2TMH = WKL   + 294912;
  constexpr size_t W2TML = W2TMH + 2949120;
  constexpr size_t W2TTH = W2TML + 2949120;
  constexpr size_t W2TTL = W2TTH + 1769472;
  constexpr size_t QF    = SCR;

  float* out = (float*)d_out;
  float* o_attn = out;
  float* o_logp = out + (size_t)10240000;
  float* o_hard = out + (size_t)20480000;
  float* o_dur  = out + (size_t)30720000;

  hipMemsetAsync(o_hard, 0, (size_t)(10240000 + 6400) * sizeof(float), stream);

  split_pad_k<<<9600, 256, 0, stream>>>(mel_x, (__bf16*)(wsb + MXH), (__bf16*)(wsb + MXL), 80, 96, 2457600L);
  split_pad_k<<<12800, 256, 0, stream>>>(txt_x, (__bf16*)(wsb + TXH), (__bf16*)(wsb + TXL), 512, 512, 3276800L);
  wsplit_k<<<2880, 256, 0, stream>>>(mel_w1, (__bf16*)(wsb + W1MH), (__bf16*)(wsb + W1ML), 80, 5, 96, 737280L);
  wsplit_k<<<9216, 256, 0, stream>>>(txt_w1, (__bf16*)(wsb + W1TH), (__bf16*)(wsb + W1TL), 512, 3, 512, 2359296L);
  wsplit_k<<<576, 256, 0, stream>>>(wq, (__bf16*)(wsb + WQH), (__bf16*)(wsb + WQL), 384, 1, 384, 147456L);
  wsplit_k<<<576, 256, 0, stream>>>(wk, (__bf16*)(wsb + WKH), (__bf16*)(wsb + WKL), 384, 1, 384, 147456L);
  tsplit_k<<<5760, 256, 0, stream>>>(mel_w2, (__bf16*)(wsb + W2TMH), (__bf16*)(wsb + W2TML), 3840, 1474560L);
  tsplit_k<<<3456, 256, 0, stream>>>(txt_w2, (__bf16*)(wsb + W2TTH), (__bf16*)(wsb + W2TTL), 2304, 884736L);
  fold_mfma<5><<<dim3(60, 3), 256, 0, stream>>>(
      (const __bf16*)(wsb + W2TMH), (const __bf16*)(wsb + W2TML),
      (const __bf16*)(wsb + WQH), (const __bf16*)(wsb + WQL),
      (__bf16*)(wsb + WFMH), (__bf16*)(wsb + WFML));
  fold_mfma<3><<<dim3(36, 3), 256, 0, stream>>>(
      (const __bf16*)(wsb + W2TTH), (const __bf16*)(wsb + W2TTL),
      (const __bf16*)(wsb + WKH), (const __bf16*)(wsb + WKL),
      (__bf16*)(wsb + WFTH), (__bf16*)(wsb + WFTL));
  fold_bias_k<<<1, 384, 0, stream>>>(wq, mel_b2, (float*)(wsb + B2M));
  fold_bias_k<<<1, 384, 0, stream>>>(wk, txt_b2, (float*)(wsb + B2T));

  // text pipeline: conv1 -> conv2(folded) writes kT directly
  conv1_mfma<512, 3, 400><<<dim3(4, 12, B), 256, 0, stream>>>(
      (const __bf16*)(wsb + TXH), (const __bf16*)(wsb + TXL),
      (const __bf16*)(wsb + W1TH), (const __bf16*)(wsb + W1TL),
      txt_b1, xl, (__bf16*)(wsb + HH), (__bf16*)(wsb + HL));
  conv2_mfma<3, 400, true><<<dim3(4, 2, B), 256, 0, stream>>>(
      (const __bf16*)(wsb + HH), (const __bf16*)(wsb + HL),
      (const __bf16*)(wsb + WFTH), (const __bf16*)(wsb + WFTL),
      (const float*)(wsb + B2T), bk, xl, (float*)(wsb + KTF));

  // mel pipeline: conv1 -> conv2(folded) writes q directly
  conv1_mfma<96, 5, 1600><<<dim3(13, 12, B), 256, 0, stream>>>(
      (const __bf16*)(wsb + MXH), (const __bf16*)(wsb + MXL),
      (const __bf16*)(wsb + W1MH), (const __bf16*)(wsb + W1ML),
      mel_b1, yl, (__bf16*)(wsb + HH), (__bf16*)(wsb + HL));
  conv2_mfma<5, 1600, false><<<dim3(13, 2, B), 256, 0, stream>>>(
      (const __bf16*)(wsb + HH), (const __bf16*)(wsb + HL),
      (const __bf16*)(wsb + WFMH), (const __bf16*)(wsb + WFML),
      (const float*)(wsb + B2M), bq, yl, (float*)(wsb + QF));

  // attention + MAS (fused fwd+bt, bits in LDS)
  scores_k<<<dim3(100, B), 512, 0, stream>>>(
      (const float*)(wsb + QF), (const float*)(wsb + KTF), xl, yl, o_attn, o_logp);
  mas_k<<<B, 64, 0, stream>>>(o_logp, xl, yl, o_hard, o_dur);
}

// Round 15
// 1454.982 us; speedup vs baseline: 1.2909x; 1.0313x over previous
//
#include <hip/hip_runtime.h>
#include <cstdint>

#define B 16
#define TY 1600
#define TX 400
#define MAS 384
#define HID 768
#define NEGV -1e9f

typedef __bf16 bf16x8 __attribute__((ext_vector_type(8)));
typedef float  f32x4  __attribute__((ext_vector_type(4)));
typedef float  f32x16 __attribute__((ext_vector_type(16)));

__device__ __forceinline__ f32x4 mfma16(bf16x8 a, bf16x8 b, f32x4 c) {
  return __builtin_amdgcn_mfma_f32_16x16x32_bf16(a, b, c, 0, 0, 0);
}
__device__ __forceinline__ f32x16 mfma32(bf16x8 a, bf16x8 b, f32x16 c) {
  return __builtin_amdgcn_mfma_f32_32x32x16_bf16(a, b, c, 0, 0, 0);
}

// ---------------- fp32 -> bf16 hi/lo split with channel padding ----------------
__global__ void split_pad_k(const float* __restrict__ in, __bf16* __restrict__ oh,
                            __bf16* __restrict__ ol, int CIN, int CINP, long n) {
  long i = (long)blockIdx.x * 256 + threadIdx.x;
  if (i >= n) return;
  long row = i / CINP; int ci = (int)(i - row * CINP);
  float v = (ci < CIN) ? in[row * CIN + ci] : 0.f;
  __bf16 h = (__bf16)v;
  oh[i] = h; ol[i] = (__bf16)(v - (float)h);
}

// ---------------- weight repack+split: w[N][CIN][K] -> oh/ol[N][k*CINP + ci] ----------------
__global__ void wsplit_k(const float* __restrict__ w, __bf16* __restrict__ oh,
                         __bf16* __restrict__ ol, int CIN, int K_, int CINP, long n) {
  long i = (long)blockIdx.x * 256 + threadIdx.x;
  if (i >= n) return;
  long kdspan = (long)K_ * CINP;
  long nn = i / kdspan; int kd = (int)(i - nn * kdspan);
  int k = kd / CINP, ci = kd - k * CINP;
  float v = (ci < CIN) ? w[(nn * CIN + ci) * K_ + k] : 0.f;
  __bf16 h = (__bf16)v;
  oh[i] = h; ol[i] = (__bf16)(v - (float)h);
}

// ---------------- transpose+split: w2 [m][JTOT] -> oh/ol [j][384] ----------------
__global__ void tsplit_k(const float* __restrict__ in, __bf16* __restrict__ oh,
                         __bf16* __restrict__ ol, int JTOT, long n) {
  long i = (long)blockIdx.x * 256 + threadIdx.x;
  if (i >= n) return;
  int m = (int)(i / JTOT), j = (int)(i - (long)m * JTOT);
  float v = in[i];
  long o = (long)j * 384 + m;
  __bf16 h = (__bf16)v;
  oh[o] = h; ol[o] = (__bf16)(v - (float)h);
}

// ---------------- bias fold: o[n] = sum_m wq[n][m] * b[m] ----------------
__global__ void fold_bias_k(const float* __restrict__ wq, const float* __restrict__ b,
                            float* __restrict__ o) {
  int n = threadIdx.x;
  float s = 0.f;
  for (int m = 0; m < 384; ++m) s = fmaf(wq[n * 384 + m], b[m], s);
  o[n] = s;
}

// ---------------- weight-fold GEMM (conv2-staging-native output layout) ----------------
template<int KK>
__global__ __launch_bounds__(256)
void fold_mfma(const __bf16* __restrict__ xh, const __bf16* __restrict__ xl,
               const __bf16* __restrict__ wh, const __bf16* __restrict__ wl,
               __bf16* __restrict__ oh, __bf16* __restrict__ ol)
{
  constexpr int CINP = 384, ROWS = 64, STRIDE = 65;
  __shared__ float4 xs[8 * STRIDE];
  const int t0 = blockIdx.x * 64, n0 = blockIdx.y * 128;
  const int tid = threadIdx.x, wn = tid >> 6, lane = tid & 63;
  const int lr = lane & 15, lg = lane >> 4;
  const f32x4 Z4 = {0.f, 0.f, 0.f, 0.f};
  f32x4 acc[4][2];
  #pragma unroll
  for (int m = 0; m < 4; ++m) { acc[m][0] = Z4; acc[m][1] = Z4; }

  #pragma unroll 1
  for (int ci0 = 0; ci0 < CINP; ci0 += 32) {
    __syncthreads();
    for (int e = tid; e < ROWS * 8; e += 256) {
      int row = e >> 3, sc = e & 7, spl = sc >> 2, cg = sc & 3;
      int t = t0 + row;
      xs[(spl * 4 + cg) * STRIDE + row] =
          *(const float4*)((spl ? xl : xh) + (size_t)t * CINP + ci0 + cg * 8);
    }
    __syncthreads();
    bf16x8 ah[4], al[4];
    #pragma unroll
    for (int mf = 0; mf < 4; ++mf) {
      int row = mf * 16 + lr;
      ah[mf] = *(const bf16x8*)&xs[lg * STRIDE + row];
      al[mf] = *(const bf16x8*)&xs[(4 + lg) * STRIDE + row];
    }
    size_t kd = (size_t)ci0 + lg * 8;
    bf16x8 bh[2], bl[2];
    #pragma unroll
    for (int nf = 0; nf < 2; ++nf) {
      int nc = n0 + wn * 32 + nf * 16 + lr;
      bh[nf] = *(const bf16x8*)(wh + (size_t)nc * 384 + kd);
      bl[nf] = *(const bf16x8*)(wl + (size_t)nc * 384 + kd);
    }
    #pragma unroll
    for (int nf = 0; nf < 2; ++nf)
      #pragma unroll
      for (int mf = 0; mf < 4; ++mf) acc[mf][nf] = mfma16(ah[mf], bh[nf], acc[mf][nf]);
    #pragma unroll
    for (int nf = 0; nf < 2; ++nf)
      #pragma unroll
      for (int mf = 0; mf < 4; ++mf) acc[mf][nf] = mfma16(ah[mf], bl[nf], acc[mf][nf]);
    #pragma unroll
    for (int nf = 0; nf < 2; ++nf)
      #pragma unroll
      for (int mf = 0; mf < 4; ++mf) acc[mf][nf] = mfma16(al[mf], bh[nf], acc[mf][nf]);
  }
  #pragma unroll
  for (int nf = 0; nf < 2; ++nf) {
    int c = n0 + wn * 32 + nf * 16 + lr;
    #pragma unroll
    for (int mf = 0; mf < 4; ++mf) {
      #pragma unroll
      for (int r = 0; r < 4; ++r) {
        int j = t0 + mf * 16 + lg * 4 + r;   // j = ci*KK + k
        int k = j % KK, ci = j / KK;
        size_t o = (size_t)((((ci >> 4) * KK + k) * 2 + ((ci >> 3) & 1)) * 3072)
                 + (size_t)c * 8 + (ci & 7);
        float v = acc[mf][nf][r];
        __bf16 vh = (__bf16)v;
        oh[o] = vh; ol[o] = (__bf16)(v - (float)vh);
      }
    }
  }
}

// ---------------- conv1 + ReGLU, split-bf16 MFMA ----------------
template<int CINP, int K, int T>
__global__ __launch_bounds__(256)
void conv1_mfma(const __bf16* __restrict__ xh, const __bf16* __restrict__ xl,
                const __bf16* __restrict__ wh, const __bf16* __restrict__ wl,
                const float* __restrict__ bias, const int* __restrict__ lens,
                __bf16* __restrict__ hh, __bf16* __restrict__ hl)
{
  constexpr int BM = 128, PAD = K / 2, ROWS = BM + K - 1, KD = K * CINP;
  __shared__ float4 xs[8 * ROWS];
  const int b = blockIdx.z, t0 = blockIdx.x * BM, n0 = blockIdx.y * 64;
  const int tid = threadIdx.x, wid = tid >> 6, lane = tid & 63;
  const int wm = wid >> 1, wn = wid & 1, lr = lane & 15, lg = lane >> 4;
  const int len = lens[b];
  const f32x4 Z4 = {0.f, 0.f, 0.f, 0.f};
  f32x4 acc_a[4][2], acc_g[4][2];
  #pragma unroll
  for (int m = 0; m < 4; ++m)
    #pragma unroll
    for (int n = 0; n < 2; ++n) { acc_a[m][n] = Z4; acc_g[m][n] = Z4; }

  #pragma unroll 1
  for (int ci0 = 0; ci0 < CINP; ci0 += 32) {
    __syncthreads();
    for (int e = tid; e < ROWS * 8; e += 256) {
      int row = e >> 3, sc = e & 7, spl = sc >> 2, cg = sc & 3;
      int t = t0 + row - PAD;
      float4 v = {0.f, 0.f, 0.f, 0.f};
      if (t >= 0 && t < len)
        v = *(const float4*)((spl ? xl : xh) + ((size_t)b * T + t) * CINP + ci0 + cg * 8);
      xs[(spl * 4 + cg) * ROWS + row] = v;
    }
    __syncthreads();
    #pragma unroll
    for (int k = 0; k < K; ++k) {
      bf16x8 ah[4], al[4];
      #pragma unroll
      for (int mf = 0; mf < 4; ++mf) {
        int row = wm * 64 + mf * 16 + lr + k;
        ah[mf] = *(const bf16x8*)&xs[lg * ROWS + row];
        al[mf] = *(const bf16x8*)&xs[(4 + lg) * ROWS + row];
      }
      size_t kd = (size_t)k * CINP + ci0 + lg * 8;
      #pragma unroll
      for (int nf = 0; nf < 2; ++nf) {
        int na = n0 + wn * 32 + nf * 16 + lr;
        bf16x8 bah = *(const bf16x8*)(wh + (size_t)na * KD + kd);
        bf16x8 bal = *(const bf16x8*)(wl + (size_t)na * KD + kd);
        bf16x8 bgh = *(const bf16x8*)(wh + (size_t)(na + HID) * KD + kd);
        bf16x8 bgl = *(const bf16x8*)(wl + (size_t)(na + HID) * KD + kd);
        #pragma unroll
        for (int mf = 0; mf < 4; ++mf) {
          acc_a[mf][nf] = mfma16(ah[mf], bah, acc_a[mf][nf]);
          acc_a[mf][nf] = mfma16(ah[mf], bal, acc_a[mf][nf]);
          acc_a[mf][nf] = mfma16(al[mf], bah, acc_a[mf][nf]);
          acc_g[mf][nf] = mfma16(ah[mf], bgh, acc_g[mf][nf]);
          acc_g[mf][nf] = mfma16(ah[mf], bgl, acc_g[mf][nf]);
          acc_g[mf][nf] = mfma16(al[mf], bgh, acc_g[mf][nf]);
        }
      }
    }
  }
  #pragma unroll
  for (int nf = 0; nf < 2; ++nf) {
    int c = n0 + wn * 32 + nf * 16 + lr;
    float ba = bias[c], bg = bias[c + HID];
    #pragma unroll
    for (int mf = 0; mf < 4; ++mf) {
      #pragma unroll
      for (int r = 0; r < 4; ++r) {
        int t = t0 + wm * 64 + mf * 16 + lg * 4 + r;
        if (t < T) {
          float a = acc_a[mf][nf][r] + ba;
          float g = acc_g[mf][nf][r] + bg;
          float v = a * fmaxf(g, 0.f);
          __bf16 vh = (__bf16)v;
          size_t o = ((size_t)b * T + t) * HID + c;
          hh[o] = vh;
          hl[o] = (__bf16)(v - (float)vh);
        }
      }
    }
  }
}

// ---------------- conv2 (folded weights), 32x32x16, B staged in LDS via global_load_lds ----------------
template<int K, int T, bool STORET>
__global__ __launch_bounds__(256)
void conv2_mfma(const __bf16* __restrict__ xh, const __bf16* __restrict__ xl,
                const __bf16* __restrict__ wh, const __bf16* __restrict__ wl,
                const float* __restrict__ bias, const float* __restrict__ ab,
                const int* __restrict__ lens, float* __restrict__ out)
{
  constexpr int CINP = 768, BM = 128, PAD = K / 2, ROWS = BM + K - 1, STRIDE = ROWS + 1;
  constexpr int BROWS = K * 2;
  __shared__ float4 xa[4 * STRIDE];
  __shared__ float4 bs[2 * BROWS * 192];
  const int b = blockIdx.z, t0 = blockIdx.x * BM, n0 = blockIdx.y * 192;
  const int tid = threadIdx.x, wid = tid >> 6, lane = tid & 63;
  const int wm = wid >> 1, wn = wid & 1, lc = lane & 31, lk = lane >> 5;
  const int len = lens[b];
  f32x16 acc[2][3];
  #pragma unroll
  for (int m = 0; m < 2; ++m)
    #pragma unroll
    for (int n = 0; n < 3; ++n)
      #pragma unroll
      for (int r = 0; r < 16; ++r) acc[m][n][r] = 0.f;

  #pragma unroll 1
  for (int s = 0; s < 48; ++s) {
    __syncthreads();
    for (int e = tid; e < ROWS * 4; e += 256) {
      int row = e >> 2, sc = e & 3, spl = sc >> 1, cg = sc & 1;
      int t = t0 + row - PAD;
      float4 v = {0.f, 0.f, 0.f, 0.f};
      if (t >= 0 && t < len)
        v = *(const float4*)((spl ? xl : xh) + ((size_t)b * T + t) * CINP + s * 16 + cg * 8);
      xa[(spl * 2 + cg) * STRIDE + row] = v;
    }
    for (int r = wid; r < 2 * BROWS; r += 4) {
      int spl = r / BROWS, rr = r - spl * BROWS;
      const char* src = (const char*)((spl ? wl : wh) + (size_t)(s * BROWS + rr) * 3072
                                      + (size_t)n0 * 8) + (size_t)lane * 16;
      char* dst = (char*)&bs[r * 192];
      #pragma unroll
      for (int i = 0; i < 3; ++i)
        __builtin_amdgcn_global_load_lds(
            (const __attribute__((address_space(1))) void*)(src + i * 1024),
            (__attribute__((address_space(3))) void*)(dst + i * 1024), 16, 0, 0);
    }
    __syncthreads();
    #pragma unroll
    for (int k = 0; k < K; ++k) {
      bf16x8 ah[2], al[2], bh[3], bl[3];
      #pragma unroll
      for (int mf = 0; mf < 2; ++mf) {
        int row = wm * 64 + mf * 32 + lc + k;
        ah[mf] = *(const bf16x8*)&xa[lk * STRIDE + row];
        al[mf] = *(const bf16x8*)&xa[(2 + lk) * STRIDE + row];
      }
      #pragma unroll
      for (int nf = 0; nf < 3; ++nf) {
        int col = wn * 96 + nf * 32 + lc;
        bh[nf] = *(const bf16x8*)&bs[(k * 2 + lk) * 192 + col];
        bl[nf] = *(const bf16x8*)&bs[(BROWS + k * 2 + lk) * 192 + col];
      }
      #pragma unroll
      for (int nf = 0; nf < 3; ++nf)
        #pragma unroll
        for (int mf = 0; mf < 2; ++mf)
          acc[mf][nf] = mfma32(ah[mf], bh[nf], acc[mf][nf]);
      #pragma unroll
      for (int nf = 0; nf < 3; ++nf)
        #pragma unroll
        for (int mf = 0; mf < 2; ++mf)
          acc[mf][nf] = mfma32(ah[mf], bl[nf], acc[mf][nf]);
      #pragma unroll
      for (int nf = 0; nf < 3; ++nf)
        #pragma unroll
        for (int mf = 0; mf < 2; ++mf)
          acc[mf][nf] = mfma32(al[mf], bh[nf], acc[mf][nf]);
    }
  }
  #pragma unroll
  for (int nf = 0; nf < 3; ++nf) {
    int c = n0 + wn * 96 + nf * 32 + lc;
    float bb = bias[c], aB = ab[c];
    #pragma unroll
    for (int mf = 0; mf < 2; ++mf) {
      #pragma unroll
      for (int r = 0; r < 16; ++r) {
        int t = t0 + wm * 64 + mf * 32 + (r & 3) + 8 * (r >> 2) + 4 * lk;
        if (t < T) {
          float v = acc[mf][nf][r] + bb;
          if (t >= len) v = 0.f;
          v += aB;
          if (STORET) out[((size_t)b * MAS + c) * T + t] = v;
          else        out[((size_t)b * T + t) * MAS + c] = v;
        }
      }
    }
  }
}

// ---------------- scores + softmax + safe_log ----------------
__global__ __launch_bounds__(512)
void scores_k(const float* __restrict__ q, const float* __restrict__ kT,
              const int* __restrict__ xl, const int* __restrict__ yl,
              float* __restrict__ oattn, float* __restrict__ ologp)
{
  __shared__ float qs[16 * 384];
  __shared__ float tmp[8];
  const int b = blockIdx.y, y0 = blockIdx.x * 16, tid = threadIdx.x;
  for (int e = tid; e < 16 * 384; e += 512)
    qs[e] = q[((size_t)b * TY + (y0 + e / 384)) * 384 + (e - (e / 384) * 384)];
  __syncthreads();
  float acc[16];
  #pragma unroll
  for (int i = 0; i < 16; ++i) acc[i] = 0.f;
  const int x = tid;
  if (x < TX) {
    const float* kb = kT + (size_t)b * MAS * TX + x;
    for (int d = 0; d < 384; d += 4) {
      float k0 = kb[(size_t)(d + 0) * TX], k1 = kb[(size_t)(d + 1) * TX];
      float k2 = kb[(size_t)(d + 2) * TX], k3 = kb[(size_t)(d + 3) * TX];
      #pragma unroll
      for (int yy = 0; yy < 16; ++yy) {
        float4 qv = *(const float4*)&qs[yy * 384 + d];
        acc[yy] = fmaf(qv.x, k0, fmaf(qv.y, k1, fmaf(qv.z, k2, fmaf(qv.w, k3, acc[yy]))));
      }
    }
  }
  const int xlen = xl[b], ylen = yl[b];
  const float scale = 0.05103103630798288f;
  const bool xpad = (x >= xlen);
  const int wv = tid >> 6, ln = tid & 63;
  #pragma unroll 1
  for (int yy = 0; yy < 16; ++yy) {
    int y = y0 + yy;
    float s = -3.0e38f;
    if (x < TX) {
      s = acc[yy] * scale;
      if (xpad && (y >= ylen)) s = -1e-9f;
    }
    float m = s;
    for (int off = 32; off; off >>= 1) m = fmaxf(m, __shfl_xor(m, off));
    if (ln == 0) tmp[wv] = m;
    __syncthreads();
    float mx = fmaxf(fmaxf(fmaxf(tmp[0], tmp[1]), fmaxf(tmp[2], tmp[3])),
                     fmaxf(fmaxf(tmp[4], tmp[5]), fmaxf(tmp[6], tmp[7])));
    __syncthreads();
    float e = (x < TX) ? expf(s - mx) : 0.f;
    float sm = e;
    for (int off = 32; off; off >>= 1) sm += __shfl_xor(sm, off);
    if (ln == 0) tmp[wv] = sm;
    __syncthreads();
    float tot = tmp[0] + tmp[1] + tmp[2] + tmp[3] + tmp[4] + tmp[5] + tmp[6] + tmp[7];
    __syncthreads();
    if (x < TX) {
      float w = e / tot;
      size_t o = ((size_t)b * TY + y) * TX + x;
      oattn[o] = w;
      ologp[o] = logf(w + 1e-6f);
    }
  }
}

// ---------------- MAS fused: 4-wave super-wave forward DP (2 cols/lane + 4-col halo,
//                  LDS exchange every 4 rows) + in-LDS bits + wave-0 backtrack ----------------
__global__ __launch_bounds__(256, 1)
void mas_k(const float* __restrict__ logprob, const int* __restrict__ xl,
           const int* __restrict__ yl, float* __restrict__ hard, float* __restrict__ dur)
{
  __shared__ float ring[12800];              // 2 slots x 16 rows x 400 floats = 51,200 B
  __shared__ unsigned char lbits[102400];    // [yblk 200][byte 64][8 rows] = 100 KB
  __shared__ float vbuf[2][400];             // boundary-exchange rows (double-buffered)
  const int b = blockIdx.x;
  const int tid = threadIdx.x, wid = tid >> 6;
  const int GL = tid;                        // global lane 0..255; owns x = 2GL, 2GL+1
  const int xlen = xl[b], ylen = yl[b];
  const float* lpb = logprob + (size_t)b * TY * TX;
  const int p0 = GL * 2 - 4;                 // leftmost halo position

  // clamped float2 load offsets (even -> 8B aligned)
  int a0 = p0, a1 = p0 + 2, a2 = p0 + 4;
  a0 = a0 < 0 ? 0 : (a0 > 398 ? 398 : a0);
  a1 = a1 < 0 ? 0 : (a1 > 398 ? 398 : a1);
  a2 = a2 < 0 ? 0 : (a2 > 398 ? 398 : a2);

  float w[6], wxm[6];
  #pragma unroll
  for (int j = 0; j < 6; ++j) {
    int x = p0 + j;
    wxm[j] = (x >= 0 && x < xlen) ? 0.f : NEGV;
    w[j] = (x == 0) ? 0.f : NEGV;
  }

  const char* lpc = (const char*)lpb;
  constexpr size_t maxgs = (size_t)TY * 1600 - 25600;
  char* ringc = (char*)ring;
  const int lane = tid & 63;
  auto issue_group = [&](int g) {
    size_t gs = (size_t)g * 25600; if (gs > maxgs) gs = maxgs;
    for (int c = wid; c < 25; c += 4)
      __builtin_amdgcn_global_load_lds(
          (const __attribute__((address_space(1))) void*)(lpc + gs + (size_t)c * 1024 + (size_t)lane * 16),
          (__attribute__((address_space(3))) void*)(ringc + (g & 1) * 25600 + c * 1024), 16, 0, 0);
  };

  issue_group(0);
  issue_group(1);

  int pb = 0;
  unsigned p16 = 0;
  const int ngroups = (ylen + 15) >> 4;
  #pragma unroll 1
  for (int g = 0; g < ngroups; ++g) {
    if (wid == 0) asm volatile("s_waitcnt vmcnt(7)" ::: "memory");  // own share: 7 chunks in flight (g+1)
    else          asm volatile("s_waitcnt vmcnt(6)" ::: "memory");
    __builtin_amdgcn_sched_barrier(0);
    __syncthreads();                                   // all waves' slot-g chunks landed
    const float* half = ring + (g & 1) * 6400;
    const int ybase = g * 16;
    const bool phase1 = (ybase < TX);
    #pragma unroll
    for (int sb = 0; sb < 4; ++sb) {
      #pragma unroll
      for (int r = 0; r < 4; ++r) {
        const int row = sb * 4 + r;
        const int y = ybase + row;
        const float2 d0 = *(const float2*)&half[row * 400 + a0];
        const float2 d1 = *(const float2*)&half[row * 400 + a1];
        const float2 d2 = *(const float2*)&half[row * 400 + a2];
        float lp[6] = {d0.x + wxm[0], d0.y + wxm[1], d1.x + wxm[2],
                       d1.y + wxm[3], d2.x + wxm[4], d2.y + wxm[5]};
        if (phase1) {
          int c = y - p0;
          #pragma unroll
          for (int j = 0; j < 6; ++j) lp[j] = (j <= c) ? lp[j] : NEGV;
        }
        unsigned pr = ((w[3] > w[4]) ? 1u : 0u) | ((w[4] > w[5]) ? 2u : 0u);
        p16 |= pr << ((y & 7) * 2);
        float nw[6];
        nw[0] = lp[0] + w[0];
        #pragma unroll
        for (int j = 1; j < 6; ++j) nw[j] = lp[j] + fmaxf(w[j], w[j - 1]);
        #pragma unroll
        for (int j = 0; j < 6; ++j) w[j] = nw[j];
      }
      if (sb & 1) {
        // flush 8 rows of 2-bit pairs -> byte-per-row u64, merged across 4-lane groups
        const int y7 = ybase + sb * 4 + 3;             // (y7 & 7) == 7
        unsigned lo = 0, hi = 0;
        #pragma unroll
        for (int r2 = 0; r2 < 4; ++r2) {
          lo |= ((p16 >> (2 * r2)) & 3u) << (8 * r2);
          hi |= ((p16 >> (2 * r2 + 8)) & 3u) << (8 * r2);
        }
        unsigned lo1 = (unsigned)__shfl_xor((int)lo, 1), hi1 = (unsigned)__shfl_xor((int)hi, 1);
        lo |= lo1 << 2; hi |= hi1 << 2;
        unsigned lo2 = (unsigned)__shfl_xor((int)lo, 2), hi2 = (unsigned)__shfl_xor((int)hi, 2);
        lo |= lo2 << 4; hi |= hi2 << 4;
        if ((GL & 3) == 0 && GL < 200) {
          unsigned long long E = (unsigned long long)lo | ((unsigned long long)hi << 32);
          *(unsigned long long*)&lbits[(size_t)(y7 >> 3) * 512 + (size_t)(GL >> 2) * 8] = E;
        }
        p16 = 0;
      }
      // boundary exchange: publish own cells, re-seed halo (exact)
      if (GL < 200) { vbuf[pb][2 * GL] = w[4]; vbuf[pb][2 * GL + 1] = w[5]; }
      __syncthreads();
      #pragma unroll
      for (int j = 0; j < 4; ++j) {
        int x = p0 + j;
        w[j] = (x >= 0 && GL < 200) ? vbuf[pb][x] : NEGV;
      }
      pb ^= 1;
    }
    __builtin_amdgcn_sched_barrier(0);
    issue_group(g + 2);                                // refills the slot just consumed
  }

  __syncthreads();
  if (wid != 0) return;

  // backtrack: wave 0 only; uniform scalar walk via readlane; window from LDS bits
  int x = xlen - 1;
  int cnt = 0;
  float* hb = hard + (size_t)b * TX * TY;
  float* db = dur + (size_t)b * TX;

  #pragma unroll 1
  for (int ycur = ylen - 1; ycur >= 0; ycur -= 64) {
    int lo = x - 63; if (lo < 0) lo = 0;
    const int wb = (lo >> 3) & ~3;
    int ry = ycur - lane;
    unsigned w0 = 0, w1 = 0, w2 = 0;
    if (ry >= 0) {
      const unsigned char* p = lbits + (size_t)(ry >> 3) * 512 + (ry & 7);
      unsigned bt_[12];
      #pragma unroll
      for (int j = 0; j < 12; ++j) bt_[j] = p[(size_t)(wb + j) * 8];
      w0 = bt_[0] | (bt_[1] << 8) | (bt_[2] << 16) | (bt_[3] << 24);
      w1 = bt_[4] | (bt_[5] << 8) | (bt_[6] << 16) | (bt_[7] << 24);
      w2 = bt_[8] | (bt_[9] << 8) | (bt_[10] << 16) | (bt_[11] << 24);
    }
    const int rows = (ycur + 1 < 64) ? (ycur + 1) : 64;
    #pragma unroll 1
    for (int s = 0; s < rows; s += 8) {
      const int cnt8 = (rows - s < 8) ? (rows - s) : 8;
      unsigned r0[8], r1[8], r2[8];
      #pragma unroll
      for (int u = 0; u < 8; ++u) {
        r0[u] = (unsigned)__builtin_amdgcn_readlane((int)w0, s + u);
        r1[u] = (unsigned)__builtin_amdgcn_readlane((int)w1, s + u);
        r2[u] = (unsigned)__builtin_amdgcn_readlane((int)w2, s + u);
      }
      #pragma unroll
      for (int u = 0; u < 8; ++u) {
        if (u < cnt8) {
          const int yy = ycur - s - u;
          ++cnt;
          if (yy > 0 && x > 0) {
            const int boff = (x >> 3) - wb;
            const unsigned word = (boff < 4) ? r0[u] : ((boff < 8) ? r1[u] : r2[u]);
            const unsigned byte = word >> ((boff & 3) * 8);
            if ((x == yy) || ((byte >> (x & 7)) & 1)) {
              for (int q = lane; q < cnt; q += 64) hb[(size_t)x * TY + yy + q] = 1.0f;
              if (lane == 0) db[x] = (float)cnt;
              cnt = 0;
              --x;
            }
          }
        }
      }
    }
  }
  for (int q = lane; q < cnt; q += 64) hb[(size_t)x * TY + q] = 1.0f;
  if (lane == 0) db[x] = (float)cnt;
}

extern "C" void kernel_launch(void* const* d_in, const int* in_sizes, int n_in,
                              void* d_out, int out_size, void* d_ws, size_t ws_size,
                              hipStream_t stream) {
  const float* mel_x  = (const float*)d_in[0];
  const float* txt_x  = (const float*)d_in[1];
  const float* mel_w1 = (const float*)d_in[2];
  const float* mel_b1 = (const float*)d_in[3];
  const float* mel_w2 = (const float*)d_in[4];
  const float* mel_b2 = (const float*)d_in[5];
  const float* txt_w1 = (const float*)d_in[6];
  const float* txt_b1 = (const float*)d_in[7];
  const float* txt_w2 = (const float*)d_in[8];
  const float* txt_b2 = (const float*)d_in[9];
  const float* wq     = (const float*)d_in[10];
  const float* bq     = (const float*)d_in[11];
  const float* wk     = (const float*)d_in[12];
  const float* bk     = (const float*)d_in[13];
  const int*   xl     = (const int*)d_in[14];
  const int*   yl     = (const int*)d_in[15];

  char* wsb = (char*)d_ws;
  constexpr size_t MXH   = 0;
  constexpr size_t MXL   = MXH   + 4915200;
  constexpr size_t TXH   = MXL   + 4915200;
  constexpr size_t TXL   = TXH   + 6553600;
  constexpr size_t KTF   = TXH;
  constexpr size_t WFMH  = TXL   + 6553600;
  constexpr size_t WFML  = WFMH  + 2949120;
  constexpr size_t WFTH  = WFML  + 2949120;
  constexpr size_t WFTL  = WFTH  + 1769472;
  constexpr size_t B2M   = WFTL  + 1769472;
  constexpr size_t B2T   = B2M   + 2048;
  constexpr size_t HH    = B2T   + 2048;
  constexpr size_t HL    = HH    + 39321600;
  constexpr size_t SCR   = HL    + 39321600;
  constexpr size_t W1MH  = SCR;
  constexpr size_t W1ML  = W1MH  + 1474560;
  constexpr size_t W1TH  = W1ML  + 1474560;
  constexpr size_t W1TL  = W1TH  + 4718592;
  constexpr size_t WQH   = W1TL  + 4718592;
  constexpr size_t WQL   = WQH   + 294912;
  constexpr size_t WKH   = WQL   + 294912;
  constexpr size_t WKL   = WKH   + 294912;
  constexpr size_t W2TMH = WKL   + 294912;
  constexpr size_t W2TML = W2TMH + 2949120;
  constexpr size_t W2TTH = W2TML + 2949120;
  constexpr size_t W2TTL = W2TTH + 1769472;
  constexpr size_t QF    = SCR;

  float* out = (float*)d_out;
  float* o_attn = out;
  float* o_logp = out + (size_t)10240000;
  float* o_hard = out + (size_t)20480000;
  float* o_dur  = out + (size_t)30720000;

  hipMemsetAsync(o_hard, 0, (size_t)(10240000 + 6400) * sizeof(float), stream);

  split_pad_k<<<9600, 256, 0, stream>>>(mel_x, (__bf16*)(wsb + MXH), (__bf16*)(wsb + MXL), 80, 96, 2457600L);
  split_pad_k<<<12800, 256, 0, stream>>>(txt_x, (__bf16*)(wsb + TXH), (__bf16*)(wsb + TXL), 512, 512, 3276800L);
  wsplit_k<<<2880, 256, 0, stream>>>(mel_w1, (__bf16*)(wsb + W1MH), (__bf16*)(wsb + W1ML), 80, 5, 96, 737280L);
  wsplit_k<<<9216, 256, 0, stream>>>(txt_w1, (__bf16*)(wsb + W1TH), (__bf16*)(wsb + W1TL), 512, 3, 512, 2359296L);
  wsplit_k<<<576, 256, 0, stream>>>(wq, (__bf16*)(wsb + WQH), (__bf16*)(wsb + WQL), 384, 1, 384, 147456L);
  wsplit_k<<<576, 256, 0, stream>>>(wk, (__bf16*)(wsb + WKH), (__bf16*)(wsb + WKL), 384, 1, 384, 147456L);
  tsplit_k<<<5760, 256, 0, stream>>>(mel_w2, (__bf16*)(wsb + W2TMH), (__bf16*)(wsb + W2TML), 3840, 1474560L);
  tsplit_k<<<3456, 256, 0, stream>>>(txt_w2, (__bf16*)(wsb + W2TTH), (__bf16*)(wsb + W2TTL), 2304, 884736L);
  fold_mfma<5><<<dim3(60, 3), 256, 0, stream>>>(
      (const __bf16*)(wsb + W2TMH), (const __bf16*)(wsb + W2TML),
      (const __bf16*)(wsb + WQH), (const __bf16*)(wsb + WQL),
      (__bf16*)(wsb + WFMH), (__bf16*)(wsb + WFML));
  fold_mfma<3><<<dim3(36, 3), 256, 0, stream>>>(
      (const __bf16*)(wsb + W2TTH), (const __bf16*)(wsb + W2TTL),
      (const __bf16*)(wsb + WKH), (const __bf16*)(wsb + WKL),
      (__bf16*)(wsb + WFTH), (__bf16*)(wsb + WFTL));
  fold_bias_k<<<1, 384, 0, stream>>>(wq, mel_b2, (float*)(wsb + B2M));
  fold_bias_k<<<1, 384, 0, stream>>>(wk, txt_b2, (float*)(wsb + B2T));

  // text pipeline: conv1 -> conv2(folded) writes kT directly
  conv1_mfma<512, 3, 400><<<dim3(4, 12, B), 256, 0, stream>>>(
      (const __bf16*)(wsb + TXH), (const __bf16*)(wsb + TXL),
      (const __bf16*)(wsb + W1TH), (const __bf16*)(wsb + W1TL),
      txt_b1, xl, (__bf16*)(wsb + HH), (__bf16*)(wsb + HL));
  conv2_mfma<3, 400, true><<<dim3(4, 2, B), 256, 0, stream>>>(
      (const __bf16*)(wsb + HH), (const __bf16*)(wsb + HL),
      (const __bf16*)(wsb + WFTH), (const __bf16*)(wsb + WFTL),
      (const float*)(wsb + B2T), bk, xl, (float*)(wsb + KTF));

  // mel pipeline: conv1 -> conv2(folded) writes q directly
  conv1_mfma<96, 5, 1600><<<dim3(13, 12, B), 256, 0, stream>>>(
      (const __bf16*)(wsb + MXH), (const __bf16*)(wsb + MXL),
      (const __bf16*)(wsb + W1MH), (const __bf16*)(wsb + W1ML),
      mel_b1, yl, (__bf16*)(wsb + HH), (__bf16*)(wsb + HL));
  conv2_mfma<5, 1600, false><<<dim3(13, 2, B), 256, 0, stream>>>(
      (const __bf16*)(wsb + HH), (const __bf16*)(wsb + HL),
      (const __bf16*)(wsb + WFMH), (const __bf16*)(wsb + WFML),
      (const float*)(wsb + B2M), bq, yl, (float*)(wsb + QF));

  // attention + MAS (fused fwd+bt, 4-wave super-wave)
  scores_k<<<dim3(100, B), 512, 0, stream>>>(
      (const float*)(wsb + QF), (const float*)(wsb + KTF), xl, yl, o_attn, o_logp);
  mas_k<<<B, 256, 0, stream>>>(o_logp, xl, yl, o_hard, o_dur);
}

// Round 16
// 1436.509 us; speedup vs baseline: 1.3075x; 1.0129x over previous
//
#include <hip/hip_runtime.h>
#include <cstdint>

#define B 16
#define TY 1600
#define TX 400
#define MAS 384
#define HID 768
#define NEGV -1e9f

typedef __bf16 bf16x8 __attribute__((ext_vector_type(8)));
typedef float  f32x4  __attribute__((ext_vector_type(4)));
typedef float  f32x16 __attribute__((ext_vector_type(16)));

__device__ __forceinline__ f32x4 mfma16(bf16x8 a, bf16x8 b, f32x4 c) {
  return __builtin_amdgcn_mfma_f32_16x16x32_bf16(a, b, c, 0, 0, 0);
}
__device__ __forceinline__ f32x16 mfma32(bf16x8 a, bf16x8 b, f32x16 c) {
  return __builtin_amdgcn_mfma_f32_32x32x16_bf16(a, b, c, 0, 0, 0);
}

// ---------------- fp32 -> bf16 hi/lo split with channel padding ----------------
__global__ void split_pad_k(const float* __restrict__ in, __bf16* __restrict__ oh,
                            __bf16* __restrict__ ol, int CIN, int CINP, long n) {
  long i = (long)blockIdx.x * 256 + threadIdx.x;
  if (i >= n) return;
  long row = i / CINP; int ci = (int)(i - row * CINP);
  float v = (ci < CIN) ? in[row * CIN + ci] : 0.f;
  __bf16 h = (__bf16)v;
  oh[i] = h; ol[i] = (__bf16)(v - (float)h);
}

// ---------------- weight repack+split: w[N][CIN][K] -> oh/ol[N][k*CINP + ci] ----------------
__global__ void wsplit_k(const float* __restrict__ w, __bf16* __restrict__ oh,
                         __bf16* __restrict__ ol, int CIN, int K_, int CINP, long n) {
  long i = (long)blockIdx.x * 256 + threadIdx.x;
  if (i >= n) return;
  long kdspan = (long)K_ * CINP;
  long nn = i / kdspan; int kd = (int)(i - nn * kdspan);
  int k = kd / CINP, ci = kd - k * CINP;
  float v = (ci < CIN) ? w[(nn * CIN + ci) * K_ + k] : 0.f;
  __bf16 h = (__bf16)v;
  oh[i] = h; ol[i] = (__bf16)(v - (float)h);
}

// ---------------- transpose+split: w2 [m][JTOT] -> oh/ol [j][384] ----------------
__global__ void tsplit_k(const float* __restrict__ in, __bf16* __restrict__ oh,
                         __bf16* __restrict__ ol, int JTOT, long n) {
  long i = (long)blockIdx.x * 256 + threadIdx.x;
  if (i >= n) return;
  int m = (int)(i / JTOT), j = (int)(i - (long)m * JTOT);
  float v = in[i];
  long o = (long)j * 384 + m;
  __bf16 h = (__bf16)v;
  oh[o] = h; ol[o] = (__bf16)(v - (float)h);
}

// ---------------- bias fold: o[n] = sum_m wq[n][m] * b[m] ----------------
__global__ void fold_bias_k(const float* __restrict__ wq, const float* __restrict__ b,
                            float* __restrict__ o) {
  int n = threadIdx.x;
  float s = 0.f;
  for (int m = 0; m < 384; ++m) s = fmaf(wq[n * 384 + m], b[m], s);
  o[n] = s;
}

// ---------------- weight-fold GEMM (conv2-staging-native output layout) ----------------
template<int KK>
__global__ __launch_bounds__(256)
void fold_mfma(const __bf16* __restrict__ xh, const __bf16* __restrict__ xl,
               const __bf16* __restrict__ wh, const __bf16* __restrict__ wl,
               __bf16* __restrict__ oh, __bf16* __restrict__ ol)
{
  constexpr int CINP = 384, ROWS = 64, STRIDE = 65;
  __shared__ float4 xs[8 * STRIDE];
  const int t0 = blockIdx.x * 64, n0 = blockIdx.y * 128;
  const int tid = threadIdx.x, wn = tid >> 6, lane = tid & 63;
  const int lr = lane & 15, lg = lane >> 4;
  const f32x4 Z4 = {0.f, 0.f, 0.f, 0.f};
  f32x4 acc[4][2];
  #pragma unroll
  for (int m = 0; m < 4; ++m) { acc[m][0] = Z4; acc[m][1] = Z4; }

  #pragma unroll 1
  for (int ci0 = 0; ci0 < CINP; ci0 += 32) {
    __syncthreads();
    for (int e = tid; e < ROWS * 8; e += 256) {
      int row = e >> 3, sc = e & 7, spl = sc >> 2, cg = sc & 3;
      int t = t0 + row;
      xs[(spl * 4 + cg) * STRIDE + row] =
          *(const float4*)((spl ? xl : xh) + (size_t)t * CINP + ci0 + cg * 8);
    }
    __syncthreads();
    bf16x8 ah[4], al[4];
    #pragma unroll
    for (int mf = 0; mf < 4; ++mf) {
      int row = mf * 16 + lr;
      ah[mf] = *(const bf16x8*)&xs[lg * STRIDE + row];
      al[mf] = *(const bf16x8*)&xs[(4 + lg) * STRIDE + row];
    }
    size_t kd = (size_t)ci0 + lg * 8;
    bf16x8 bh[2], bl[2];
    #pragma unroll
    for (int nf = 0; nf < 2; ++nf) {
      int nc = n0 + wn * 32 + nf * 16 + lr;
      bh[nf] = *(const bf16x8*)(wh + (size_t)nc * 384 + kd);
      bl[nf] = *(const bf16x8*)(wl + (size_t)nc * 384 + kd);
    }
    #pragma unroll
    for (int nf = 0; nf < 2; ++nf)
      #pragma unroll
      for (int mf = 0; mf < 4; ++mf) acc[mf][nf] = mfma16(ah[mf], bh[nf], acc[mf][nf]);
    #pragma unroll
    for (int nf = 0; nf < 2; ++nf)
      #pragma unroll
      for (int mf = 0; mf < 4; ++mf) acc[mf][nf] = mfma16(ah[mf], bl[nf], acc[mf][nf]);
    #pragma unroll
    for (int nf = 0; nf < 2; ++nf)
      #pragma unroll
      for (int mf = 0; mf < 4; ++mf) acc[mf][nf] = mfma16(al[mf], bh[nf], acc[mf][nf]);
  }
  #pragma unroll
  for (int nf = 0; nf < 2; ++nf) {
    int c = n0 + wn * 32 + nf * 16 + lr;
    #pragma unroll
    for (int mf = 0; mf < 4; ++mf) {
      #pragma unroll
      for (int r = 0; r < 4; ++r) {
        int j = t0 + mf * 16 + lg * 4 + r;   // j = ci*KK + k
        int k = j % KK, ci = j / KK;
        size_t o = (size_t)((((ci >> 4) * KK + k) * 2 + ((ci >> 3) & 1)) * 3072)
                 + (size_t)c * 8 + (ci & 7);
        float v = acc[mf][nf][r];
        __bf16 vh = (__bf16)v;
        oh[o] = vh; ol[o] = (__bf16)(v - (float)vh);
      }
    }
  }
}

// ---------------- conv1 + ReGLU, split-bf16 MFMA ----------------
template<int CINP, int K, int T>
__global__ __launch_bounds__(256)
void conv1_mfma(const __bf16* __restrict__ xh, const __bf16* __restrict__ xl,
                const __bf16* __restrict__ wh, const __bf16* __restrict__ wl,
                const float* __restrict__ bias, const int* __restrict__ lens,
                __bf16* __restrict__ hh, __bf16* __restrict__ hl)
{
  constexpr int BM = 128, PAD = K / 2, ROWS = BM + K - 1, KD = K * CINP;
  __shared__ float4 xs[8 * ROWS];
  const int b = blockIdx.z, t0 = blockIdx.x * BM, n0 = blockIdx.y * 64;
  const int tid = threadIdx.x, wid = tid >> 6, lane = tid & 63;
  const int wm = wid >> 1, wn = wid & 1, lr = lane & 15, lg = lane >> 4;
  const int len = lens[b];
  const f32x4 Z4 = {0.f, 0.f, 0.f, 0.f};
  f32x4 acc_a[4][2], acc_g[4][2];
  #pragma unroll
  for (int m = 0; m < 4; ++m)
    #pragma unroll
    for (int n = 0; n < 2; ++n) { acc_a[m][n] = Z4; acc_g[m][n] = Z4; }

  #pragma unroll 1
  for (int ci0 = 0; ci0 < CINP; ci0 += 32) {
    __syncthreads();
    for (int e = tid; e < ROWS * 8; e += 256) {
      int row = e >> 3, sc = e & 7, spl = sc >> 2, cg = sc & 3;
      int t = t0 + row - PAD;
      float4 v = {0.f, 0.f, 0.f, 0.f};
      if (t >= 0 && t < len)
        v = *(const float4*)((spl ? xl : xh) + ((size_t)b * T + t) * CINP + ci0 + cg * 8);
      xs[(spl * 4 + cg) * ROWS + row] = v;
    }
    __syncthreads();
    #pragma unroll
    for (int k = 0; k < K; ++k) {
      bf16x8 ah[4], al[4];
      #pragma unroll
      for (int mf = 0; mf < 4; ++mf) {
        int row = wm * 64 + mf * 16 + lr + k;
        ah[mf] = *(const bf16x8*)&xs[lg * ROWS + row];
        al[mf] = *(const bf16x8*)&xs[(4 + lg) * ROWS + row];
      }
      size_t kd = (size_t)k * CINP + ci0 + lg * 8;
      #pragma unroll
      for (int nf = 0; nf < 2; ++nf) {
        int na = n0 + wn * 32 + nf * 16 + lr;
        bf16x8 bah = *(const bf16x8*)(wh + (size_t)na * KD + kd);
        bf16x8 bal = *(const bf16x8*)(wl + (size_t)na * KD + kd);
        bf16x8 bgh = *(const bf16x8*)(wh + (size_t)(na + HID) * KD + kd);
        bf16x8 bgl = *(const bf16x8*)(wl + (size_t)(na + HID) * KD + kd);
        #pragma unroll
        for (int mf = 0; mf < 4; ++mf) {
          acc_a[mf][nf] = mfma16(ah[mf], bah, acc_a[mf][nf]);
          acc_a[mf][nf] = mfma16(ah[mf], bal, acc_a[mf][nf]);
          acc_a[mf][nf] = mfma16(al[mf], bah, acc_a[mf][nf]);
          acc_g[mf][nf] = mfma16(ah[mf], bgh, acc_g[mf][nf]);
          acc_g[mf][nf] = mfma16(ah[mf], bgl, acc_g[mf][nf]);
          acc_g[mf][nf] = mfma16(al[mf], bgh, acc_g[mf][nf]);
        }
      }
    }
  }
  #pragma unroll
  for (int nf = 0; nf < 2; ++nf) {
    int c = n0 + wn * 32 + nf * 16 + lr;
    float ba = bias[c], bg = bias[c + HID];
    #pragma unroll
    for (int mf = 0; mf < 4; ++mf) {
      #pragma unroll
      for (int r = 0; r < 4; ++r) {
        int t = t0 + wm * 64 + mf * 16 + lg * 4 + r;
        if (t < T) {
          float a = acc_a[mf][nf][r] + ba;
          float g = acc_g[mf][nf][r] + bg;
          float v = a * fmaxf(g, 0.f);
          __bf16 vh = (__bf16)v;
          size_t o = ((size_t)b * T + t) * HID + c;
          hh[o] = vh;
          hl[o] = (__bf16)(v - (float)vh);
        }
      }
    }
  }
}

// ---------------- conv2 (folded weights), 32x32x16, B staged in LDS via global_load_lds ----------------
template<int K, int T, bool STORET>
__global__ __launch_bounds__(256)
void conv2_mfma(const __bf16* __restrict__ xh, const __bf16* __restrict__ xl,
                const __bf16* __restrict__ wh, const __bf16* __restrict__ wl,
                const float* __restrict__ bias, const float* __restrict__ ab,
                const int* __restrict__ lens, float* __restrict__ out)
{
  constexpr int CINP = 768, BM = 128, PAD = K / 2, ROWS = BM + K - 1, STRIDE = ROWS + 1;
  constexpr int BROWS = K * 2;
  __shared__ float4 xa[4 * STRIDE];
  __shared__ float4 bs[2 * BROWS * 192];
  const int b = blockIdx.z, t0 = blockIdx.x * BM, n0 = blockIdx.y * 192;
  const int tid = threadIdx.x, wid = tid >> 6, lane = tid & 63;
  const int wm = wid >> 1, wn = wid & 1, lc = lane & 31, lk = lane >> 5;
  const int len = lens[b];
  f32x16 acc[2][3];
  #pragma unroll
  for (int m = 0; m < 2; ++m)
    #pragma unroll
    for (int n = 0; n < 3; ++n)
      #pragma unroll
      for (int r = 0; r < 16; ++r) acc[m][n][r] = 0.f;

  #pragma unroll 1
  for (int s = 0; s < 48; ++s) {
    __syncthreads();
    for (int e = tid; e < ROWS * 4; e += 256) {
      int row = e >> 2, sc = e & 3, spl = sc >> 1, cg = sc & 1;
      int t = t0 + row - PAD;
      float4 v = {0.f, 0.f, 0.f, 0.f};
      if (t >= 0 && t < len)
        v = *(const float4*)((spl ? xl : xh) + ((size_t)b * T + t) * CINP + s * 16 + cg * 8);
      xa[(spl * 2 + cg) * STRIDE + row] = v;
    }
    for (int r = wid; r < 2 * BROWS; r += 4) {
      int spl = r / BROWS, rr = r - spl * BROWS;
      const char* src = (const char*)((spl ? wl : wh) + (size_t)(s * BROWS + rr) * 3072
                                      + (size_t)n0 * 8) + (size_t)lane * 16;
      char* dst = (char*)&bs[r * 192];
      #pragma unroll
      for (int i = 0; i < 3; ++i)
        __builtin_amdgcn_global_load_lds(
            (const __attribute__((address_space(1))) void*)(src + i * 1024),
            (__attribute__((address_space(3))) void*)(dst + i * 1024), 16, 0, 0);
    }
    __syncthreads();
    #pragma unroll
    for (int k = 0; k < K; ++k) {
      bf16x8 ah[2], al[2], bh[3], bl[3];
      #pragma unroll
      for (int mf = 0; mf < 2; ++mf) {
        int row = wm * 64 + mf * 32 + lc + k;
        ah[mf] = *(const bf16x8*)&xa[lk * STRIDE + row];
        al[mf] = *(const bf16x8*)&xa[(2 + lk) * STRIDE + row];
      }
      #pragma unroll
      for (int nf = 0; nf < 3; ++nf) {
        int col = wn * 96 + nf * 32 + lc;
        bh[nf] = *(const bf16x8*)&bs[(k * 2 + lk) * 192 + col];
        bl[nf] = *(const bf16x8*)&bs[(BROWS + k * 2 + lk) * 192 + col];
      }
      #pragma unroll
      for (int nf = 0; nf < 3; ++nf)
        #pragma unroll
        for (int mf = 0; mf < 2; ++mf)
          acc[mf][nf] = mfma32(ah[mf], bh[nf], acc[mf][nf]);
      #pragma unroll
      for (int nf = 0; nf < 3; ++nf)
        #pragma unroll
        for (int mf = 0; mf < 2; ++mf)
          acc[mf][nf] = mfma32(ah[mf], bl[nf], acc[mf][nf]);
      #pragma unroll
      for (int nf = 0; nf < 3; ++nf)
        #pragma unroll
        for (int mf = 0; mf < 2; ++mf)
          acc[mf][nf] = mfma32(al[mf], bh[nf], acc[mf][nf]);
    }
  }
  #pragma unroll
  for (int nf = 0; nf < 3; ++nf) {
    int c = n0 + wn * 96 + nf * 32 + lc;
    float bb = bias[c], aB = ab[c];
    #pragma unroll
    for (int mf = 0; mf < 2; ++mf) {
      #pragma unroll
      for (int r = 0; r < 16; ++r) {
        int t = t0 + wm * 64 + mf * 32 + (r & 3) + 8 * (r >> 2) + 4 * lk;
        if (t < T) {
          float v = acc[mf][nf][r] + bb;
          if (t >= len) v = 0.f;
          v += aB;
          if (STORET) out[((size_t)b * MAS + c) * T + t] = v;
          else        out[((size_t)b * T + t) * MAS + c] = v;
        }
      }
    }
  }
}

// ---------------- scores + softmax + safe_log ----------------
__global__ __launch_bounds__(512)
void scores_k(const float* __restrict__ q, const float* __restrict__ kT,
              const int* __restrict__ xl, const int* __restrict__ yl,
              float* __restrict__ oattn, float* __restrict__ ologp)
{
  __shared__ float qs[16 * 384];
  __shared__ float tmp[8];
  const int b = blockIdx.y, y0 = blockIdx.x * 16, tid = threadIdx.x;
  for (int e = tid; e < 16 * 384; e += 512)
    qs[e] = q[((size_t)b * TY + (y0 + e / 384)) * 384 + (e - (e / 384) * 384)];
  __syncthreads();
  float acc[16];
  #pragma unroll
  for (int i = 0; i < 16; ++i) acc[i] = 0.f;
  const int x = tid;
  if (x < TX) {
    const float* kb = kT + (size_t)b * MAS * TX + x;
    for (int d = 0; d < 384; d += 4) {
      float k0 = kb[(size_t)(d + 0) * TX], k1 = kb[(size_t)(d + 1) * TX];
      float k2 = kb[(size_t)(d + 2) * TX], k3 = kb[(size_t)(d + 3) * TX];
      #pragma unroll
      for (int yy = 0; yy < 16; ++yy) {
        float4 qv = *(const float4*)&qs[yy * 384 + d];
        acc[yy] = fmaf(qv.x, k0, fmaf(qv.y, k1, fmaf(qv.z, k2, fmaf(qv.w, k3, acc[yy]))));
      }
    }
  }
  const int xlen = xl[b], ylen = yl[b];
  const float scale = 0.05103103630798288f;
  const bool xpad = (x >= xlen);
  const int wv = tid >> 6, ln = tid & 63;
  #pragma unroll 1
  for (int yy = 0; yy < 16; ++yy) {
    int y = y0 + yy;
    float s = -3.0e38f;
    if (x < TX) {
      s = acc[yy] * scale;
      if (xpad && (y >= ylen)) s = -1e-9f;
    }
    float m = s;
    for (int off = 32; off; off >>= 1) m = fmaxf(m, __shfl_xor(m, off));
    if (ln == 0) tmp[wv] = m;
    __syncthreads();
    float mx = fmaxf(fmaxf(fmaxf(tmp[0], tmp[1]), fmaxf(tmp[2], tmp[3])),
                     fmaxf(fmaxf(tmp[4], tmp[5]), fmaxf(tmp[6], tmp[7])));
    __syncthreads();
    float e = (x < TX) ? expf(s - mx) : 0.f;
    float sm = e;
    for (int off = 32; off; off >>= 1) sm += __shfl_xor(sm, off);
    if (ln == 0) tmp[wv] = sm;
    __syncthreads();
    float tot = tmp[0] + tmp[1] + tmp[2] + tmp[3] + tmp[4] + tmp[5] + tmp[6] + tmp[7];
    __syncthreads();
    if (x < TX) {
      float w = e / tot;
      size_t o = ((size_t)b * TY + y) * TX + x;
      oattn[o] = w;
      ologp[o] = logf(w + 1e-6f);
    }
  }
}

// ---------------- MAS fused: 4-wave super-wave DP, sub-block double-buffered LDS reads ----------------
#define MLD4(sbv, Lbuf) do {                                              \
    _Pragma("unroll")                                                     \
    for (int r_ = 0; r_ < 4; ++r_) {                                      \
      const int row_ = (sbv) * 4 + r_;                                    \
      Lbuf[r_][0] = *(const float2*)&half[row_ * 400 + a0];               \
      Lbuf[r_][1] = *(const float2*)&half[row_ * 400 + a1];               \
      Lbuf[r_][2] = *(const float2*)&half[row_ * 400 + a2];               \
    } } while (0)

#define MCMP4(sbv, Lbuf) do {                                             \
    _Pragma("unroll")                                                     \
    for (int r_ = 0; r_ < 4; ++r_) {                                      \
      const int y_ = ybase + (sbv) * 4 + r_;                              \
      float lp[6] = {Lbuf[r_][0].x + wxm[0], Lbuf[r_][0].y + wxm[1],      \
                     Lbuf[r_][1].x + wxm[2], Lbuf[r_][1].y + wxm[3],      \
                     Lbuf[r_][2].x + wxm[4], Lbuf[r_][2].y + wxm[5]};     \
      if (phase1) {                                                       \
        int c_ = y_ - p0;                                                 \
        _Pragma("unroll")                                                 \
        for (int j_ = 0; j_ < 6; ++j_) lp[j_] = (j_ <= c_) ? lp[j_] : NEGV; \
      }                                                                   \
      unsigned pr_ = ((w[3] > w[4]) ? 1u : 0u) | ((w[4] > w[5]) ? 2u : 0u); \
      p16 |= pr_ << ((y_ & 7) * 2);                                       \
      float nw[6];                                                        \
      nw[0] = lp[0] + w[0];                                               \
      _Pragma("unroll")                                                   \
      for (int j_ = 1; j_ < 6; ++j_) nw[j_] = lp[j_] + fmaxf(w[j_], w[j_ - 1]); \
      _Pragma("unroll")                                                   \
      for (int j_ = 0; j_ < 6; ++j_) w[j_] = nw[j_];                      \
    } } while (0)

#define FLUSHBITS(y7_) do {                                               \
    unsigned lo = 0, hi = 0;                                              \
    _Pragma("unroll")                                                     \
    for (int r2_ = 0; r2_ < 4; ++r2_) {                                   \
      lo |= ((p16 >> (2 * r2_)) & 3u) << (8 * r2_);                       \
      hi |= ((p16 >> (2 * r2_ + 8)) & 3u) << (8 * r2_);                   \
    }                                                                     \
    unsigned lo1 = (unsigned)__shfl_xor((int)lo, 1), hi1 = (unsigned)__shfl_xor((int)hi, 1); \
    lo |= lo1 << 2; hi |= hi1 << 2;                                       \
    unsigned lo2 = (unsigned)__shfl_xor((int)lo, 2), hi2 = (unsigned)__shfl_xor((int)hi, 2); \
    lo |= lo2 << 4; hi |= hi2 << 4;                                       \
    if ((GL & 3) == 0 && GL < 200) {                                      \
      unsigned long long E = (unsigned long long)lo | ((unsigned long long)hi << 32); \
      *(unsigned long long*)&lbits[(size_t)((y7_) >> 3) * 512 + (size_t)(GL >> 2) * 8] = E; \
    }                                                                     \
    p16 = 0; } while (0)

#define PUBEX() do {                                                      \
    if (GL < 200) { vbuf[pb][2 * GL] = w[4]; vbuf[pb][2 * GL + 1] = w[5]; } \
    __syncthreads();                                                      \
    _Pragma("unroll")                                                     \
    for (int j_ = 0; j_ < 4; ++j_) {                                      \
      int x_ = p0 + j_;                                                   \
      w[j_] = (x_ >= 0 && GL < 200) ? vbuf[pb][x_] : NEGV;                \
    }                                                                     \
    pb ^= 1; } while (0)

__global__ __launch_bounds__(256, 1)
void mas_k(const float* __restrict__ logprob, const int* __restrict__ xl,
           const int* __restrict__ yl, float* __restrict__ hard, float* __restrict__ dur)
{
  __shared__ float ring[12800];              // 2 slots x 16 rows x 400 floats
  __shared__ unsigned char lbits[102400];    // [yblk 200][byte 64][8 rows]
  __shared__ float vbuf[2][400];             // boundary-exchange rows
  const int b = blockIdx.x;
  const int tid = threadIdx.x, wid = tid >> 6;
  const int GL = tid;                        // owns x = 2GL, 2GL+1
  const int xlen = xl[b], ylen = yl[b];
  const float* lpb = logprob + (size_t)b * TY * TX;
  const int p0 = GL * 2 - 4;

  int a0 = p0, a1 = p0 + 2, a2 = p0 + 4;
  a0 = a0 < 0 ? 0 : (a0 > 398 ? 398 : a0);
  a1 = a1 < 0 ? 0 : (a1 > 398 ? 398 : a1);
  a2 = a2 < 0 ? 0 : (a2 > 398 ? 398 : a2);

  float w[6], wxm[6];
  #pragma unroll
  for (int j = 0; j < 6; ++j) {
    int x = p0 + j;
    wxm[j] = (x >= 0 && x < xlen) ? 0.f : NEGV;
    w[j] = (x == 0) ? 0.f : NEGV;
  }

  const char* lpc = (const char*)lpb;
  constexpr size_t maxgs = (size_t)TY * 1600 - 25600;
  char* ringc = (char*)ring;
  const int lane = tid & 63;
  auto issue_group = [&](int g) {
    size_t gs = (size_t)g * 25600; if (gs > maxgs) gs = maxgs;
    for (int c = wid; c < 25; c += 4)
      __builtin_amdgcn_global_load_lds(
          (const __attribute__((address_space(1))) void*)(lpc + gs + (size_t)c * 1024 + (size_t)lane * 16),
          (__attribute__((address_space(3))) void*)(ringc + (g & 1) * 25600 + c * 1024), 16, 0, 0);
  };

  issue_group(0);
  issue_group(1);

  int pb = 0;
  unsigned p16 = 0;
  const int ngroups = (ylen + 15) >> 4;
  #pragma unroll 1
  for (int g = 0; g < ngroups; ++g) {
    if (wid == 0) asm volatile("s_waitcnt vmcnt(7)" ::: "memory");
    else          asm volatile("s_waitcnt vmcnt(6)" ::: "memory");
    __builtin_amdgcn_sched_barrier(0);
    __syncthreads();
    const float* half = ring + (g & 1) * 6400;
    const int ybase = g * 16;
    const bool phase1 = (ybase < TX);
    float2 LA[4][3], LB[4][3];
    MLD4(0, LA);
    // sb0: compute LA, prefetch sb1 into LB before barrier
    MCMP4(0, LA);
    MLD4(1, LB);
    PUBEX();
    // sb1
    MCMP4(1, LB);
    FLUSHBITS(ybase + 7);
    MLD4(2, LA);
    PUBEX();
    // sb2
    MCMP4(2, LA);
    MLD4(3, LB);
    PUBEX();
    // sb3
    MCMP4(3, LB);
    FLUSHBITS(ybase + 15);
    PUBEX();
    __builtin_amdgcn_sched_barrier(0);
    issue_group(g + 2);
  }

  __syncthreads();
  if (wid != 0) return;

  // backtrack: wave 0 only; uniform scalar walk via readlane; window from LDS bits
  int x = xlen - 1;
  int cnt = 0;
  float* hb = hard + (size_t)b * TX * TY;
  float* db = dur + (size_t)b * TX;

  #pragma unroll 1
  for (int ycur = ylen - 1; ycur >= 0; ycur -= 64) {
    int lo = x - 63; if (lo < 0) lo = 0;
    const int wb = (lo >> 3) & ~3;
    int ry = ycur - lane;
    unsigned w0 = 0, w1 = 0, w2 = 0;
    if (ry >= 0) {
      const unsigned char* p = lbits + (size_t)(ry >> 3) * 512 + (ry & 7);
      unsigned bt_[12];
      #pragma unroll
      for (int j = 0; j < 12; ++j) bt_[j] = p[(size_t)(wb + j) * 8];
      w0 = bt_[0] | (bt_[1] << 8) | (bt_[2] << 16) | (bt_[3] << 24);
      w1 = bt_[4] | (bt_[5] << 8) | (bt_[6] << 16) | (bt_[7] << 24);
      w2 = bt_[8] | (bt_[9] << 8) | (bt_[10] << 16) | (bt_[11] << 24);
    }
    const int rows = (ycur + 1 < 64) ? (ycur + 1) : 64;
    #pragma unroll 1
    for (int s = 0; s < rows; s += 8) {
      const int cnt8 = (rows - s < 8) ? (rows - s) : 8;
      unsigned r0[8], r1[8], r2[8];
      #pragma unroll
      for (int u = 0; u < 8; ++u) {
        r0[u] = (unsigned)__builtin_amdgcn_readlane((int)w0, s + u);
        r1[u] = (unsigned)__builtin_amdgcn_readlane((int)w1, s + u);
        r2[u] = (unsigned)__builtin_amdgcn_readlane((int)w2, s + u);
      }
      #pragma unroll
      for (int u = 0; u < 8; ++u) {
        if (u < cnt8) {
          const int yy = ycur - s - u;
          ++cnt;
          if (yy > 0 && x > 0) {
            const int boff = (x >> 3) - wb;
            const unsigned word = (boff < 4) ? r0[u] : ((boff < 8) ? r1[u] : r2[u]);
            const unsigned byte = word >> ((boff & 3) * 8);
            if ((x == yy) || ((byte >> (x & 7)) & 1)) {
              for (int q = lane; q < cnt; q += 64) hb[(size_t)x * TY + yy + q] = 1.0f;
              if (lane == 0) db[x] = (float)cnt;
              cnt = 0;
              --x;
            }
          }
        }
      }
    }
  }
  for (int q = lane; q < cnt; q += 64) hb[(size_t)x * TY + q] = 1.0f;
  if (lane == 0) db[x] = (float)cnt;
}

extern "C" void kernel_launch(void* const* d_in, const int* in_sizes, int n_in,
                              void* d_out, int out_size, void* d_ws, size_t ws_size,
                              hipStream_t stream) {
  const float* mel_x  = (const float*)d_in[0];
  const float* txt_x  = (const float*)d_in[1];
  const float* mel_w1 = (const float*)d_in[2];
  const float* mel_b1 = (const float*)d_in[3];
  const float* mel_w2 = (const float*)d_in[4];
  const float* mel_b2 = (const float*)d_in[5];
  const float* txt_w1 = (const float*)d_in[6];
  const float* txt_b1 = (const float*)d_in[7];
  const float* txt_w2 = (const float*)d_in[8];
  const float* txt_b2 = (const float*)d_in[9];
  const float* wq     = (const float*)d_in[10];
  const float* bq     = (const float*)d_in[11];
  const float* wk     = (const float*)d_in[12];
  const float* bk     = (const float*)d_in[13];
  const int*   xl     = (const int*)d_in[14];
  const int*   yl     = (const int*)d_in[15];

  char* wsb = (char*)d_ws;
  constexpr size_t MXH   = 0;
  constexpr size_t MXL   = MXH   + 4915200;
  constexpr size_t TXH   = MXL   + 4915200;
  constexpr size_t TXL   = TXH   + 6553600;
  constexpr size_t KTF   = TXH;
  constexpr size_t WFMH  = TXL   + 6553600;
  constexpr size_t WFML  = WFMH  + 2949120;
  constexpr size_t WFTH  = WFML  + 2949120;
  constexpr size_t WFTL  = WFTH  + 1769472;
  constexpr size_t B2M   = WFTL  + 1769472;
  constexpr size_t B2T   = B2M   + 2048;
  constexpr size_t HH    = B2T   + 2048;
  constexpr size_t HL    = HH    + 39321600;
  constexpr size_t SCR   = HL    + 39321600;
  constexpr size_t W1MH  = SCR;
  constexpr size_t W1ML  = W1MH  + 1474560;
  constexpr size_t W1TH  = W1ML  + 1474560;
  constexpr size_t W1TL  = W1TH  + 4718592;
  constexpr size_t WQH   = W1TL  + 4718592;
  constexpr size_t WQL   = WQH   + 294912;
  constexpr size_t WKH   = WQL   + 294912;
  constexpr size_t WKL   = WKH   + 294912;
  constexpr size_t W2TMH = WKL   + 294912;
  constexpr size_t W2TML = W2TMH + 2949120;
  constexpr size_t W2TTH = W2TML + 2949120;
  constexpr size_t W2TTL = W2TTH + 1769472;
  constexpr size_t QF    = SCR;

  float* out = (float*)d_out;
  float* o_attn = out;
  float* o_logp = out + (size_t)10240000;
  float* o_hard = out + (size_t)20480000;
  float* o_dur  = out + (size_t)30720000;

  hipMemsetAsync(o_hard, 0, (size_t)(10240000 + 6400) * sizeof(float), stream);

  split_pad_k<<<9600, 256, 0, stream>>>(mel_x, (__bf16*)(wsb + MXH), (__bf16*)(wsb + MXL), 80, 96, 2457600L);
  split_pad_k<<<12800, 256, 0, stream>>>(txt_x, (__bf16*)(wsb + TXH), (__bf16*)(wsb + TXL), 512, 512, 3276800L);
  wsplit_k<<<2880, 256, 0, stream>>>(mel_w1, (__bf16*)(wsb + W1MH), (__bf16*)(wsb + W1ML), 80, 5, 96, 737280L);
  wsplit_k<<<9216, 256, 0, stream>>>(txt_w1, (__bf16*)(wsb + W1TH), (__bf16*)(wsb + W1TL), 512, 3, 512, 2359296L);
  wsplit_k<<<576, 256, 0, stream>>>(wq, (__bf16*)(wsb + WQH), (__bf16*)(wsb + WQL), 384, 1, 384, 147456L);
  wsplit_k<<<576, 256, 0, stream>>>(wk, (__bf16*)(wsb + WKH), (__bf16*)(wsb + WKL), 384, 1, 384, 147456L);
  tsplit_k<<<5760, 256, 0, stream>>>(mel_w2, (__bf16*)(wsb + W2TMH), (__bf16*)(wsb + W2TML), 3840, 1474560L);
  tsplit_k<<<3456, 256, 0, stream>>>(txt_w2, (__bf16*)(wsb + W2TTH), (__bf16*)(wsb + W2TTL), 2304, 884736L);
  fold_mfma<5><<<dim3(60, 3), 256, 0, stream>>>(
      (const __bf16*)(wsb + W2TMH), (const __bf16*)(wsb + W2TML),
      (const __bf16*)(wsb + WQH), (const __bf16*)(wsb + WQL),
      (__bf16*)(wsb + WFMH), (__bf16*)(wsb + WFML));
  fold_mfma<3><<<dim3(36, 3), 256, 0, stream>>>(
      (const __bf16*)(wsb + W2TTH), (const __bf16*)(wsb + W2TTL),
      (const __bf16*)(wsb + WKH), (const __bf16*)(wsb + WKL),
      (__bf16*)(wsb + WFTH), (__bf16*)(wsb + WFTL));
  fold_bias_k<<<1, 384, 0, stream>>>(wq, mel_b2, (float*)(wsb + B2M));
  fold_bias_k<<<1, 384, 0, stream>>>(wk, txt_b2, (float*)(wsb + B2T));

  // text pipeline: conv1 -> conv2(folded) writes kT directly
  conv1_mfma<512, 3, 400><<<dim3(4, 12, B), 256, 0, stream>>>(
      (const __bf16*)(wsb + TXH), (const __bf16*)(wsb + TXL),
      (const __bf16*)(wsb + W1TH), (const __bf16*)(wsb + W1TL),
      txt_b1, xl, (__bf16*)(wsb + HH), (__bf16*)(wsb + HL));
  conv2_mfma<3, 400, true><<<dim3(4, 2, B), 256, 0, stream>>>(
      (const __bf16*)(wsb + HH), (const __bf16*)(wsb + HL),
      (const __bf16*)(wsb + WFTH), (const __bf16*)(wsb + WFTL),
      (const float*)(wsb + B2T), bk, xl, (float*)(wsb + KTF));

  // mel pipeline: conv1 -> conv2(folded) writes q directly
  conv1_mfma<96, 5, 1600><<<dim3(13, 12, B), 256, 0, stream>>>(
      (const __bf16*)(wsb + MXH), (const __bf16*)(wsb + MXL),
      (const __bf16*)(wsb + W1MH), (const __bf16*)(wsb + W1ML),
      mel_b1, yl, (__bf16*)(wsb + HH), (__bf16*)(wsb + HL));
  conv2_mfma<5, 1600, false><<<dim3(13, 2, B), 256, 0, stream>>>(
      (const __bf16*)(wsb + HH), (const __bf16*)(wsb + HL),
      (const __bf16*)(wsb + WFMH), (const __bf16*)(wsb + WFML),
      (const float*)(wsb + B2M), bq, yl, (float*)(wsb + QF));

  // attention + MAS (fused fwd+bt, 4-wave super-wave, pipelined LDS reads)
  scores_k<<<dim3(100, B), 512, 0, stream>>>(
      (const float*)(wsb + QF), (const float*)(wsb + KTF), xl, yl, o_attn, o_logp);
  mas_k<<<B, 256, 0, stream>>>(o_logp, xl, yl, o_hard, o_dur);
}

// Round 17
// 1435.111 us; speedup vs baseline: 1.3088x; 1.0010x over previous
//
#include <hip/hip_runtime.h>
#include <cstdint>

#define B 16
#define TY 1600
#define TX 400
#define MAS 384
#define HID 768
#define NEGV -1e9f

typedef __bf16 bf16x8 __attribute__((ext_vector_type(8)));
typedef float  f32x4  __attribute__((ext_vector_type(4)));
typedef float  f32x16 __attribute__((ext_vector_type(16)));

__device__ __forceinline__ f32x4 mfma16(bf16x8 a, bf16x8 b, f32x4 c) {
  return __builtin_amdgcn_mfma_f32_16x16x32_bf16(a, b, c, 0, 0, 0);
}
__device__ __forceinline__ f32x16 mfma32(bf16x8 a, bf16x8 b, f32x16 c) {
  return __builtin_amdgcn_mfma_f32_32x32x16_bf16(a, b, c, 0, 0, 0);
}

// ---------------- fp32 -> bf16 hi/lo split with channel padding ----------------
__global__ void split_pad_k(const float* __restrict__ in, __bf16* __restrict__ oh,
                            __bf16* __restrict__ ol, int CIN, int CINP, long n) {
  long i = (long)blockIdx.x * 256 + threadIdx.x;
  if (i >= n) return;
  long row = i / CINP; int ci = (int)(i - row * CINP);
  float v = (ci < CIN) ? in[row * CIN + ci] : 0.f;
  __bf16 h = (__bf16)v;
  oh[i] = h; ol[i] = (__bf16)(v - (float)h);
}

// ---------------- weight repack+split: w[N][CIN][K] -> oh/ol[N][k*CINP + ci] ----------------
__global__ void wsplit_k(const float* __restrict__ w, __bf16* __restrict__ oh,
                         __bf16* __restrict__ ol, int CIN, int K_, int CINP, long n) {
  long i = (long)blockIdx.x * 256 + threadIdx.x;
  if (i >= n) return;
  long kdspan = (long)K_ * CINP;
  long nn = i / kdspan; int kd = (int)(i - nn * kdspan);
  int k = kd / CINP, ci = kd - k * CINP;
  float v = (ci < CIN) ? w[(nn * CIN + ci) * K_ + k] : 0.f;
  __bf16 h = (__bf16)v;
  oh[i] = h; ol[i] = (__bf16)(v - (float)h);
}

// ---------------- transpose+split: w2 [m][JTOT] -> oh/ol [j][384] ----------------
__global__ void tsplit_k(const float* __restrict__ in, __bf16* __restrict__ oh,
                         __bf16* __restrict__ ol, int JTOT, long n) {
  long i = (long)blockIdx.x * 256 + threadIdx.x;
  if (i >= n) return;
  int m = (int)(i / JTOT), j = (int)(i - (long)m * JTOT);
  float v = in[i];
  long o = (long)j * 384 + m;
  __bf16 h = (__bf16)v;
  oh[o] = h; ol[o] = (__bf16)(v - (float)h);
}

// ---------------- bias fold: o[n] = sum_m wq[n][m] * b[m] ----------------
__global__ void fold_bias_k(const float* __restrict__ wq, const float* __restrict__ b,
                            float* __restrict__ o) {
  int n = threadIdx.x;
  float s = 0.f;
  for (int m = 0; m < 384; ++m) s = fmaf(wq[n * 384 + m], b[m], s);
  o[n] = s;
}

// ---------------- weight-fold GEMM (conv2-staging-native output layout) ----------------
template<int KK>
__global__ __launch_bounds__(256)
void fold_mfma(const __bf16* __restrict__ xh, const __bf16* __restrict__ xl,
               const __bf16* __restrict__ wh, const __bf16* __restrict__ wl,
               __bf16* __restrict__ oh, __bf16* __restrict__ ol)
{
  constexpr int CINP = 384, ROWS = 64, STRIDE = 65;
  __shared__ float4 xs[8 * STRIDE];
  const int t0 = blockIdx.x * 64, n0 = blockIdx.y * 128;
  const int tid = threadIdx.x, wn = tid >> 6, lane = tid & 63;
  const int lr = lane & 15, lg = lane >> 4;
  const f32x4 Z4 = {0.f, 0.f, 0.f, 0.f};
  f32x4 acc[4][2];
  #pragma unroll
  for (int m = 0; m < 4; ++m) { acc[m][0] = Z4; acc[m][1] = Z4; }

  #pragma unroll 1
  for (int ci0 = 0; ci0 < CINP; ci0 += 32) {
    __syncthreads();
    for (int e = tid; e < ROWS * 8; e += 256) {
      int row = e >> 3, sc = e & 7, spl = sc >> 2, cg = sc & 3;
      int t = t0 + row;
      xs[(spl * 4 + cg) * STRIDE + row] =
          *(const float4*)((spl ? xl : xh) + (size_t)t * CINP + ci0 + cg * 8);
    }
    __syncthreads();
    bf16x8 ah[4], al[4];
    #pragma unroll
    for (int mf = 0; mf < 4; ++mf) {
      int row = mf * 16 + lr;
      ah[mf] = *(const bf16x8*)&xs[lg * STRIDE + row];
      al[mf] = *(const bf16x8*)&xs[(4 + lg) * STRIDE + row];
    }
    size_t kd = (size_t)ci0 + lg * 8;
    bf16x8 bh[2], bl[2];
    #pragma unroll
    for (int nf = 0; nf < 2; ++nf) {
      int nc = n0 + wn * 32 + nf * 16 + lr;
      bh[nf] = *(const bf16x8*)(wh + (size_t)nc * 384 + kd);
      bl[nf] = *(const bf16x8*)(wl + (size_t)nc * 384 + kd);
    }
    #pragma unroll
    for (int nf = 0; nf < 2; ++nf)
      #pragma unroll
      for (int mf = 0; mf < 4; ++mf) acc[mf][nf] = mfma16(ah[mf], bh[nf], acc[mf][nf]);
    #pragma unroll
    for (int nf = 0; nf < 2; ++nf)
      #pragma unroll
      for (int mf = 0; mf < 4; ++mf) acc[mf][nf] = mfma16(ah[mf], bl[nf], acc[mf][nf]);
    #pragma unroll
    for (int nf = 0; nf < 2; ++nf)
      #pragma unroll
      for (int mf = 0; mf < 4; ++mf) acc[mf][nf] = mfma16(al[mf], bh[nf], acc[mf][nf]);
  }
  #pragma unroll
  for (int nf = 0; nf < 2; ++nf) {
    int c = n0 + wn * 32 + nf * 16 + lr;
    #pragma unroll
    for (int mf = 0; mf < 4; ++mf) {
      #pragma unroll
      for (int r = 0; r < 4; ++r) {
        int j = t0 + mf * 16 + lg * 4 + r;   // j = ci*KK + k
        int k = j % KK, ci = j / KK;
        size_t o = (size_t)((((ci >> 4) * KK + k) * 2 + ((ci >> 3) & 1)) * 3072)
                 + (size_t)c * 8 + (ci & 7);
        float v = acc[mf][nf][r];
        __bf16 vh = (__bf16)v;
        oh[o] = vh; ol[o] = (__bf16)(v - (float)vh);
      }
    }
  }
}

// ---------------- conv1 + ReGLU, split-bf16 MFMA ----------------
template<int CINP, int K, int T>
__global__ __launch_bounds__(256)
void conv1_mfma(const __bf16* __restrict__ xh, const __bf16* __restrict__ xl,
                const __bf16* __restrict__ wh, const __bf16* __restrict__ wl,
                const float* __restrict__ bias, const int* __restrict__ lens,
                __bf16* __restrict__ hh, __bf16* __restrict__ hl)
{
  constexpr int BM = 128, PAD = K / 2, ROWS = BM + K - 1, KD = K * CINP;
  __shared__ float4 xs[8 * ROWS];
  const int b = blockIdx.z, t0 = blockIdx.x * BM, n0 = blockIdx.y * 64;
  const int tid = threadIdx.x, wid = tid >> 6, lane = tid & 63;
  const int wm = wid >> 1, wn = wid & 1, lr = lane & 15, lg = lane >> 4;
  const int len = lens[b];
  const f32x4 Z4 = {0.f, 0.f, 0.f, 0.f};
  f32x4 acc_a[4][2], acc_g[4][2];
  #pragma unroll
  for (int m = 0; m < 4; ++m)
    #pragma unroll
    for (int n = 0; n < 2; ++n) { acc_a[m][n] = Z4; acc_g[m][n] = Z4; }

  #pragma unroll 1
  for (int ci0 = 0; ci0 < CINP; ci0 += 32) {
    __syncthreads();
    for (int e = tid; e < ROWS * 8; e += 256) {
      int row = e >> 3, sc = e & 7, spl = sc >> 2, cg = sc & 3;
      int t = t0 + row - PAD;
      float4 v = {0.f, 0.f, 0.f, 0.f};
      if (t >= 0 && t < len)
        v = *(const float4*)((spl ? xl : xh) + ((size_t)b * T + t) * CINP + ci0 + cg * 8);
      xs[(spl * 4 + cg) * ROWS + row] = v;
    }
    __syncthreads();
    #pragma unroll
    for (int k = 0; k < K; ++k) {
      bf16x8 ah[4], al[4];
      #pragma unroll
      for (int mf = 0; mf < 4; ++mf) {
        int row = wm * 64 + mf * 16 + lr + k;
        ah[mf] = *(const bf16x8*)&xs[lg * ROWS + row];
        al[mf] = *(const bf16x8*)&xs[(4 + lg) * ROWS + row];
      }
      size_t kd = (size_t)k * CINP + ci0 + lg * 8;
      #pragma unroll
      for (int nf = 0; nf < 2; ++nf) {
        int na = n0 + wn * 32 + nf * 16 + lr;
        bf16x8 bah = *(const bf16x8*)(wh + (size_t)na * KD + kd);
        bf16x8 bal = *(const bf16x8*)(wl + (size_t)na * KD + kd);
        bf16x8 bgh = *(const bf16x8*)(wh + (size_t)(na + HID) * KD + kd);
        bf16x8 bgl = *(const bf16x8*)(wl + (size_t)(na + HID) * KD + kd);
        #pragma unroll
        for (int mf = 0; mf < 4; ++mf) {
          acc_a[mf][nf] = mfma16(ah[mf], bah, acc_a[mf][nf]);
          acc_a[mf][nf] = mfma16(ah[mf], bal, acc_a[mf][nf]);
          acc_a[mf][nf] = mfma16(al[mf], bah, acc_a[mf][nf]);
          acc_g[mf][nf] = mfma16(ah[mf], bgh, acc_g[mf][nf]);
          acc_g[mf][nf] = mfma16(ah[mf], bgl, acc_g[mf][nf]);
          acc_g[mf][nf] = mfma16(al[mf], bgh, acc_g[mf][nf]);
        }
      }
    }
  }
  #pragma unroll
  for (int nf = 0; nf < 2; ++nf) {
    int c = n0 + wn * 32 + nf * 16 + lr;
    float ba = bias[c], bg = bias[c + HID];
    #pragma unroll
    for (int mf = 0; mf < 4; ++mf) {
      #pragma unroll
      for (int r = 0; r < 4; ++r) {
        int t = t0 + wm * 64 + mf * 16 + lg * 4 + r;
        if (t < T) {
          float a = acc_a[mf][nf][r] + ba;
          float g = acc_g[mf][nf][r] + bg;
          float v = a * fmaxf(g, 0.f);
          __bf16 vh = (__bf16)v;
          size_t o = ((size_t)b * T + t) * HID + c;
          hh[o] = vh;
          hl[o] = (__bf16)(v - (float)vh);
        }
      }
    }
  }
}

// ---------------- conv2 (folded weights), 32x32x16, B staged in LDS via global_load_lds ----------------
template<int K, int T, bool STORET>
__global__ __launch_bounds__(256)
void conv2_mfma(const __bf16* __restrict__ xh, const __bf16* __restrict__ xl,
                const __bf16* __restrict__ wh, const __bf16* __restrict__ wl,
                const float* __restrict__ bias, const float* __restrict__ ab,
                const int* __restrict__ lens, float* __restrict__ out)
{
  constexpr int CINP = 768, BM = 128, PAD = K / 2, ROWS = BM + K - 1, STRIDE = ROWS + 1;
  constexpr int BROWS = K * 2;
  __shared__ float4 xa[4 * STRIDE];
  __shared__ float4 bs[2 * BROWS * 192];
  const int b = blockIdx.z, t0 = blockIdx.x * BM, n0 = blockIdx.y * 192;
  const int tid = threadIdx.x, wid = tid >> 6, lane = tid & 63;
  const int wm = wid >> 1, wn = wid & 1, lc = lane & 31, lk = lane >> 5;
  const int len = lens[b];
  f32x16 acc[2][3];
  #pragma unroll
  for (int m = 0; m < 2; ++m)
    #pragma unroll
    for (int n = 0; n < 3; ++n)
      #pragma unroll
      for (int r = 0; r < 16; ++r) acc[m][n][r] = 0.f;

  #pragma unroll 1
  for (int s = 0; s < 48; ++s) {
    __syncthreads();
    for (int e = tid; e < ROWS * 4; e += 256) {
      int row = e >> 2, sc = e & 3, spl = sc >> 1, cg = sc & 1;
      int t = t0 + row - PAD;
      float4 v = {0.f, 0.f, 0.f, 0.f};
      if (t >= 0 && t < len)
        v = *(const float4*)((spl ? xl : xh) + ((size_t)b * T + t) * CINP + s * 16 + cg * 8);
      xa[(spl * 2 + cg) * STRIDE + row] = v;
    }
    for (int r = wid; r < 2 * BROWS; r += 4) {
      int spl = r / BROWS, rr = r - spl * BROWS;
      const char* src = (const char*)((spl ? wl : wh) + (size_t)(s * BROWS + rr) * 3072
                                      + (size_t)n0 * 8) + (size_t)lane * 16;
      char* dst = (char*)&bs[r * 192];
      #pragma unroll
      for (int i = 0; i < 3; ++i)
        __builtin_amdgcn_global_load_lds(
            (const __attribute__((address_space(1))) void*)(src + i * 1024),
            (__attribute__((address_space(3))) void*)(dst + i * 1024), 16, 0, 0);
    }
    __syncthreads();
    #pragma unroll
    for (int k = 0; k < K; ++k) {
      bf16x8 ah[2], al[2], bh[3], bl[3];
      #pragma unroll
      for (int mf = 0; mf < 2; ++mf) {
        int row = wm * 64 + mf * 32 + lc + k;
        ah[mf] = *(const bf16x8*)&xa[lk * STRIDE + row];
        al[mf] = *(const bf16x8*)&xa[(2 + lk) * STRIDE + row];
      }
      #pragma unroll
      for (int nf = 0; nf < 3; ++nf) {
        int col = wn * 96 + nf * 32 + lc;
        bh[nf] = *(const bf16x8*)&bs[(k * 2 + lk) * 192 + col];
        bl[nf] = *(const bf16x8*)&bs[(BROWS + k * 2 + lk) * 192 + col];
      }
      #pragma unroll
      for (int nf = 0; nf < 3; ++nf)
        #pragma unroll
        for (int mf = 0; mf < 2; ++mf)
          acc[mf][nf] = mfma32(ah[mf], bh[nf], acc[mf][nf]);
      #pragma unroll
      for (int nf = 0; nf < 3; ++nf)
        #pragma unroll
        for (int mf = 0; mf < 2; ++mf)
          acc[mf][nf] = mfma32(ah[mf], bl[nf], acc[mf][nf]);
      #pragma unroll
      for (int nf = 0; nf < 3; ++nf)
        #pragma unroll
        for (int mf = 0; mf < 2; ++mf)
          acc[mf][nf] = mfma32(al[mf], bh[nf], acc[mf][nf]);
    }
  }
  #pragma unroll
  for (int nf = 0; nf < 3; ++nf) {
    int c = n0 + wn * 96 + nf * 32 + lc;
    float bb = bias[c], aB = ab[c];
    #pragma unroll
    for (int mf = 0; mf < 2; ++mf) {
      #pragma unroll
      for (int r = 0; r < 16; ++r) {
        int t = t0 + wm * 64 + mf * 32 + (r & 3) + 8 * (r >> 2) + 4 * lk;
        if (t < T) {
          float v = acc[mf][nf][r] + bb;
          if (t >= len) v = 0.f;
          v += aB;
          if (STORET) out[((size_t)b * MAS + c) * T + t] = v;
          else        out[((size_t)b * T + t) * MAS + c] = v;
        }
      }
    }
  }
}

// ---------------- scores + softmax + safe_log ----------------
__global__ __launch_bounds__(512)
void scores_k(const float* __restrict__ q, const float* __restrict__ kT,
              const int* __restrict__ xl, const int* __restrict__ yl,
              float* __restrict__ oattn, float* __restrict__ ologp)
{
  __shared__ float qs[16 * 384];
  __shared__ float tmp[8];
  const int b = blockIdx.y, y0 = blockIdx.x * 16, tid = threadIdx.x;
  for (int e = tid; e < 16 * 384; e += 512)
    qs[e] = q[((size_t)b * TY + (y0 + e / 384)) * 384 + (e - (e / 384) * 384)];
  __syncthreads();
  float acc[16];
  #pragma unroll
  for (int i = 0; i < 16; ++i) acc[i] = 0.f;
  const int x = tid;
  if (x < TX) {
    const float* kb = kT + (size_t)b * MAS * TX + x;
    for (int d = 0; d < 384; d += 4) {
      float k0 = kb[(size_t)(d + 0) * TX], k1 = kb[(size_t)(d + 1) * TX];
      float k2 = kb[(size_t)(d + 2) * TX], k3 = kb[(size_t)(d + 3) * TX];
      #pragma unroll
      for (int yy = 0; yy < 16; ++yy) {
        float4 qv = *(const float4*)&qs[yy * 384 + d];
        acc[yy] = fmaf(qv.x, k0, fmaf(qv.y, k1, fmaf(qv.z, k2, fmaf(qv.w, k3, acc[yy]))));
      }
    }
  }
  const int xlen = xl[b], ylen = yl[b];
  const float scale = 0.05103103630798288f;
  const bool xpad = (x >= xlen);
  const int wv = tid >> 6, ln = tid & 63;
  #pragma unroll 1
  for (int yy = 0; yy < 16; ++yy) {
    int y = y0 + yy;
    float s = -3.0e38f;
    if (x < TX) {
      s = acc[yy] * scale;
      if (xpad && (y >= ylen)) s = -1e-9f;
    }
    float m = s;
    for (int off = 32; off; off >>= 1) m = fmaxf(m, __shfl_xor(m, off));
    if (ln == 0) tmp[wv] = m;
    __syncthreads();
    float mx = fmaxf(fmaxf(fmaxf(tmp[0], tmp[1]), fmaxf(tmp[2], tmp[3])),
                     fmaxf(fmaxf(tmp[4], tmp[5]), fmaxf(tmp[6], tmp[7])));
    __syncthreads();
    float e = (x < TX) ? expf(s - mx) : 0.f;
    float sm = e;
    for (int off = 32; off; off >>= 1) sm += __shfl_xor(sm, off);
    if (ln == 0) tmp[wv] = sm;
    __syncthreads();
    float tot = tmp[0] + tmp[1] + tmp[2] + tmp[3] + tmp[4] + tmp[5] + tmp[6] + tmp[7];
    __syncthreads();
    if (x < TX) {
      float w = e / tot;
      size_t o = ((size_t)b * TY + y) * TX + x;
      oattn[o] = w;
      ologp[o] = logf(w + 1e-6f);
    }
  }
}

// ---------------- MAS fused: 4-wave super-wave DP, raw-barrier exchanges (no vmcnt drain) ----------------
#define MLD4(sbv, Lbuf) do {                                              \
    _Pragma("unroll")                                                     \
    for (int r_ = 0; r_ < 4; ++r_) {                                      \
      const int row_ = (sbv) * 4 + r_;                                    \
      Lbuf[r_][0] = *(const float2*)&half[row_ * 400 + a0];               \
      Lbuf[r_][1] = *(const float2*)&half[row_ * 400 + a1];               \
      Lbuf[r_][2] = *(const float2*)&half[row_ * 400 + a2];               \
    } } while (0)

#define MCMP4(sbv, Lbuf) do {                                             \
    _Pragma("unroll")                                                     \
    for (int r_ = 0; r_ < 4; ++r_) {                                      \
      const int y_ = ybase + (sbv) * 4 + r_;                              \
      float lp[6] = {Lbuf[r_][0].x + wxm[0], Lbuf[r_][0].y + wxm[1],      \
                     Lbuf[r_][1].x + wxm[2], Lbuf[r_][1].y + wxm[3],      \
                     Lbuf[r_][2].x + wxm[4], Lbuf[r_][2].y + wxm[5]};     \
      if (phase1) {                                                       \
        int c_ = y_ - p0;                                                 \
        _Pragma("unroll")                                                 \
        for (int j_ = 0; j_ < 6; ++j_) lp[j_] = (j_ <= c_) ? lp[j_] : NEGV; \
      }                                                                   \
      unsigned pr_ = ((w[3] > w[4]) ? 1u : 0u) | ((w[4] > w[5]) ? 2u : 0u); \
      p16 |= pr_ << ((y_ & 7) * 2);                                       \
      float nw[6];                                                        \
      nw[0] = lp[0] + w[0];                                               \
      _Pragma("unroll")                                                   \
      for (int j_ = 1; j_ < 6; ++j_) nw[j_] = lp[j_] + fmaxf(w[j_], w[j_ - 1]); \
      _Pragma("unroll")                                                   \
      for (int j_ = 0; j_ < 6; ++j_) w[j_] = nw[j_];                      \
    } } while (0)

#define FLUSHBITS(y7_) do {                                               \
    unsigned lo = 0, hi = 0;                                              \
    _Pragma("unroll")                                                     \
    for (int r2_ = 0; r2_ < 4; ++r2_) {                                   \
      lo |= ((p16 >> (2 * r2_)) & 3u) << (8 * r2_);                       \
      hi |= ((p16 >> (2 * r2_ + 8)) & 3u) << (8 * r2_);                   \
    }                                                                     \
    unsigned lo1 = (unsigned)__shfl_xor((int)lo, 1), hi1 = (unsigned)__shfl_xor((int)hi, 1); \
    lo |= lo1 << 2; hi |= hi1 << 2;                                       \
    unsigned lo2 = (unsigned)__shfl_xor((int)lo, 2), hi2 = (unsigned)__shfl_xor((int)hi, 2); \
    lo |= lo2 << 4; hi |= hi2 << 4;                                       \
    if ((GL & 3) == 0 && GL < 200) {                                      \
      unsigned long long E = (unsigned long long)lo | ((unsigned long long)hi << 32); \
      *(unsigned long long*)&lbits[(size_t)((y7_) >> 3) * 512 + (size_t)(GL >> 2) * 8] = E; \
    }                                                                     \
    p16 = 0; } while (0)

// raw barrier: drain LDS ops only (NOT vmcnt), then hw barrier (keeps gload_lds stream alive)
#define LBAR() do {                                                       \
    asm volatile("s_waitcnt lgkmcnt(0)" ::: "memory");                    \
    __builtin_amdgcn_sched_barrier(0);                                    \
    __builtin_amdgcn_s_barrier();                                         \
    __builtin_amdgcn_sched_barrier(0); } while (0)

#define PUBEX() do {                                                      \
    if (GL < 200) { vbuf[pb][2 * GL] = w[4]; vbuf[pb][2 * GL + 1] = w[5]; } \
    LBAR();                                                               \
    _Pragma("unroll")                                                     \
    for (int j_ = 0; j_ < 4; ++j_) {                                      \
      int x_ = p0 + j_;                                                   \
      w[j_] = (x_ >= 0 && GL < 200) ? vbuf[pb][x_] : NEGV;                \
    }                                                                     \
    pb ^= 1; } while (0)

__global__ __launch_bounds__(256, 1)
void mas_k(const float* __restrict__ logprob, const int* __restrict__ xl,
           const int* __restrict__ yl, float* __restrict__ hard, float* __restrict__ dur)
{
  __shared__ float ring[12800];              // 2 slots x 16 rows x 400 floats
  __shared__ unsigned char lbits[102400];    // [yblk 200][byte 64][8 rows]
  __shared__ float vbuf[2][400];             // boundary-exchange rows
  const int b = blockIdx.x;
  const int tid = threadIdx.x, wid = tid >> 6;
  const int GL = tid;                        // owns x = 2GL, 2GL+1
  const int xlen = xl[b], ylen = yl[b];
  const float* lpb = logprob + (size_t)b * TY * TX;
  const int p0 = GL * 2 - 4;

  int a0 = p0, a1 = p0 + 2, a2 = p0 + 4;
  a0 = a0 < 0 ? 0 : (a0 > 398 ? 398 : a0);
  a1 = a1 < 0 ? 0 : (a1 > 398 ? 398 : a1);
  a2 = a2 < 0 ? 0 : (a2 > 398 ? 398 : a2);

  float w[6], wxm[6];
  #pragma unroll
  for (int j = 0; j < 6; ++j) {
    int x = p0 + j;
    wxm[j] = (x >= 0 && x < xlen) ? 0.f : NEGV;
    w[j] = (x == 0) ? 0.f : NEGV;
  }

  const char* lpc = (const char*)lpb;
  constexpr size_t maxgs = (size_t)TY * 1600 - 25600;
  char* ringc = (char*)ring;
  const int lane = tid & 63;
  auto issue_group = [&](int g) {
    size_t gs = (size_t)g * 25600; if (gs > maxgs) gs = maxgs;
    for (int c = wid; c < 25; c += 4)
      __builtin_amdgcn_global_load_lds(
          (const __attribute__((address_space(1))) void*)(lpc + gs + (size_t)c * 1024 + (size_t)lane * 16),
          (__attribute__((address_space(3))) void*)(ringc + (g & 1) * 25600 + c * 1024), 16, 0, 0);
  };

  issue_group(0);
  issue_group(1);

  int pb = 0;
  unsigned p16 = 0;
  const int ngroups = (ylen + 15) >> 4;
  #pragma unroll 1
  for (int g = 0; g < ngroups; ++g) {
    // own counted vmem wait (group g's chunks landed; g+1 stays in flight), then raw barrier
    if (wid == 0) asm volatile("s_waitcnt vmcnt(7)" ::: "memory");
    else          asm volatile("s_waitcnt vmcnt(6)" ::: "memory");
    __builtin_amdgcn_sched_barrier(0);
    __builtin_amdgcn_s_barrier();
    __builtin_amdgcn_sched_barrier(0);
    const float* half = ring + (g & 1) * 6400;
    const int ybase = g * 16;
    const bool phase1 = (ybase < TX);
    float2 LA[4][3], LB[4][3];
    MLD4(0, LA);
    MCMP4(0, LA);
    MLD4(1, LB);
    PUBEX();
    MCMP4(1, LB);
    FLUSHBITS(ybase + 7);
    MLD4(2, LA);
    PUBEX();
    MCMP4(2, LA);
    MLD4(3, LB);
    PUBEX();
    MCMP4(3, LB);
    FLUSHBITS(ybase + 15);
    PUBEX();
    __builtin_amdgcn_sched_barrier(0);
    issue_group(g + 2);
  }

  __syncthreads();
  if (wid != 0) return;

  // backtrack: wave 0 only; uniform scalar walk via readlane; window from LDS bits
  int x = xlen - 1;
  int cnt = 0;
  float* hb = hard + (size_t)b * TX * TY;
  float* db = dur + (size_t)b * TX;

  #pragma unroll 1
  for (int ycur = ylen - 1; ycur >= 0; ycur -= 64) {
    int lo = x - 63; if (lo < 0) lo = 0;
    const int wb = (lo >> 3) & ~3;
    int ry = ycur - lane;
    unsigned w0 = 0, w1 = 0, w2 = 0;
    if (ry >= 0) {
      const unsigned char* p = lbits + (size_t)(ry >> 3) * 512 + (ry & 7);
      unsigned bt_[12];
      #pragma unroll
      for (int j = 0; j < 12; ++j) bt_[j] = p[(size_t)(wb + j) * 8];
      w0 = bt_[0] | (bt_[1] << 8) | (bt_[2] << 16) | (bt_[3] << 24);
      w1 = bt_[4] | (bt_[5] << 8) | (bt_[6] << 16) | (bt_[7] << 24);
      w2 = bt_[8] | (bt_[9] << 8) | (bt_[10] << 16) | (bt_[11] << 24);
    }
    const int rows = (ycur + 1 < 64) ? (ycur + 1) : 64;
    #pragma unroll 1
    for (int s = 0; s < rows; s += 8) {
      const int cnt8 = (rows - s < 8) ? (rows - s) : 8;
      unsigned r0[8], r1[8], r2[8];
      #pragma unroll
      for (int u = 0; u < 8; ++u) {
        r0[u] = (unsigned)__builtin_amdgcn_readlane((int)w0, s + u);
        r1[u] = (unsigned)__builtin_amdgcn_readlane((int)w1, s + u);
        r2[u] = (unsigned)__builtin_amdgcn_readlane((int)w2, s + u);
      }
      #pragma unroll
      for (int u = 0; u < 8; ++u) {
        if (u < cnt8) {
          const int yy = ycur - s - u;
          ++cnt;
          if (yy > 0 && x > 0) {
            const int boff = (x >> 3) - wb;
            const unsigned word = (boff < 4) ? r0[u] : ((boff < 8) ? r1[u] : r2[u]);
            const unsigned byte = word >> ((boff & 3) * 8);
            if ((x == yy) || ((byte >> (x & 7)) & 1)) {
              for (int q = lane; q < cnt; q += 64) hb[(size_t)x * TY + yy + q] = 1.0f;
              if (lane == 0) db[x] = (float)cnt;
              cnt = 0;
              --x;
            }
          }
        }
      }
    }
  }
  for (int q = lane; q < cnt; q += 64) hb[(size_t)x * TY + q] = 1.0f;
  if (lane == 0) db[x] = (float)cnt;
}

extern "C" void kernel_launch(void* const* d_in, const int* in_sizes, int n_in,
                              void* d_out, int out_size, void* d_ws, size_t ws_size,
                              hipStream_t stream) {
  const float* mel_x  = (const float*)d_in[0];
  const float* txt_x  = (const float*)d_in[1];
  const float* mel_w1 = (const float*)d_in[2];
  const float* mel_b1 = (const float*)d_in[3];
  const float* mel_w2 = (const float*)d_in[4];
  const float* mel_b2 = (const float*)d_in[5];
  const float* txt_w1 = (const float*)d_in[6];
  const float* txt_b1 = (const float*)d_in[7];
  const float* txt_w2 = (const float*)d_in[8];
  const float* txt_b2 = (const float*)d_in[9];
  const float* wq     = (const float*)d_in[10];
  const float* bq     = (const float*)d_in[11];
  const float* wk     = (const float*)d_in[12];
  const float* bk     = (const float*)d_in[13];
  const int*   xl     = (const int*)d_in[14];
  const int*   yl     = (const int*)d_in[15];

  char* wsb = (char*)d_ws;
  constexpr size_t MXH   = 0;
  constexpr size_t MXL   = MXH   + 4915200;
  constexpr size_t TXH   = MXL   + 4915200;
  constexpr size_t TXL   = TXH   + 6553600;
  constexpr size_t KTF   = TXH;
  constexpr size_t WFMH  = TXL   + 6553600;
  constexpr size_t WFML  = WFMH  + 2949120;
  constexpr size_t WFTH  = WFML  + 2949120;
  constexpr size_t WFTL  = WFTH  + 1769472;
  constexpr size_t B2M   = WFTL  + 1769472;
  constexpr size_t B2T   = B2M   + 2048;
  constexpr size_t HH    = B2T   + 2048;
  constexpr size_t HL    = HH    + 39321600;
  constexpr size_t SCR   = HL    + 39321600;
  constexpr size_t W1MH  = SCR;
  constexpr size_t W1ML  = W1MH  + 1474560;
  constexpr size_t W1TH  = W1ML  + 1474560;
  constexpr size_t W1TL  = W1TH  + 4718592;
  constexpr size_t WQH   = W1TL  + 4718592;
  constexpr size_t WQL   = WQH   + 294912;
  constexpr size_t WKH   = WQL   + 294912;
  constexpr size_t WKL   = WKH   + 294912;
  constexpr size_t W2TMH = WKL   + 294912;
  constexpr size_t W2TML = W2TMH + 2949120;
  constexpr size_t W2TTH = W2TML + 2949120;
  constexpr size_t W2TTL = W2TTH + 1769472;
  constexpr size_t QF    = SCR;

  float* out = (float*)d_out;
  float* o_attn = out;
  float* o_logp = out + (size_t)10240000;
  float* o_hard = out + (size_t)20480000;
  float* o_dur  = out + (size_t)30720000;

  hipMemsetAsync(o_hard, 0, (size_t)(10240000 + 6400) * sizeof(float), stream);

  split_pad_k<<<9600, 256, 0, stream>>>(mel_x, (__bf16*)(wsb + MXH), (__bf16*)(wsb + MXL), 80, 96, 2457600L);
  split_pad_k<<<12800, 256, 0, stream>>>(txt_x, (__bf16*)(wsb + TXH), (__bf16*)(wsb + TXL), 512, 512, 3276800L);
  wsplit_k<<<2880, 256, 0, stream>>>(mel_w1, (__bf16*)(wsb + W1MH), (__bf16*)(wsb + W1ML), 80, 5, 96, 737280L);
  wsplit_k<<<9216, 256, 0, stream>>>(txt_w1, (__bf16*)(wsb + W1TH), (__bf16*)(wsb + W1TL), 512, 3, 512, 2359296L);
  wsplit_k<<<576, 256, 0, stream>>>(wq, (__bf16*)(wsb + WQH), (__bf16*)(wsb + WQL), 384, 1, 384, 147456L);
  wsplit_k<<<576, 256, 0, stream>>>(wk, (__bf16*)(wsb + WKH), (__bf16*)(wsb + WKL), 384, 1, 384, 147456L);
  tsplit_k<<<5760, 256, 0, stream>>>(mel_w2, (__bf16*)(wsb + W2TMH), (__bf16*)(wsb + W2TML), 3840, 1474560L);
  tsplit_k<<<3456, 256, 0, stream>>>(txt_w2, (__bf16*)(wsb + W2TTH), (__bf16*)(wsb + W2TTL), 2304, 884736L);
  fold_mfma<5><<<dim3(60, 3), 256, 0, stream>>>(
      (const __bf16*)(wsb + W2TMH), (const __bf16*)(wsb + W2TML),
      (const __bf16*)(wsb + WQH), (const __bf16*)(wsb + WQL),
      (__bf16*)(wsb + WFMH), (__bf16*)(wsb + WFML));
  fold_mfma<3><<<dim3(36, 3), 256, 0, stream>>>(
      (const __bf16*)(wsb + W2TTH), (const __bf16*)(wsb + W2TTL),
      (const __bf16*)(wsb + WKH), (const __bf16*)(wsb + WKL),
      (__bf16*)(wsb + WFTH), (__bf16*)(wsb + WFTL));
  fold_bias_k<<<1, 384, 0, stream>>>(wq, mel_b2, (float*)(wsb + B2M));
  fold_bias_k<<<1, 384, 0, stream>>>(wk, txt_b2, (float*)(wsb + B2T));

  // text pipeline: conv1 -> conv2(folded) writes kT directly
  conv1_mfma<512, 3, 400><<<dim3(4, 12, B), 256, 0, stream>>>(
      (const __bf16*)(wsb + TXH), (const __bf16*)(wsb + TXL),
      (const __bf16*)(wsb + W1TH), (const __bf16*)(wsb + W1TL),
      txt_b1, xl, (__bf16*)(wsb + HH), (__bf16*)(wsb + HL));
  conv2_mfma<3, 400, true><<<dim3(4, 2, B), 256, 0, stream>>>(
      (const __bf16*)(wsb + HH), (const __bf16*)(wsb + HL),
      (const __bf16*)(wsb + WFTH), (const __bf16*)(wsb + WFTL),
      (const float*)(wsb + B2T), bk, xl, (float*)(wsb + KTF));

  // mel pipeline: conv1 -> conv2(folded) writes q directly
  conv1_mfma<96, 5, 1600><<<dim3(13, 12, B), 256, 0, stream>>>(
      (const __bf16*)(wsb + MXH), (const __bf16*)(wsb + MXL),
      (const __bf16*)(wsb + W1MH), (const __bf16*)(wsb + W1ML),
      mel_b1, yl, (__bf16*)(wsb + HH), (__bf16*)(wsb + HL));
  conv2_mfma<5, 1600, false><<<dim3(13, 2, B), 256, 0, stream>>>(
      (const __bf16*)(wsb + HH), (const __bf16*)(wsb + HL),
      (const __bf16*)(wsb + WFMH), (const __bf16*)(wsb + WFML),
      (const float*)(wsb + B2M), bq, yl, (float*)(wsb + QF));

  // attention + MAS
  scores_k<<<dim3(100, B), 512, 0, stream>>>(
      (const float*)(wsb + QF), (const float*)(wsb + KTF), xl, yl, o_attn, o_logp);
  mas_k<<<B, 256, 0, stream>>>(o_logp, xl, yl, o_hard, o_dur);
}